// Round 7
// baseline (1821.699 us; speedup 1.0000x reference)
//
#include <hip/hip_runtime.h>
#include <cstddef>

// ---------------------------------------------------------------------------
// VQ-VAE forward. Round 13: mconv3s1_k gets the mconv3s2 treatment —
// direct-global B fragments (no B LDS, 8->2 barriers per c32), LDS 51.8 KB
// -> 3 blocks/CU, 2-pass half-co epilogue through a [32][257] overlay.
// ---------------------------------------------------------------------------

typedef float v4f __attribute__((ext_vector_type(4)));
typedef _Float16 f16x8 __attribute__((ext_vector_type(8)));
typedef _Float16 f16x4 __attribute__((ext_vector_type(4)));

__device__ __forceinline__ void fma4(v4f& a, float p, const v4f& w) {
    a.x = fmaf(p, w.x, a.x); a.y = fmaf(p, w.y, a.y);
    a.z = fmaf(p, w.z, a.z); a.w = fmaf(p, w.w, a.w);
}

// Repack conv/deconv weights to fp32 [ci][9][cout] (for fp32 kernels).
__global__ void repack_k(const float* __restrict__ src, float* __restrict__ dst,
                         int cout, int coutR, int cin, int flip, int deconv)
{
    int t = blockIdx.x * 256 + threadIdx.x;
    int tot = cin * 9 * cout;
    if (t >= tot) return;
    int co = t % cout; int k = (t / cout) % 9; int ci = t / (9 * cout);
    float v = 0.f;
    if (co < coutR) {
        int ks = flip ? 8 - k : k;
        v = deconv ? src[((size_t)ci * coutR + co) * 9 + ks]
                   : src[((size_t)co * cin + ci) * 9 + ks];
    }
    dst[t] = v;
}

// Prepack weights to fp16 hi/lo MFMA B-fragment order.
__global__ void repackB16_k(const float* __restrict__ src, _Float16* __restrict__ bh,
                            _Float16* __restrict__ bl, int COUT, int CIN, int deconv)
{
    int t = blockIdx.x * 256 + threadIdx.x;
    int tot = 9 * CIN * COUT;
    if (t >= tot) return;
    int NGtot = COUT >> 4, C32 = CIN >> 5;
    int j = t & 7;
    int lane = (t >> 3) & 63;
    int blk = t >> 9;
    int ng = blk % NGtot; blk /= NGtot;
    int c32 = blk % C32;
    int tap = blk / C32;
    int co = ng * 16 + (lane & 15);
    int ci = c32 * 32 + ((lane >> 4) & 3) * 8 + j;
    float v = deconv ? src[((size_t)ci * COUT + co) * 9 + (8 - tap)]
                     : src[((size_t)co * CIN + ci) * 9 + tap];
    _Float16 h = (_Float16)v;
    _Float16 l = (_Float16)(v - (float)h);
    bh[t] = h; bl[t] = l;
}

// Pack codebook (512 x 64) to fp16 hi/lo B-fragment order.
__global__ void repackQ_k(const float* __restrict__ cb, _Float16* __restrict__ qb)
{
    int t = blockIdx.x * 256 + threadIdx.x;
    if (t >= 65536) return;
    int j = t & 7;
    int lane = (t >> 3) & 63;
    int hl = (t >> 9) & 1;
    int s = (t >> 10) & 1;
    int nt = t >> 11;
    int code = nt * 16 + (lane & 15);
    int ci = s * 32 + ((lane >> 4) & 3) * 8 + j;
    float v = cb[(size_t)code * 64 + ci];
    _Float16 h = (_Float16)v;
    qb[t] = hl ? (_Float16)(v - (float)h) : h;
}

// Codebook squared norms.
__global__ void cbnorm_k(const float* __restrict__ cb, float* __restrict__ cn)
{
    int i = blockIdx.x * 256 + threadIdx.x;
    if (i >= 512) return;
    float s = 0.f;
#pragma unroll
    for (int j = 0; j < 64; ++j) { float v = cb[i * 64 + j]; s = fmaf(v, v, s); }
    cn[i] = s;
}

// ================= MFMA 3x3 conv s1 p1 (fp16 hi/lo split) ===================
// Block: 256 positions (16x16) x 64 co. Wave: 4 rows x 64 co.
// B fragments read directly from fragment-packed global (L1-resident);
// only A staged in LDS (51.8 KB -> 3 blocks/CU). 2 barriers per c32.
// ADDMODE: 0 none, 2 channels-last addend. CLIN/CLOUT: channels-last fp32.
template<int CIN, bool RELU, int ADDMODE, bool CLIN, bool CLOUT>
__launch_bounds__(256, 3)
__global__ void mconv3s1_k(const float* __restrict__ in,
                           const _Float16* __restrict__ Bh, const _Float16* __restrict__ Bl,
                           const float* __restrict__ bias, float* __restrict__ out,
                           const float* __restrict__ addend,
                           int COUT, int H, int W)
{
    constexpr int C32 = CIN / 32;
    __shared__ __align__(16) unsigned char smBuf[51840];
    _Float16* AH = (_Float16*)smBuf;        // [18][18][40] = 12960 halves
    _Float16* AL = AH + 12960;              // 12960
    float* smO = (float*)smBuf;             // [32][257] epilogue overlay (32896 B)

    const int tid = threadIdx.x;
    const int lane = tid & 63, yb = tid >> 6;
    const int n16 = lane & 15, q = lane >> 4;

    int b = blockIdx.x;
    const int chunks = COUT >> 6;
    const int coch = b % chunks; b /= chunks;
    const int tX = W >> 4; const int tx = b % tX; b /= tX;
    const int tY = H >> 4; const int ty = b % tY; const int n = b / tY;
    const int x0 = tx * 16, y0 = ty * 16;
    const int NGtot = COUT >> 4;
    const int ngbase = coch * 4, cobase = coch * 64;

    v4f acc[4][4];
#pragma unroll
    for (int ng = 0; ng < 4; ++ng) {
        float bb = bias[cobase + ng * 16 + n16];
        v4f bv = {bb, bb, bb, bb};
#pragma unroll
        for (int mg = 0; mg < 4; ++mg) acc[mg][ng] = bv;
    }

    const uint4* bhp = (const uint4*)Bh;
    const uint4* blp = (const uint4*)Bl;

    for (int c32 = 0; c32 < C32; ++c32) {
        __syncthreads();
        if (CLIN) {
            // ---- stage A from channels-last: float4 loads, b64 LDS writes ----
            for (int u = tid; u < 2592; u += 256) {
                int cell = u >> 3, f4 = u & 7;
                int yy = cell / 18, xx = cell - yy * 18;
                int gy = y0 - 1 + yy, gx = x0 - 1 + xx;
                float4 v = make_float4(0.f, 0.f, 0.f, 0.f);
                if (gy >= 0 && gy < H && gx >= 0 && gx < W)
                    v = *(const float4*)&in[(((size_t)n * H + gy) * W + gx) * CIN + c32 * 32 + f4 * 4];
                f16x4 h4, l4;
                h4[0] = (_Float16)v.x; l4[0] = (_Float16)(v.x - (float)h4[0]);
                h4[1] = (_Float16)v.y; l4[1] = (_Float16)(v.y - (float)h4[1]);
                h4[2] = (_Float16)v.z; l4[2] = (_Float16)(v.z - (float)h4[2]);
                h4[3] = (_Float16)v.w; l4[3] = (_Float16)(v.w - (float)h4[3]);
                int a = (yy * 18 + xx) * 40 + f4 * 4;
                *(f16x4*)&AH[a] = h4; *(f16x4*)&AL[a] = l4;
            }
        } else {
            // ---- stage A from NCHW: scalar gather ----
            for (int u = tid; u < 10368; u += 256) {
                int ci = u / 324, rem = u - ci * 324;
                int yy = rem / 18, xx = rem - yy * 18;
                int gy = y0 - 1 + yy, gx = x0 - 1 + xx;
                float v = 0.f;
                if (gy >= 0 && gy < H && gx >= 0 && gx < W)
                    v = in[(((size_t)n * CIN + c32 * 32 + ci) * H + gy) * W + gx];
                _Float16 h = (_Float16)v;
                _Float16 l = (_Float16)(v - (float)h);
                int a = (yy * 18 + xx) * 40 + ci;
                AH[a] = h; AL[a] = l;
            }
        }
        __syncthreads();
#pragma unroll
        for (int ky = 0; ky < 3; ++ky) {
#pragma unroll
            for (int kx = 0; kx < 3; ++kx) {
                f16x8 aH[4], aL[4];
#pragma unroll
                for (int mg = 0; mg < 4; ++mg) {
                    int aoff = ((4 * yb + mg + ky) * 18 + n16 + kx) * 40 + q * 8;
                    aH[mg] = *(const f16x8*)&AH[aoff];
                    aL[mg] = *(const f16x8*)&AL[aoff];
                }
                size_t sb0 = (((size_t)(ky * 3 + kx) * C32 + c32) * NGtot + ngbase) * 64 + lane;
#pragma unroll
                for (int ng = 0; ng < 4; ++ng) {
                    uint4 rH = bhp[sb0 + (size_t)ng * 64];
                    uint4 rL = blp[sb0 + (size_t)ng * 64];
                    f16x8 bH = *(const f16x8*)&rH;
                    f16x8 bL = *(const f16x8*)&rL;
#pragma unroll
                    for (int mg = 0; mg < 4; ++mg) {
                        acc[mg][ng] = __builtin_amdgcn_mfma_f32_16x16x32_f16(aH[mg], bH, acc[mg][ng], 0, 0, 0);
                        acc[mg][ng] = __builtin_amdgcn_mfma_f32_16x16x32_f16(aL[mg], bH, acc[mg][ng], 0, 0, 0);
                        acc[mg][ng] = __builtin_amdgcn_mfma_f32_16x16x32_f16(aH[mg], bL, acc[mg][ng], 0, 0, 0);
                    }
                }
            }
        }
    }

    // ---- epilogue: 2 half-co passes through [32][257] LDS transpose ----
#pragma unroll
    for (int half = 0; half < 2; ++half) {
        __syncthreads();
#pragma unroll
        for (int g2 = 0; g2 < 2; ++g2) {
            int ng = half * 2 + g2;
            int row = g2 * 16 + n16;
#pragma unroll
            for (int mg = 0; mg < 4; ++mg) {
                int p = (4 * yb + mg) * 16 + q * 4;
#pragma unroll
                for (int r = 0; r < 4; ++r)
                    smO[row * 257 + p + r] = acc[mg][ng][r];
            }
        }
        __syncthreads();
        if (CLOUT) {
            const int p = tid;
            const int py = p >> 4, px = p & 15;
            size_t cellBase = (((size_t)n * H + (y0 + py)) * W + (x0 + px)) * COUT + cobase + half * 32;
            float* cellp = out + cellBase;
            const float* acell = (ADDMODE == 2) ? addend + cellBase : nullptr;
#pragma unroll
            for (int g = 0; g < 8; ++g) {
                float4 v;
                v.x = smO[(4 * g + 0) * 257 + p];
                v.y = smO[(4 * g + 1) * 257 + p];
                v.z = smO[(4 * g + 2) * 257 + p];
                v.w = smO[(4 * g + 3) * 257 + p];
                if (ADDMODE == 2) {
                    float4 a4 = *(const float4*)&acell[4 * g];
                    v.x += a4.x; v.y += a4.y; v.z += a4.z; v.w += a4.w;
                }
                if (RELU) {
                    v.x = fmaxf(v.x, 0.f); v.y = fmaxf(v.y, 0.f);
                    v.z = fmaxf(v.z, 0.f); v.w = fmaxf(v.w, 0.f);
                }
                *(float4*)&cellp[4 * g] = v;
            }
        } else {
            const size_t plane = (size_t)H * W;
            float* ob = out + ((size_t)n * COUT + cobase + half * 32) * plane;
#pragma unroll
            for (int k = 0; k < 32; ++k) {
                int e = tid + 256 * k;
                int co = e >> 8, p = e & 255;
                int py = p >> 4, px = p & 15;
                size_t g = (size_t)co * plane + (size_t)(y0 + py) * W + x0 + px;
                float v = smO[co * 257 + p];
                if (RELU) v = fmaxf(v, 0.f);
                ob[g] = v;
            }
        }
    }
}

// ============== MFMA 3x3 conv s2 p1 (fp16 hi/lo split) ======================
// Input channels-last [n][Hin][Win][CIN]; output channels-last.
// A-tile 9x33 halo, column-parity-split. B fragments loaded DIRECTLY from
// global (coalesced dwordx4, L1/L2-resident) — no B LDS, no per-tap barriers.
template<int CIN, int NG, bool RELU>
__launch_bounds__(256, 3)
__global__ void mconv3s2_k(const float* __restrict__ in,
                           const _Float16* __restrict__ Bh, const _Float16* __restrict__ Bl,
                           const float* __restrict__ bias, float* __restrict__ out,
                           int COUT, int Hin, int Win)
{
    constexpr int C32 = CIN / 32;
    constexpr int ASZ = 9 * 2 * 17 * 40;        // 12240 halves per H/L
    __shared__ __align__(16) unsigned char smBuf[2 * ASZ * 2];   // 48960 B
    _Float16* AH = (_Float16*)smBuf;
    _Float16* AL = AH + ASZ;
    float* smO = (float*)smBuf;                 // [NG*16][65] overlay (33280 B)

    const int tid = threadIdx.x;
    const int lane = tid & 63, yb = tid >> 6;
    const int n16 = lane & 15, q = lane >> 4;

    const int Hout = Hin >> 1, Wout = Win >> 1;
    int b = blockIdx.x;
    const int chunks = COUT / (NG * 16);
    const int coch = b % chunks; b /= chunks;
    const int tX = Wout >> 4; const int tx = b % tX; b /= tX;
    const int tY = Hout >> 2; const int ty = b % tY; const int n = b / tY;
    const int x0 = tx * 16, y0 = ty * 4;
    const int gx0 = 2 * x0 - 1, gy0 = 2 * y0 - 1;
    const int NGtot = COUT >> 4;
    const int ngbase = coch * NG, cobase = coch * NG * 16;

    v4f acc[NG];
#pragma unroll
    for (int ng = 0; ng < NG; ++ng) {
        float bb = bias[cobase + ng * 16 + n16];
        v4f bv = {bb, bb, bb, bb};
        acc[ng] = bv;
    }

    const uint4* bhp = (const uint4*)Bh;
    const uint4* blp = (const uint4*)Bl;

    for (int c32 = 0; c32 < C32; ++c32) {
        __syncthreads();
        // ---- stage A from CL: 297 cells x 8 float4, parity-split columns ----
        for (int u = tid; u < 2376; u += 256) {
            int cell = u >> 3, f4 = u & 7;
            int yy = cell / 33, xx = cell - yy * 33;
            int gy = gy0 + yy, gx = gx0 + xx;
            float4 v = make_float4(0.f, 0.f, 0.f, 0.f);
            if (gy >= 0 && gy < Hin && gx >= 0 && gx < Win)
                v = *(const float4*)&in[(((size_t)n * Hin + gy) * Win + gx) * CIN + c32 * 32 + f4 * 4];
            f16x4 h4, l4;
            h4[0] = (_Float16)v.x; l4[0] = (_Float16)(v.x - (float)h4[0]);
            h4[1] = (_Float16)v.y; l4[1] = (_Float16)(v.y - (float)h4[1]);
            h4[2] = (_Float16)v.z; l4[2] = (_Float16)(v.z - (float)h4[2]);
            h4[3] = (_Float16)v.w; l4[3] = (_Float16)(v.w - (float)h4[3]);
            int a = ((yy * 2 + (xx & 1)) * 17 + (xx >> 1)) * 40 + f4 * 4;
            *(f16x4*)&AH[a] = h4; *(f16x4*)&AL[a] = l4;
        }
        __syncthreads();
#pragma unroll
        for (int ky = 0; ky < 3; ++ky) {
#pragma unroll
            for (int kx = 0; kx < 3; ++kx) {
                const int par = kx & 1, xs = kx >> 1;
                int aoff = (((2 * yb + ky) * 2 + par) * 17 + n16 + xs) * 40 + q * 8;
                f16x8 aH = *(const f16x8*)&AH[aoff];
                f16x8 aL = *(const f16x8*)&AL[aoff];
                size_t sb0 = (((size_t)(ky * 3 + kx) * C32 + c32) * NGtot + ngbase) * 64 + lane;
#pragma unroll
                for (int ng = 0; ng < NG; ++ng) {
                    uint4 rH = bhp[sb0 + (size_t)ng * 64];
                    uint4 rL = blp[sb0 + (size_t)ng * 64];
                    f16x8 bH = *(const f16x8*)&rH;
                    f16x8 bL = *(const f16x8*)&rL;
                    acc[ng] = __builtin_amdgcn_mfma_f32_16x16x32_f16(aH, bH, acc[ng], 0, 0, 0);
                    acc[ng] = __builtin_amdgcn_mfma_f32_16x16x32_f16(aL, bH, acc[ng], 0, 0, 0);
                    acc[ng] = __builtin_amdgcn_mfma_f32_16x16x32_f16(aH, bL, acc[ng], 0, 0, 0);
                }
            }
        }
    }

    // ---- epilogue: LDS transpose -> channels-last float4 stores ----
    __syncthreads();
#pragma unroll
    for (int ng = 0; ng < NG; ++ng) {
        int co = ng * 16 + n16;
        int p = yb * 16 + q * 4;
#pragma unroll
        for (int r = 0; r < 4; ++r)
            smO[co * 65 + p + r] = acc[ng][r];
    }
    __syncthreads();
    const int p2 = tid >> 2, s2 = tid & 3;
    const int py = p2 >> 4, px = p2 & 15;
    float* cellp = out + ((((size_t)n * Hout + (y0 + py)) * Wout + (x0 + px)) * COUT + s2 * 32);
#pragma unroll
    for (int k = 0; k < 8; ++k) {
        float4 v;
        v.x = smO[(s2 * 32 + 4 * k + 0) * 65 + p2];
        v.y = smO[(s2 * 32 + 4 * k + 1) * 65 + p2];
        v.z = smO[(s2 * 32 + 4 * k + 2) * 65 + p2];
        v.w = smO[(s2 * 32 + 4 * k + 3) * 65 + p2];
        if (RELU) {
            v.x = fmaxf(v.x, 0.f); v.y = fmaxf(v.y, 0.f);
            v.z = fmaxf(v.z, 0.f); v.w = fmaxf(v.w, 0.f);
        }
        *(float4*)&cellp[4 * k] = v;
    }
}

// ======== MFMA ConvT k3 s2 p1 op1 (fp16 hi/lo), 4-phase decomposition =======
// Input D0 channels-last [n][Hin][Win][CIN]; output D1 NCHW.
template<int CIN, bool RELU>
__launch_bounds__(256, 3)
__global__ void mdeconv2_k(const float* __restrict__ in,
                           const _Float16* __restrict__ Bh, const _Float16* __restrict__ Bl,
                           const float* __restrict__ bias, float* __restrict__ out,
                           int COUT, int Hin, int Win)
{
    constexpr int C32 = CIN / 32;
    __shared__ __align__(16) unsigned char smBuf[38976];
    _Float16* AH = (_Float16*)smBuf;        // [5][18][40] = 3600 halves
    _Float16* AL = AH + 3600;               // 3600
    _Float16* BW = AL + 3600;               // [tapL3][ng4][hl2][lane64][8] = 12288
    float* smO = (float*)smBuf;             // [32][257] epilogue overlay = 32896B

    const int tid = threadIdx.x;
    const int lane = tid & 63, yb = tid >> 6;   // wave = one input row
    const int n16 = lane & 15, q = lane >> 4;

    int b = blockIdx.x;
    const int chunks = COUT >> 6;
    const int coch = b % chunks; b /= chunks;
    const int tX = Win >> 4; const int tx = b % tX; b /= tX;
    const int tY = Hin >> 2; const int ty = b % tY; const int n = b / tY;
    const int x0 = tx * 16, y0 = ty * 4;
    const int NGtot = COUT >> 4;
    const int ngbase = coch * 4, cobase = coch * 64;

    v4f acc[4][4];                              // [phase dy*2+dx][ng]
#pragma unroll
    for (int ng = 0; ng < 4; ++ng) {
        float bb = bias[cobase + ng * 16 + n16];
        v4f bv = {bb, bb, bb, bb};
#pragma unroll
        for (int ph = 0; ph < 4; ++ph) acc[ph][ng] = bv;
    }

    for (int c32 = 0; c32 < C32; ++c32) {
        __syncthreads();
        // ---- stage A (channels-last): 5 rows x 17 cols x 32 ci ----
        for (int u = tid; u < 680; u += 256) {
            int cell = u >> 3, f4 = u & 7;
            int yy = cell / 17, xx = cell - yy * 17;
            int gy = y0 + yy, gx = x0 + xx;
            float4 v = make_float4(0.f, 0.f, 0.f, 0.f);
            if (gy < Hin && gx < Win)
                v = *(const float4*)&in[(((size_t)n * Hin + gy) * Win + gx) * CIN + c32 * 32 + f4 * 4];
            f16x4 h4, l4;
            h4[0] = (_Float16)v.x; l4[0] = (_Float16)(v.x - (float)h4[0]);
            h4[1] = (_Float16)v.y; l4[1] = (_Float16)(v.y - (float)h4[1]);
            h4[2] = (_Float16)v.z; l4[2] = (_Float16)(v.z - (float)h4[2]);
            h4[3] = (_Float16)v.w; l4[3] = (_Float16)(v.w - (float)h4[3]);
            int a = (yy * 18 + xx) * 40 + f4 * 4;
            *(f16x4*)&AH[a] = h4; *(f16x4*)&AL[a] = l4;
        }
        for (int ky = 0; ky < 3; ++ky) {
            __syncthreads();
            // ---- stage B row: 3 taps x 4 ng x hi/lo, 1536 x 16B ----
            for (int u = tid; u < 1536; u += 256) {
                int lu = u & 63;
                int rest = u >> 6;
                int hl = rest & 1; rest >>= 1;
                int ng = rest & 3;
                int tapL = rest >> 2;
                const uint4* srcp = (const uint4*)(hl ? Bl : Bh);
                size_t sidx = (((size_t)(ky * 3 + tapL) * C32 + c32) * NGtot + ngbase + ng) * 64 + lu;
                ((uint4*)BW)[u] = srcp[sidx];
            }
            __syncthreads();
            const int iy = (ky == 2) ? 1 : 0;
            const int phy = (ky == 1) ? 0 : 2;
#pragma unroll
            for (int kx = 0; kx < 3; ++kx) {
                const int ix = (kx == 2) ? 1 : 0;
                const int ph = phy + ((kx == 1) ? 0 : 1);
                int aoff = ((yb + iy) * 18 + n16 + ix) * 40 + q * 8;
                f16x8 aH = *(const f16x8*)&AH[aoff];
                f16x8 aL = *(const f16x8*)&AL[aoff];
#pragma unroll
                for (int ng = 0; ng < 4; ++ng) {
                    int boff = ((kx * 4 + ng) * 2) * 512 + lane * 8;
                    f16x8 bH = *(const f16x8*)&BW[boff];
                    f16x8 bL = *(const f16x8*)&BW[boff + 512];
                    acc[ph][ng] = __builtin_amdgcn_mfma_f32_16x16x32_f16(aH, bH, acc[ph][ng], 0, 0, 0);
                    acc[ph][ng] = __builtin_amdgcn_mfma_f32_16x16x32_f16(aL, bH, acc[ph][ng], 0, 0, 0);
                    acc[ph][ng] = __builtin_amdgcn_mfma_f32_16x16x32_f16(aH, bL, acc[ph][ng], 0, 0, 0);
                }
            }
        }
    }

    // ---- epilogue: 2 half-cout passes through [32][257] LDS transpose ----
    const int Wout = Win * 2;
    const size_t plane = (size_t)(Hin * 2) * (size_t)Wout;
    float* ob = out + ((size_t)n * COUT + cobase) * plane;
    const int oy0 = 2 * y0, ox0 = 2 * x0;
#pragma unroll
    for (int half = 0; half < 2; ++half) {
        __syncthreads();
#pragma unroll
        for (int ph = 0; ph < 4; ++ph) {
            const int dy = ph >> 1, dx = ph & 1;
#pragma unroll
            for (int g = 0; g < 2; ++g) {
                int ng = half * 2 + g;
#pragma unroll
                for (int r = 0; r < 4; ++r)
                    smO[(g * 16 + n16) * 257 + (2 * yb + dy) * 32 + 2 * (q * 4 + r) + dx] = acc[ph][ng][r];
            }
        }
        __syncthreads();
#pragma unroll
        for (int k = 0; k < 32; ++k) {
            int pos = tid;
            int oyl = pos >> 5, oxl = pos & 31;
            float v = smO[k * 257 + pos];
            if (RELU) v = fmaxf(v, 0.f);
            ob[(size_t)(half * 32 + k) * plane + (size_t)(oy0 + oyl) * Wout + ox0 + oxl] = v;
        }
    }
}

// ===================== 3x3 conv s2 p1 — fp32, 1x2 out x 32 co ===============
// Output channels-last (only used for enc0 conv1 -> T1).
template<int CIN, int CB, bool RELU>
__launch_bounds__(256, 4)
__global__ void conv3s2_k(const float* __restrict__ in, const float* __restrict__ wp,
                          const float* __restrict__ bias, float* __restrict__ out,
                          int COUT, int Hin, int Win)
{
    constexpr int COC = 32;
    __shared__ float smIn[CB * 2178];           // 33 x 66
    __shared__ float smW[CB * 9 * COC];
    const int Hout = Hin >> 1, Wout = Win >> 1;
    const int tid = threadIdx.x;
    int b = blockIdx.x;
    const int chunks = COUT / COC;
    const int tX = Wout / 32, tY = Hout / 16;
    const int ch = b % chunks; b /= chunks;
    const int tx = b % tX; b /= tX;
    const int ty = b % tY; const int n = b / tY;
    const int cobase = ch * COC;
    const int r = tid >> 4, c = tid & 15;
    const int gy0 = ty * 32 - 1, gx0 = tx * 64 - 1;

    v4f acc[16];
#pragma unroll
    for (int g = 0; g < 8; ++g) {
        v4f bv = *(const v4f*)&bias[cobase + 4 * g];
        acc[g] = bv; acc[8 + g] = bv;
    }

    const size_t plane = (size_t)Hin * Win;
    const float* ip0 = in + (size_t)n * CIN * plane;
    const float* wp0 = wp + cobase;

    for (int ci0 = 0; ci0 < CIN; ci0 += CB) {
        __syncthreads();
        for (int idx = tid; idx < CB * 2178; idx += 256) {
            int ci = idx / 2178, rem = idx - ci * 2178;
            int rr = rem / 66, cc = rem - rr * 66;
            int gy = gy0 + rr, gx = gx0 + cc;
            float v = 0.f;
            if (gy >= 0 && gy < Hin && gx >= 0 && gx < Win)
                v = ip0[(size_t)(ci0 + ci) * plane + (size_t)gy * Win + gx];
            smIn[idx] = v;
        }
        for (int idx = tid; idx < CB * 9 * COC; idx += 256) {
            int q2 = idx >> 5, co = idx & 31;
            smW[idx] = wp0[((size_t)ci0 * 9 + q2) * COUT + co];
        }
        __syncthreads();

#pragma unroll 1
        for (int ci = 0; ci < CB; ++ci) {
            float p[15];
            const float* sp = &smIn[ci * 2178 + 2 * r * 66 + 4 * c];
#pragma unroll
            for (int i = 0; i < 3; ++i)
#pragma unroll
                for (int j = 0; j < 5; ++j)
                    p[i * 5 + j] = sp[i * 66 + j];
            const float* wrow = &smW[ci * 288];
#pragma unroll
            for (int k = 0; k < 9; ++k) {
                const int ky = k / 3, kx = k % 3;
#pragma unroll
                for (int g = 0; g < 8; ++g) {
                    v4f wv = *(const v4f*)&wrow[k * 32 + 4 * g];
                    fma4(acc[g],     p[ky * 5 + kx],     wv);
                    fma4(acc[8 + g], p[ky * 5 + kx + 2], wv);
                }
            }
        }
    }

    // channels-last epilogue: two cells (oy,ox), (oy,ox+1), 32 co contiguous
    const int oy = ty * 16 + r, ox = tx * 32 + 2 * c;
    size_t cellBase = (((size_t)n * Hout + oy) * Wout + ox) * COUT + cobase;
#pragma unroll
    for (int g = 0; g < 8; ++g) {
        v4f v0 = acc[g], v1 = acc[8 + g];
        if (RELU) {
#pragma unroll
            for (int e = 0; e < 4; ++e) { v0[e] = fmaxf(v0[e], 0.f); v1[e] = fmaxf(v1[e], 0.f); }
        }
        *(v4f*)&out[cellBase + 4 * g] = v0;
        *(v4f*)&out[cellBase + COUT + 4 * g] = v1;
    }
}

// =========== ConvTranspose k3 s2 p1 op1 — fp32, 2 quads/thread ==============
template<int CIN, int CB, int COC, bool RELU>
__launch_bounds__(256, 3)
__global__ void deconv2_k(const float* __restrict__ in, const float* __restrict__ wp,
                          const float* __restrict__ bias, float* __restrict__ out,
                          int COUTR, int COUTP, int Hin, int Win)
{
    constexpr int RW = 33, RH = 17;
    __shared__ float smIn[CB * RH * RW];
    __shared__ float smW[CB * 9 * COC];
    const int Wout = Win * 2;
    const int tid = threadIdx.x;
    int b = blockIdx.x;
    const int chunks = COUTP / COC;
    const int qTX = Win / 32, qTY = Hin / 16;
    const int ch = b % chunks; b /= chunks;
    const int qtx = b % qTX; b /= qTX;
    const int qty = b % qTY; const int n = b / qTY;
    const int cobase = ch * COC;
    const int tqy = tid >> 4, tqx = tid & 15;
    const int qby = qty * 16, qbx = qtx * 32;

    v4f acc[8 * COC / 4];
#pragma unroll
    for (int g = 0; g < COC / 4; ++g) {
        v4f bv;
#pragma unroll
        for (int e = 0; e < 4; ++e)
            bv[e] = (cobase + 4 * g + e < COUTR) ? bias[cobase + 4 * g + e] : 0.f;
#pragma unroll
        for (int pt = 0; pt < 8; ++pt) acc[pt * (COC / 4) + g] = bv;
    }

    const size_t plane = (size_t)Hin * Win;
    const float* ip0 = in + (size_t)n * CIN * plane;
    const float* wp0 = wp + cobase;

    for (int ci0 = 0; ci0 < CIN; ci0 += CB) {
        __syncthreads();
        for (int idx = tid; idx < CB * RH * RW; idx += 256) {
            int ci = idx / (RH * RW), rem = idx - ci * (RH * RW);
            int rr = rem / RW, cc = rem - rr * RW;
            int gy = qby + rr, gx = qbx + cc;
            float v = 0.f;
            if (gy < Hin && gx < Win)
                v = ip0[(size_t)(ci0 + ci) * plane + (size_t)gy * Win + gx];
            smIn[idx] = v;
        }
        for (int idx = tid; idx < CB * 9 * COC; idx += 256) {
            int q2 = idx / COC, co = idx % COC;
            smW[idx] = wp0[((size_t)ci0 * 9 + q2) * COUTP + co];
        }
        __syncthreads();

#pragma unroll 1
        for (int ci = 0; ci < CB; ++ci) {
            float p[6];
            const float* sp = &smIn[ci * RH * RW + tqy * RW + 2 * tqx];
#pragma unroll
            for (int i = 0; i < 2; ++i)
#pragma unroll
                for (int j = 0; j < 3; ++j)
                    p[i * 3 + j] = sp[i * RW + j];
            const float* wrow = &smW[ci * 9 * COC];
#pragma unroll
            for (int k = 0; k < 9; ++k) {
                const int ky = k / 3, kx = k % 3;
                const int dy = (ky == 1) ? 0 : 1, iy = (ky == 0) ? 1 : 0;
                const int dx = (kx == 1) ? 0 : 1, ix = (kx == 0) ? 1 : 0;
#pragma unroll
                for (int g = 0; g < COC / 4; ++g) {
                    v4f wv = *(const v4f*)&wrow[k * COC + 4 * g];
                    fma4(acc[(0 + dy * 2 + dx) * (COC / 4) + g], p[iy * 3 + ix],     wv);
                    fma4(acc[(4 + dy * 2 + dx) * (COC / 4) + g], p[iy * 3 + ix + 1], wv);
                }
            }
        }
    }

    const size_t oPlane = (size_t)(Hin * 2) * Wout;
    const int oy = 2 * (qby + tqy), ox = 2 * (qbx + 2 * tqx);
#pragma unroll
    for (int g = 0; g < COC / 4; ++g)
#pragma unroll
        for (int e = 0; e < 4; ++e) {
            int cch = cobase + 4 * g + e;
            if (cch >= COUTR) break;
            float* op = out + ((size_t)n * COUTR + cch) * oPlane + (size_t)oy * Wout + ox;
#pragma unroll
            for (int a2 = 0; a2 < 2; ++a2) {
                float u0 = acc[(0 + a2 * 2 + 0) * (COC / 4) + g][e];
                float u1 = acc[(0 + a2 * 2 + 1) * (COC / 4) + g][e];
                float u2 = acc[(4 + a2 * 2 + 0) * (COC / 4) + g][e];
                float u3 = acc[(4 + a2 * 2 + 1) * (COC / 4) + g][e];
                if (RELU) { u0 = fmaxf(u0, 0.f); u1 = fmaxf(u1, 0.f);
                            u2 = fmaxf(u2, 0.f); u3 = fmaxf(u3, 0.f); }
                *(float4*)&op[(size_t)a2 * Wout] = make_float4(u0, u1, u2, u3);
            }
        }
}

// ===================== 1x1 conv stride S — 1 pos/thread, 32 co ==============
template<int CIN, int S, bool RELU, bool CLIN, bool CLOUT>
__launch_bounds__(256, 4)
__global__ void conv1x1_k(const float* __restrict__ in, const float* __restrict__ w,
                          const float* __restrict__ bias, float* __restrict__ out,
                          int COUT, int Hin, int Win, int Hout, int Wout)
{
    constexpr int COC = 32;
    __shared__ float smW[CIN * COC];
    const int tid = threadIdx.x;
    int b = blockIdx.x;
    const int chunks = COUT / COC;
    const int spB = (Hout * Wout) / 256;
    const int ch = b % chunks; b /= chunks;
    const int sb = b % spB; const int n = b / spB;
    const int cobase = ch * COC;

    for (int idx = tid; idx < CIN * COC; idx += 256) {
        int ci = idx / COC, co = idx - ci * COC;
        smW[idx] = w[(size_t)(cobase + co) * CIN + ci];
    }
    __syncthreads();

    const int pos = sb * 256 + tid;
    const int oy = pos / Wout, ox = pos - oy * Wout;

    v4f acc[8];
#pragma unroll
    for (int g = 0; g < 8; ++g) acc[g] = *(const v4f*)&bias[cobase + 4 * g];

    if (CLIN) {
        const float* ip = in + (((size_t)n * Hin + oy * S) * Win + ox * S) * CIN;
#pragma unroll 1
        for (int c4 = 0; c4 < CIN / 4; ++c4) {
            v4f v = *(const v4f*)&ip[c4 * 4];
#pragma unroll
            for (int e = 0; e < 4; ++e)
#pragma unroll
                for (int g = 0; g < 8; ++g)
                    fma4(acc[g], v[e], *(const v4f*)&smW[(c4 * 4 + e) * COC + 4 * g]);
        }
    } else {
        const size_t inPlane = (size_t)Hin * Win;
        const float* ip = in + (size_t)n * CIN * inPlane + (size_t)(oy * S) * Win + (size_t)(ox * S);
#pragma unroll 1
        for (int ci = 0; ci < CIN; ++ci) {
            float v = ip[(size_t)ci * inPlane];
#pragma unroll
            for (int g = 0; g < 8; ++g)
                fma4(acc[g], v, *(const v4f*)&smW[ci * COC + 4 * g]);
        }
    }
    const size_t outPlane = (size_t)Hout * Wout;
    if (CLOUT) {
        size_t cb2 = ((size_t)n * outPlane + pos) * COUT + cobase;
#pragma unroll
        for (int g = 0; g < 8; ++g) {
            v4f v = acc[g];
            if (RELU) {
#pragma unroll
                for (int e = 0; e < 4; ++e) v[e] = fmaxf(v[e], 0.f);
            }
            *(v4f*)&out[cb2 + 4 * g] = v;
        }
    } else {
        float* op = out + ((size_t)n * COUT + cobase) * outPlane + pos;
#pragma unroll
        for (int g = 0; g < 8; ++g)
#pragma unroll
            for (int e = 0; e < 4; ++e) {
                float v = acc[g][e];
                if (RELU) v = fmaxf(v, 0.f);
                op[(size_t)(4 * g + e) * outPlane] = v;
            }
    }
}

// ==================== MFMA quantize (argmin distance GEMM) ==================
// Input S2 channels-last [pos][64]; output Q channels-last [pos][64].
__launch_bounds__(256, 4)
__global__ void mquant_k(const float* __restrict__ h, const _Float16* __restrict__ QB,
                         const float* __restrict__ cn, const float* __restrict__ cb,
                         float* __restrict__ q)
{
    __shared__ __align__(16) _Float16 AF[2][8192];   // [hl][((mt*2+s)*64+lane)*8+j]
    __shared__ float cns[512];
    __shared__ int bidxs[128];

    const int tid = threadIdx.x;
    const int lane = tid & 63;
    const int wv = tid >> 6;
    const int n16 = lane & 15, qq = lane >> 4;

    const int n = blockIdx.x >> 5;
    const int rem0 = (blockIdx.x & 31) << 7;

    for (int u = tid; u < 1024; u += 256) {
        int posL = u >> 3, grp = u & 7;
        const float* gp = h + ((size_t)n * 4096 + rem0 + posL) * 64 + grp * 8;
        float4 v0 = *(const float4*)gp;
        float4 v1 = *(const float4*)(gp + 4);
        f16x8 hh, ll;
        hh[0] = (_Float16)v0.x; ll[0] = (_Float16)(v0.x - (float)hh[0]);
        hh[1] = (_Float16)v0.y; ll[1] = (_Float16)(v0.y - (float)hh[1]);
        hh[2] = (_Float16)v0.z; ll[2] = (_Float16)(v0.z - (float)hh[2]);
        hh[3] = (_Float16)v0.w; ll[3] = (_Float16)(v0.w - (float)hh[3]);
        hh[4] = (_Float16)v1.x; ll[4] = (_Float16)(v1.x - (float)hh[4]);
        hh[5] = (_Float16)v1.y; ll[5] = (_Float16)(v1.y - (float)hh[5]);
        hh[6] = (_Float16)v1.z; ll[6] = (_Float16)(v1.z - (float)hh[6]);
        hh[7] = (_Float16)v1.w; ll[7] = (_Float16)(v1.w - (float)hh[7]);
        int mt = posL >> 4, s = grp >> 2, qv = grp & 3;
        int a = ((mt * 2 + s) * 64 + (posL & 15) + qv * 16) * 8;
        *(f16x8*)&AF[0][a] = hh;
        *(f16x8*)&AF[1][a] = ll;
    }
    for (int u = tid; u < 512; u += 256) cns[u] = cn[u];
    __syncthreads();

    f16x8 aH[2][2], aL[2][2];
#pragma unroll
    for (int m = 0; m < 2; ++m)
#pragma unroll
        for (int s = 0; s < 2; ++s) {
            int a = (((wv * 2 + m) * 2 + s) * 64 + lane) * 8;
            aH[m][s] = *(const f16x8*)&AF[0][a];
            aL[m][s] = *(const f16x8*)&AF[1][a];
        }

    float best[2][4]; int bi[2][4];
#pragma unroll
    for (int m = 0; m < 2; ++m)
#pragma unroll
        for (int r = 0; r < 4; ++r) { best[m][r] = 3.4e38f; bi[m][r] = 0; }

    const uint4* qbp = (const uint4*)QB;
#pragma unroll 1
    for (int nt = 0; nt < 32; ++nt) {
        uint4 rH0 = qbp[((nt * 2 + 0) * 2 + 0) * 64 + lane];
        uint4 rL0 = qbp[((nt * 2 + 0) * 2 + 1) * 64 + lane];
        uint4 rH1 = qbp[((nt * 2 + 1) * 2 + 0) * 64 + lane];
        uint4 rL1 = qbp[((nt * 2 + 1) * 2 + 1) * 64 + lane];
        f16x8 bH0 = *(const f16x8*)&rH0;
        f16x8 bL0 = *(const f16x8*)&rL0;
        f16x8 bH1 = *(const f16x8*)&rH1;
        f16x8 bL1 = *(const f16x8*)&rL1;
        float cnv = cns[nt * 16 + n16];
        const int code = nt * 16 + n16;
#pragma unroll
        for (int m = 0; m < 2; ++m) {
            v4f acc = {0.f, 0.f, 0.f, 0.f};
            acc = __builtin_amdgcn_mfma_f32_16x16x32_f16(aH[m][0], bH0, acc, 0, 0, 0);
            acc = __builtin_amdgcn_mfma_f32_16x16x32_f16(aL[m][0], bH0, acc, 0, 0, 0);
            acc = __builtin_amdgcn_mfma_f32_16x16x32_f16(aH[m][0], bL0, acc, 0, 0, 0);
            acc = __builtin_amdgcn_mfma_f32_16x16x32_f16(aH[m][1], bH1, acc, 0, 0, 0);
            acc = __builtin_amdgcn_mfma_f32_16x16x32_f16(aL[m][1], bH1, acc, 0, 0, 0);
            acc = __builtin_amdgcn_mfma_f32_16x16x32_f16(aH[m][1], bL1, acc, 0, 0, 0);
#pragma unroll
            for (int r = 0; r < 4; ++r) {
                float d = fmaf(-2.f, acc[r], cnv);
                if (d < best[m][r]) { best[m][r] = d; bi[m][r] = code; }
            }
        }
    }

    // reduce across the 16 lane-columns; first-min tie-break (lowest index)
#pragma unroll
    for (int m = 0; m < 2; ++m)
#pragma unroll
        for (int r = 0; r < 4; ++r) {
#pragma unroll
            for (int msk = 1; msk < 16; msk <<= 1) {
                float ob = __shfl_xor(best[m][r], msk);
                int oi = __shfl_xor(bi[m][r], msk);
                if (ob < best[m][r] || (ob == best[m][r] && oi < bi[m][r])) {
                    best[m][r] = ob; bi[m][r] = oi;
                }
            }
            if (n16 == 0) bidxs[wv * 32 + m * 16 + qq * 4 + r] = bi[m][r];
        }
    __syncthreads();

    const int p = tid & 127, jh = tid >> 7;
    const int code = bidxs[p];
    const float4* crow4 = (const float4*)(cb + (size_t)code * 64);
    float4* qp4 = (float4*)(q + ((size_t)n * 4096 + rem0 + p) * 64);
#pragma unroll
    for (int k = 0; k < 8; ++k)
        qp4[jh * 8 + k] = crow4[jh * 8 + k];
}

extern "C" void kernel_launch(void* const* d_in, const int* in_sizes, int n_in,
                              void* d_out, int out_size, void* d_ws, size_t ws_size,
                              hipStream_t stream)
{
    const float* x    = (const float*)d_in[0];
    const float* e0w1 = (const float*)d_in[1];  const float* e0b1 = (const float*)d_in[2];
    const float* e0w2 = (const float*)d_in[3];  const float* e0b2 = (const float*)d_in[4];
    const float* e0wd = (const float*)d_in[5];  const float* e0bd = (const float*)d_in[6];
    const float* e1w1 = (const float*)d_in[7];  const float* e1b1 = (const float*)d_in[8];
    const float* e1w2 = (const float*)d_in[9];  const float* e1b2 = (const float*)d_in[10];
    const float* e1wd = (const float*)d_in[11]; const float* e1bd = (const float*)d_in[12];
    const float* e2w1 = (const float*)d_in[13]; const float* e2b1 = (const float*)d_in[14];
    const float* e2w2 = (const float*)d_in[15]; const float* e2b2 = (const float*)d_in[16];
    const float* e2wd = (const float*)d_in[17]; const float* e2bd = (const float*)d_in[18];
    const float* d0w  = (const float*)d_in[19]; const float* d0b  = (const float*)d_in[20];
    const float* d1w  = (const float*)d_in[21]; const float* d1b  = (const float*)d_in[22];
    const float* d2w  = (const float*)d_in[23]; const float* d2b  = (const float*)d_in[24];
    const float* cb   = (const float*)d_in[25];
    float* out = (float*)d_out;
    float* ws  = (float*)d_ws;

    // ---- packs in d_out slack (d_out only written by the final dec2) ----
    float* P_e0w1 = out + 0;            // fp32 pack, 1728
    _Float16* Bh_d1   = (_Float16*)(out + 1728);     // 73728 halves
    _Float16* Bl_d1   = (_Float16*)(out + 38592);    // 73728 halves
    _Float16* Bh_e0c2 = (_Float16*)(out + 77760);
    _Float16* Bl_e0c2 = (_Float16*)(out + 96192);
    _Float16* Bh_e1c2 = (_Float16*)(out + 114624);
    _Float16* Bl_e1c2 = (_Float16*)(out + 188352);
    _Float16* Bh_e2c1 = (_Float16*)(out + 262080);
    _Float16* Bl_e2c1 = (_Float16*)(out + 298944);
    _Float16* Bh_e2c2 = (_Float16*)(out + 335808);
    _Float16* Bl_e2c2 = (_Float16*)(out + 354240);
    _Float16* Bh_d0   = (_Float16*)(out + 372672);
    _Float16* Bl_d0   = (_Float16*)(out + 409536);
    _Float16* Bh_e1c1 = (_Float16*)(out + 446400);   // 73728 halves
    _Float16* Bl_e1c1 = (_Float16*)(out + 483264);   // 73728 halves
    _Float16* QB = (_Float16*)(out + 520128);
    float* CN = out + 552896;
    float* P_d2w  = ws + 50405376;      // fp32 pack; written after S1 is dead

    // ---- ws activation layout (floats), liveness-planned ----
    // ALL activations channels-last except x (input) and D1.
    float* S0 = ws;                     // CL [n][128][128][64], enc0 out
    float* T1 = ws + 33554432;          // CL, enc0 conv1 out
    float* T3 = ws + 33554432;          // CL, enc1 conv1 out
    float* S1 = ws + 50331648;          // CL [n][64][64][128], enc1 out
    float* S2 = ws;                     // CL, enc2 out
    float* T5 = ws + 8388608;           // CL
    float* Q  = ws + 16777216;          // CL
    float* D0 = ws + 33554432;          // CL, dec0 out
    float* D1 = ws;                     // NCHW, dec1 out

    dim3 blk(256);
    auto rp = [&](const float* src, float* dst, int cout, int coutR, int cin, int flip, int dec) {
        int tot = cin * 9 * cout;
        repack_k<<<dim3((tot + 255) / 256), blk, 0, stream>>>(src, dst, cout, coutR, cin, flip, dec);
    };
    auto rpB = [&](const float* src, _Float16* bh, _Float16* bl, int cout, int cin, int dec) {
        int tot = 9 * cin * cout;
        repackB16_k<<<dim3((tot + 255) / 256), blk, 0, stream>>>(src, bh, bl, cout, cin, dec);
    };

    rp(e0w1, P_e0w1, 64, 64, 3, 0, 0);
    rpB(e0w2, Bh_e0c2, Bl_e0c2, 64, 64, 0);
    rpB(e1w1, Bh_e1c1, Bl_e1c1, 128, 64, 0);
    rpB(e1w2, Bh_e1c2, Bl_e1c2, 128, 128, 0);
    rpB(e2w1, Bh_e2c1, Bl_e2c1, 64, 128, 0);
    rpB(e2w2, Bh_e2c2, Bl_e2c2, 64, 64, 0);
    rpB(d0w,  Bh_d0,   Bl_d0,   128, 64, 1);   // ConvT s1 == flipped conv
    rpB(d1w,  Bh_d1,   Bl_d1,   64, 128, 1);   // ConvT s2, flipped-tap pack
    repackQ_k<<<dim3(256), blk, 0, stream>>>(cb, QB);
    cbnorm_k<<<dim3(2), blk, 0, stream>>>(cb, CN);

    // --- enc0 (3 -> 64, s2): 256 -> 128 ---
    conv1x1_k<3, 2, false, false, true><<<dim3(32 * 64 * 2), blk, 0, stream>>>(
        x, e0wd, e0bd, S0, 64, 256, 256, 128, 128);
    conv3s2_k<3, 3, true><<<dim3(32 * 8 * 4 * 2), blk, 0, stream>>>(
        x, P_e0w1, e0b1, T1, 64, 256, 256);
    mconv3s1_k<64, true, 2, true, true><<<dim3(32 * 8 * 8 * 1), blk, 0, stream>>>(
        T1, Bh_e0c2, Bl_e0c2, e0b2, S0, S0, 64, 128, 128);

    // --- enc1 (64 -> 128, s2): 128 -> 64 ---
    conv1x1_k<64, 2, false, true, true><<<dim3(32 * 16 * 4), blk, 0, stream>>>(
        S0, e1wd, e1bd, S1, 128, 128, 128, 64, 64);
    mconv3s2_k<64, 8, true><<<dim3(32 * 16 * 4), blk, 0, stream>>>(
        S0, Bh_e1c1, Bl_e1c1, e1b1, T3, 128, 128, 128);
    mconv3s1_k<128, true, 2, true, true><<<dim3(32 * 4 * 4 * 2), blk, 0, stream>>>(
        T3, Bh_e1c2, Bl_e1c2, e1b2, S1, S1, 128, 64, 64);

    // --- enc2 (128 -> 64, s1) ---
    conv1x1_k<128, 1, false, true, true><<<dim3(32 * 16 * 2), blk, 0, stream>>>(
        S1, e2wd, e2bd, S2, 64, 64, 64, 64, 64);
    mconv3s1_k<128, true, 0, true, true><<<dim3(32 * 4 * 4 * 1), blk, 0, stream>>>(
        S1, Bh_e2c1, Bl_e2c1, e2b1, T5, nullptr, 64, 64, 64);
    rp(d2w, P_d2w, 4, 3, 64, 0, 1);             // S1 dead after the two reads above
    mconv3s1_k<64, true, 2, true, true><<<dim3(32 * 4 * 4 * 1), blk, 0, stream>>>(
        T5, Bh_e2c2, Bl_e2c2, e2b2, S2, S2, 64, 64, 64);

    // --- quantize (MFMA argmin), CL in/out ---
    mquant_k<<<dim3(1024), blk, 0, stream>>>(S2, QB, CN, cb, Q);

    // --- dec0: ConvT s1 (64 -> 128) as flipped conv, ReLU, CL in/out ---
    mconv3s1_k<64, true, 0, true, true><<<dim3(32 * 4 * 4 * 2), blk, 0, stream>>>(
        Q, Bh_d0, Bl_d0, d0b, D0, nullptr, 128, 64, 64);

    // --- dec1: ConvT s2 (128 -> 64), ReLU: 64 -> 128 (MFMA, 4-phase, CL in) ---
    mdeconv2_k<128, true><<<dim3(32 * 16 * 4), blk, 0, stream>>>(
        D0, Bh_d1, Bl_d1, d1b, D1, 64, 64, 64);

    // --- dec2: ConvT s2 (64 -> 3): 128 -> 256 ---
    deconv2_k<64, 8, 4, false><<<dim3(32 * 4 * 8), blk, 0, stream>>>(
        D1, P_d2w, d2b, out, 3, 4, 128, 128);
}

// Round 8
// 1577.839 us; speedup vs baseline: 1.1546x; 1.1546x over previous
//
#include <hip/hip_runtime.h>
#include <cstddef>

// ---------------------------------------------------------------------------
// VQ-VAE forward. Round 14: revert mconv3s1_k to LDS-staged B (R12 structure,
// direct-global B regressed: 1.2MB packs miss L1, 200+cyc on critical path).
// New: T14 async-STAGE split for B — global loads into regs issued BEFORE the
// previous ky compute (latency hidden under 144 MFMAs); only regs->LDS write
// between barriers. Barriers 8->6 per c32.
// ---------------------------------------------------------------------------

typedef float v4f __attribute__((ext_vector_type(4)));
typedef _Float16 f16x8 __attribute__((ext_vector_type(8)));
typedef _Float16 f16x4 __attribute__((ext_vector_type(4)));

__device__ __forceinline__ void fma4(v4f& a, float p, const v4f& w) {
    a.x = fmaf(p, w.x, a.x); a.y = fmaf(p, w.y, a.y);
    a.z = fmaf(p, w.z, a.z); a.w = fmaf(p, w.w, a.w);
}

// Repack conv/deconv weights to fp32 [ci][9][cout] (for fp32 kernels).
__global__ void repack_k(const float* __restrict__ src, float* __restrict__ dst,
                         int cout, int coutR, int cin, int flip, int deconv)
{
    int t = blockIdx.x * 256 + threadIdx.x;
    int tot = cin * 9 * cout;
    if (t >= tot) return;
    int co = t % cout; int k = (t / cout) % 9; int ci = t / (9 * cout);
    float v = 0.f;
    if (co < coutR) {
        int ks = flip ? 8 - k : k;
        v = deconv ? src[((size_t)ci * coutR + co) * 9 + ks]
                   : src[((size_t)co * cin + ci) * 9 + ks];
    }
    dst[t] = v;
}

// Prepack weights to fp16 hi/lo MFMA B-fragment order.
__global__ void repackB16_k(const float* __restrict__ src, _Float16* __restrict__ bh,
                            _Float16* __restrict__ bl, int COUT, int CIN, int deconv)
{
    int t = blockIdx.x * 256 + threadIdx.x;
    int tot = 9 * CIN * COUT;
    if (t >= tot) return;
    int NGtot = COUT >> 4, C32 = CIN >> 5;
    int j = t & 7;
    int lane = (t >> 3) & 63;
    int blk = t >> 9;
    int ng = blk % NGtot; blk /= NGtot;
    int c32 = blk % C32;
    int tap = blk / C32;
    int co = ng * 16 + (lane & 15);
    int ci = c32 * 32 + ((lane >> 4) & 3) * 8 + j;
    float v = deconv ? src[((size_t)ci * COUT + co) * 9 + (8 - tap)]
                     : src[((size_t)co * CIN + ci) * 9 + tap];
    _Float16 h = (_Float16)v;
    _Float16 l = (_Float16)(v - (float)h);
    bh[t] = h; bl[t] = l;
}

// Pack codebook (512 x 64) to fp16 hi/lo B-fragment order.
__global__ void repackQ_k(const float* __restrict__ cb, _Float16* __restrict__ qb)
{
    int t = blockIdx.x * 256 + threadIdx.x;
    if (t >= 65536) return;
    int j = t & 7;
    int lane = (t >> 3) & 63;
    int hl = (t >> 9) & 1;
    int s = (t >> 10) & 1;
    int nt = t >> 11;
    int code = nt * 16 + (lane & 15);
    int ci = s * 32 + ((lane >> 4) & 3) * 8 + j;
    float v = cb[(size_t)code * 64 + ci];
    _Float16 h = (_Float16)v;
    qb[t] = hl ? (_Float16)(v - (float)h) : h;
}

// Codebook squared norms.
__global__ void cbnorm_k(const float* __restrict__ cb, float* __restrict__ cn)
{
    int i = blockIdx.x * 256 + threadIdx.x;
    if (i >= 512) return;
    float s = 0.f;
#pragma unroll
    for (int j = 0; j < 64; ++j) { float v = cb[i * 64 + j]; s = fmaf(v, v, s); }
    cn[i] = s;
}

// ================= MFMA 3x3 conv s1 p1 (fp16 hi/lo split) ===================
// Block: 256 positions (16x16) x 64 co. Wave: 4 rows x 64 co.
// B staged per ky-row via LDS (12-cyc reads); global->reg B prefetch issued
// BEFORE previous ky's compute (T14 async split). 6 barriers per c32.
// ADDMODE: 0 none, 1 NCHW addend, 2 channels-last addend.
template<int CIN, bool RELU, int ADDMODE, bool CLIN, bool CLOUT>
__launch_bounds__(256, 2)
__global__ void mconv3s1_k(const float* __restrict__ in,
                           const _Float16* __restrict__ Bh, const _Float16* __restrict__ Bl,
                           const float* __restrict__ bias, float* __restrict__ out,
                           const float* __restrict__ addend,
                           int COUT, int H, int W)
{
    constexpr int C32 = CIN / 32;
    __shared__ __align__(16) unsigned char smBuf[76416];
    _Float16* AH = (_Float16*)smBuf;        // [18][18][40] = 12960 halves
    _Float16* AL = AH + 12960;              // 12960
    _Float16* BW = AL + 12960;              // [tapL3][ng4][hl2][lane64][8] = 12288
    float* smO = (float*)smBuf;             // [64][257] epilogue overlay (65784 B)

    const int tid = threadIdx.x;
    const int lane = tid & 63, yb = tid >> 6;
    const int n16 = lane & 15, q = lane >> 4;

    int b = blockIdx.x;
    const int chunks = COUT >> 6;
    const int coch = b % chunks; b /= chunks;
    const int tX = W >> 4; const int tx = b % tX; b /= tX;
    const int tY = H >> 4; const int ty = b % tY; const int n = b / tY;
    const int x0 = tx * 16, y0 = ty * 16;
    const int NGtot = COUT >> 4;
    const int ngbase = coch * 4, cobase = coch * 64;

    v4f acc[4][4];
#pragma unroll
    for (int ng = 0; ng < 4; ++ng) {
        float bb = bias[cobase + ng * 16 + n16];
        v4f bv = {bb, bb, bb, bb};
#pragma unroll
        for (int mg = 0; mg < 4; ++mg) acc[mg][ng] = bv;
    }

    const uint4* bhp = (const uint4*)Bh;
    const uint4* blp = (const uint4*)Bl;

    uint4 breg[6];
    auto loadB = [&](int kyL, int c32L) {
#pragma unroll
        for (int i = 0; i < 6; ++i) {
            int u = tid + 256 * i;
            int lu = u & 63;
            int rest = u >> 6;
            int hl = rest & 1; rest >>= 1;
            int ng = rest & 3;
            int tapL = rest >> 2;
            const uint4* srcp = hl ? blp : bhp;
            size_t sidx = (((size_t)(kyL * 3 + tapL) * C32 + c32L) * NGtot + ngbase + ng) * 64 + lu;
            breg[i] = srcp[sidx];
        }
    };

    loadB(0, 0);

    for (int c32 = 0; c32 < C32; ++c32) {
        __syncthreads();
        // ---- commit prefetched B(ky=0) regs -> LDS ----
#pragma unroll
        for (int i = 0; i < 6; ++i) ((uint4*)BW)[tid + 256 * i] = breg[i];
        if (CLIN) {
            // ---- stage A from channels-last: float4 loads, b64 LDS writes ----
            for (int u = tid; u < 2592; u += 256) {
                int cell = u >> 3, f4 = u & 7;
                int yy = cell / 18, xx = cell - yy * 18;
                int gy = y0 - 1 + yy, gx = x0 - 1 + xx;
                float4 v = make_float4(0.f, 0.f, 0.f, 0.f);
                if (gy >= 0 && gy < H && gx >= 0 && gx < W)
                    v = *(const float4*)&in[(((size_t)n * H + gy) * W + gx) * CIN + c32 * 32 + f4 * 4];
                f16x4 h4, l4;
                h4[0] = (_Float16)v.x; l4[0] = (_Float16)(v.x - (float)h4[0]);
                h4[1] = (_Float16)v.y; l4[1] = (_Float16)(v.y - (float)h4[1]);
                h4[2] = (_Float16)v.z; l4[2] = (_Float16)(v.z - (float)h4[2]);
                h4[3] = (_Float16)v.w; l4[3] = (_Float16)(v.w - (float)h4[3]);
                int a = (yy * 18 + xx) * 40 + f4 * 4;
                *(f16x4*)&AH[a] = h4; *(f16x4*)&AL[a] = l4;
            }
        } else {
            // ---- stage A from NCHW: scalar gather ----
            for (int u = tid; u < 10368; u += 256) {
                int ci = u / 324, rem = u - ci * 324;
                int yy = rem / 18, xx = rem - yy * 18;
                int gy = y0 - 1 + yy, gx = x0 - 1 + xx;
                float v = 0.f;
                if (gy >= 0 && gy < H && gx >= 0 && gx < W)
                    v = in[(((size_t)n * CIN + c32 * 32 + ci) * H + gy) * W + gx];
                _Float16 h = (_Float16)v;
                _Float16 l = (_Float16)(v - (float)h);
                int a = (yy * 18 + xx) * 40 + ci;
                AH[a] = h; AL[a] = l;
            }
        }
        __syncthreads();
#pragma unroll
        for (int ky = 0; ky < 3; ++ky) {
            // ---- T14: issue next B-row global loads before this ky's MFMAs ----
            if (ky < 2) loadB(ky + 1, c32);
            else if (c32 + 1 < C32) loadB(0, c32 + 1);
#pragma unroll
            for (int kx = 0; kx < 3; ++kx) {
                f16x8 aH[4], aL[4];
#pragma unroll
                for (int mg = 0; mg < 4; ++mg) {
                    int aoff = ((4 * yb + mg + ky) * 18 + n16 + kx) * 40 + q * 8;
                    aH[mg] = *(const f16x8*)&AH[aoff];
                    aL[mg] = *(const f16x8*)&AL[aoff];
                }
#pragma unroll
                for (int ng = 0; ng < 4; ++ng) {
                    int boff = ((kx * 4 + ng) * 2) * 512 + lane * 8;
                    f16x8 bH = *(const f16x8*)&BW[boff];
                    f16x8 bL = *(const f16x8*)&BW[boff + 512];
#pragma unroll
                    for (int mg = 0; mg < 4; ++mg) {
                        acc[mg][ng] = __builtin_amdgcn_mfma_f32_16x16x32_f16(aH[mg], bH, acc[mg][ng], 0, 0, 0);
                        acc[mg][ng] = __builtin_amdgcn_mfma_f32_16x16x32_f16(aL[mg], bH, acc[mg][ng], 0, 0, 0);
                        acc[mg][ng] = __builtin_amdgcn_mfma_f32_16x16x32_f16(aH[mg], bL, acc[mg][ng], 0, 0, 0);
                    }
                }
            }
            if (ky < 2) {
                __syncthreads();
#pragma unroll
                for (int i = 0; i < 6; ++i) ((uint4*)BW)[tid + 256 * i] = breg[i];
                __syncthreads();
            }
        }
    }

    // ---- epilogue: LDS transpose -> coalesced stores ----
    __syncthreads();
#pragma unroll
    for (int mg = 0; mg < 4; ++mg)
#pragma unroll
        for (int ng = 0; ng < 4; ++ng) {
            int p = (4 * yb + mg) * 16 + q * 4;
            int co = ng * 16 + n16;
#pragma unroll
            for (int r = 0; r < 4; ++r)
                smO[co * 257 + p + r] = acc[mg][ng][r];
        }
    __syncthreads();
    if (CLOUT) {
        const int p = tid;
        const int py = p >> 4, px = p & 15;
        size_t cellBase = (((size_t)n * H + (y0 + py)) * W + (x0 + px)) * COUT + cobase;
        float* cellp = out + cellBase;
        const float* acell = (ADDMODE == 2) ? addend + cellBase : nullptr;
#pragma unroll
        for (int g = 0; g < 16; ++g) {
            float4 v;
            v.x = smO[(4 * g + 0) * 257 + p];
            v.y = smO[(4 * g + 1) * 257 + p];
            v.z = smO[(4 * g + 2) * 257 + p];
            v.w = smO[(4 * g + 3) * 257 + p];
            if (ADDMODE == 2) {
                float4 a4 = *(const float4*)&acell[4 * g];
                v.x += a4.x; v.y += a4.y; v.z += a4.z; v.w += a4.w;
            }
            if (RELU) {
                v.x = fmaxf(v.x, 0.f); v.y = fmaxf(v.y, 0.f);
                v.z = fmaxf(v.z, 0.f); v.w = fmaxf(v.w, 0.f);
            }
            *(float4*)&cellp[4 * g] = v;
        }
    } else {
        const size_t plane = (size_t)H * W;
        float* ob = out + ((size_t)n * COUT + cobase) * plane;
        const float* ab = (ADDMODE == 1) ? addend + ((size_t)n * COUT + cobase) * plane : nullptr;
#pragma unroll
        for (int k = 0; k < 64; ++k) {
            int e = tid + 256 * k;
            int co = e >> 8, p = e & 255;
            int py = p >> 4, px = p & 15;
            size_t g = (size_t)co * plane + (size_t)(y0 + py) * W + x0 + px;
            float v = smO[co * 257 + p];
            if (ADDMODE == 1) v += ab[g];
            if (RELU) v = fmaxf(v, 0.f);
            ob[g] = v;
        }
    }
}

// ============== MFMA 3x3 conv s2 p1 (fp16 hi/lo split) ======================
// Input channels-last [n][Hin][Win][CIN]; output channels-last.
// A-tile 9x33 halo, column-parity-split. B fragments loaded DIRECTLY from
// global (coalesced dwordx4, L1/L2-resident) — no B LDS, no per-tap barriers.
template<int CIN, int NG, bool RELU>
__launch_bounds__(256, 3)
__global__ void mconv3s2_k(const float* __restrict__ in,
                           const _Float16* __restrict__ Bh, const _Float16* __restrict__ Bl,
                           const float* __restrict__ bias, float* __restrict__ out,
                           int COUT, int Hin, int Win)
{
    constexpr int C32 = CIN / 32;
    constexpr int ASZ = 9 * 2 * 17 * 40;        // 12240 halves per H/L
    __shared__ __align__(16) unsigned char smBuf[2 * ASZ * 2];   // 48960 B
    _Float16* AH = (_Float16*)smBuf;
    _Float16* AL = AH + ASZ;
    float* smO = (float*)smBuf;                 // [NG*16][65] overlay (33280 B)

    const int tid = threadIdx.x;
    const int lane = tid & 63, yb = tid >> 6;
    const int n16 = lane & 15, q = lane >> 4;

    const int Hout = Hin >> 1, Wout = Win >> 1;
    int b = blockIdx.x;
    const int chunks = COUT / (NG * 16);
    const int coch = b % chunks; b /= chunks;
    const int tX = Wout >> 4; const int tx = b % tX; b /= tX;
    const int tY = Hout >> 2; const int ty = b % tY; const int n = b / tY;
    const int x0 = tx * 16, y0 = ty * 4;
    const int gx0 = 2 * x0 - 1, gy0 = 2 * y0 - 1;
    const int NGtot = COUT >> 4;
    const int ngbase = coch * NG, cobase = coch * NG * 16;

    v4f acc[NG];
#pragma unroll
    for (int ng = 0; ng < NG; ++ng) {
        float bb = bias[cobase + ng * 16 + n16];
        v4f bv = {bb, bb, bb, bb};
        acc[ng] = bv;
    }

    const uint4* bhp = (const uint4*)Bh;
    const uint4* blp = (const uint4*)Bl;

    for (int c32 = 0; c32 < C32; ++c32) {
        __syncthreads();
        // ---- stage A from CL: 297 cells x 8 float4, parity-split columns ----
        for (int u = tid; u < 2376; u += 256) {
            int cell = u >> 3, f4 = u & 7;
            int yy = cell / 33, xx = cell - yy * 33;
            int gy = gy0 + yy, gx = gx0 + xx;
            float4 v = make_float4(0.f, 0.f, 0.f, 0.f);
            if (gy >= 0 && gy < Hin && gx >= 0 && gx < Win)
                v = *(const float4*)&in[(((size_t)n * Hin + gy) * Win + gx) * CIN + c32 * 32 + f4 * 4];
            f16x4 h4, l4;
            h4[0] = (_Float16)v.x; l4[0] = (_Float16)(v.x - (float)h4[0]);
            h4[1] = (_Float16)v.y; l4[1] = (_Float16)(v.y - (float)h4[1]);
            h4[2] = (_Float16)v.z; l4[2] = (_Float16)(v.z - (float)h4[2]);
            h4[3] = (_Float16)v.w; l4[3] = (_Float16)(v.w - (float)h4[3]);
            int a = ((yy * 2 + (xx & 1)) * 17 + (xx >> 1)) * 40 + f4 * 4;
            *(f16x4*)&AH[a] = h4; *(f16x4*)&AL[a] = l4;
        }
        __syncthreads();
#pragma unroll
        for (int ky = 0; ky < 3; ++ky) {
#pragma unroll
            for (int kx = 0; kx < 3; ++kx) {
                const int par = kx & 1, xs = kx >> 1;
                int aoff = (((2 * yb + ky) * 2 + par) * 17 + n16 + xs) * 40 + q * 8;
                f16x8 aH = *(const f16x8*)&AH[aoff];
                f16x8 aL = *(const f16x8*)&AL[aoff];
                size_t sb0 = (((size_t)(ky * 3 + kx) * C32 + c32) * NGtot + ngbase) * 64 + lane;
#pragma unroll
                for (int ng = 0; ng < NG; ++ng) {
                    uint4 rH = bhp[sb0 + (size_t)ng * 64];
                    uint4 rL = blp[sb0 + (size_t)ng * 64];
                    f16x8 bH = *(const f16x8*)&rH;
                    f16x8 bL = *(const f16x8*)&rL;
                    acc[ng] = __builtin_amdgcn_mfma_f32_16x16x32_f16(aH, bH, acc[ng], 0, 0, 0);
                    acc[ng] = __builtin_amdgcn_mfma_f32_16x16x32_f16(aL, bH, acc[ng], 0, 0, 0);
                    acc[ng] = __builtin_amdgcn_mfma_f32_16x16x32_f16(aH, bL, acc[ng], 0, 0, 0);
                }
            }
        }
    }

    // ---- epilogue: LDS transpose -> channels-last float4 stores ----
    __syncthreads();
#pragma unroll
    for (int ng = 0; ng < NG; ++ng) {
        int co = ng * 16 + n16;
        int p = yb * 16 + q * 4;
#pragma unroll
        for (int r = 0; r < 4; ++r)
            smO[co * 65 + p + r] = acc[ng][r];
    }
    __syncthreads();
    const int p2 = tid >> 2, s2 = tid & 3;
    const int py = p2 >> 4, px = p2 & 15;
    float* cellp = out + ((((size_t)n * Hout + (y0 + py)) * Wout + (x0 + px)) * COUT + s2 * 32);
#pragma unroll
    for (int k = 0; k < 8; ++k) {
        float4 v;
        v.x = smO[(s2 * 32 + 4 * k + 0) * 65 + p2];
        v.y = smO[(s2 * 32 + 4 * k + 1) * 65 + p2];
        v.z = smO[(s2 * 32 + 4 * k + 2) * 65 + p2];
        v.w = smO[(s2 * 32 + 4 * k + 3) * 65 + p2];
        if (RELU) {
            v.x = fmaxf(v.x, 0.f); v.y = fmaxf(v.y, 0.f);
            v.z = fmaxf(v.z, 0.f); v.w = fmaxf(v.w, 0.f);
        }
        *(float4*)&cellp[4 * k] = v;
    }
}

// ======== MFMA ConvT k3 s2 p1 op1 (fp16 hi/lo), 4-phase decomposition =======
// Input D0 channels-last [n][Hin][Win][CIN]; output D1 NCHW.
template<int CIN, bool RELU>
__launch_bounds__(256, 3)
__global__ void mdeconv2_k(const float* __restrict__ in,
                           const _Float16* __restrict__ Bh, const _Float16* __restrict__ Bl,
                           const float* __restrict__ bias, float* __restrict__ out,
                           int COUT, int Hin, int Win)
{
    constexpr int C32 = CIN / 32;
    __shared__ __align__(16) unsigned char smBuf[38976];
    _Float16* AH = (_Float16*)smBuf;        // [5][18][40] = 3600 halves
    _Float16* AL = AH + 3600;               // 3600
    _Float16* BW = AL + 3600;               // [tapL3][ng4][hl2][lane64][8] = 12288
    float* smO = (float*)smBuf;             // [32][257] epilogue overlay = 32896B

    const int tid = threadIdx.x;
    const int lane = tid & 63, yb = tid >> 6;   // wave = one input row
    const int n16 = lane & 15, q = lane >> 4;

    int b = blockIdx.x;
    const int chunks = COUT >> 6;
    const int coch = b % chunks; b /= chunks;
    const int tX = Win >> 4; const int tx = b % tX; b /= tX;
    const int tY = Hin >> 2; const int ty = b % tY; const int n = b / tY;
    const int x0 = tx * 16, y0 = ty * 4;
    const int NGtot = COUT >> 4;
    const int ngbase = coch * 4, cobase = coch * 64;

    v4f acc[4][4];                              // [phase dy*2+dx][ng]
#pragma unroll
    for (int ng = 0; ng < 4; ++ng) {
        float bb = bias[cobase + ng * 16 + n16];
        v4f bv = {bb, bb, bb, bb};
#pragma unroll
        for (int ph = 0; ph < 4; ++ph) acc[ph][ng] = bv;
    }

    for (int c32 = 0; c32 < C32; ++c32) {
        __syncthreads();
        // ---- stage A (channels-last): 5 rows x 17 cols x 32 ci ----
        for (int u = tid; u < 680; u += 256) {
            int cell = u >> 3, f4 = u & 7;
            int yy = cell / 17, xx = cell - yy * 17;
            int gy = y0 + yy, gx = x0 + xx;
            float4 v = make_float4(0.f, 0.f, 0.f, 0.f);
            if (gy < Hin && gx < Win)
                v = *(const float4*)&in[(((size_t)n * Hin + gy) * Win + gx) * CIN + c32 * 32 + f4 * 4];
            f16x4 h4, l4;
            h4[0] = (_Float16)v.x; l4[0] = (_Float16)(v.x - (float)h4[0]);
            h4[1] = (_Float16)v.y; l4[1] = (_Float16)(v.y - (float)h4[1]);
            h4[2] = (_Float16)v.z; l4[2] = (_Float16)(v.z - (float)h4[2]);
            h4[3] = (_Float16)v.w; l4[3] = (_Float16)(v.w - (float)h4[3]);
            int a = (yy * 18 + xx) * 40 + f4 * 4;
            *(f16x4*)&AH[a] = h4; *(f16x4*)&AL[a] = l4;
        }
        for (int ky = 0; ky < 3; ++ky) {
            __syncthreads();
            // ---- stage B row: 3 taps x 4 ng x hi/lo, 1536 x 16B ----
            for (int u = tid; u < 1536; u += 256) {
                int lu = u & 63;
                int rest = u >> 6;
                int hl = rest & 1; rest >>= 1;
                int ng = rest & 3;
                int tapL = rest >> 2;
                const uint4* srcp = (const uint4*)(hl ? Bl : Bh);
                size_t sidx = (((size_t)(ky * 3 + tapL) * C32 + c32) * NGtot + ngbase + ng) * 64 + lu;
                ((uint4*)BW)[u] = srcp[sidx];
            }
            __syncthreads();
            const int iy = (ky == 2) ? 1 : 0;
            const int phy = (ky == 1) ? 0 : 2;
#pragma unroll
            for (int kx = 0; kx < 3; ++kx) {
                const int ix = (kx == 2) ? 1 : 0;
                const int ph = phy + ((kx == 1) ? 0 : 1);
                int aoff = ((yb + iy) * 18 + n16 + ix) * 40 + q * 8;
                f16x8 aH = *(const f16x8*)&AH[aoff];
                f16x8 aL = *(const f16x8*)&AL[aoff];
#pragma unroll
                for (int ng = 0; ng < 4; ++ng) {
                    int boff = ((kx * 4 + ng) * 2) * 512 + lane * 8;
                    f16x8 bH = *(const f16x8*)&BW[boff];
                    f16x8 bL = *(const f16x8*)&BW[boff + 512];
                    acc[ph][ng] = __builtin_amdgcn_mfma_f32_16x16x32_f16(aH, bH, acc[ph][ng], 0, 0, 0);
                    acc[ph][ng] = __builtin_amdgcn_mfma_f32_16x16x32_f16(aL, bH, acc[ph][ng], 0, 0, 0);
                    acc[ph][ng] = __builtin_amdgcn_mfma_f32_16x16x32_f16(aH, bL, acc[ph][ng], 0, 0, 0);
                }
            }
        }
    }

    // ---- epilogue: 2 half-cout passes through [32][257] LDS transpose ----
    const int Wout = Win * 2;
    const size_t plane = (size_t)(Hin * 2) * (size_t)Wout;
    float* ob = out + ((size_t)n * COUT + cobase) * plane;
    const int oy0 = 2 * y0, ox0 = 2 * x0;
#pragma unroll
    for (int half = 0; half < 2; ++half) {
        __syncthreads();
#pragma unroll
        for (int ph = 0; ph < 4; ++ph) {
            const int dy = ph >> 1, dx = ph & 1;
#pragma unroll
            for (int g = 0; g < 2; ++g) {
                int ng = half * 2 + g;
#pragma unroll
                for (int r = 0; r < 4; ++r)
                    smO[(g * 16 + n16) * 257 + (2 * yb + dy) * 32 + 2 * (q * 4 + r) + dx] = acc[ph][ng][r];
            }
        }
        __syncthreads();
#pragma unroll
        for (int k = 0; k < 32; ++k) {
            int pos = tid;
            int oyl = pos >> 5, oxl = pos & 31;
            float v = smO[k * 257 + pos];
            if (RELU) v = fmaxf(v, 0.f);
            ob[(size_t)(half * 32 + k) * plane + (size_t)(oy0 + oyl) * Wout + ox0 + oxl] = v;
        }
    }
}

// ===================== 3x3 conv s2 p1 — fp32, 1x2 out x 32 co ===============
// Output channels-last (only used for enc0 conv1 -> T1).
template<int CIN, int CB, bool RELU>
__launch_bounds__(256, 4)
__global__ void conv3s2_k(const float* __restrict__ in, const float* __restrict__ wp,
                          const float* __restrict__ bias, float* __restrict__ out,
                          int COUT, int Hin, int Win)
{
    constexpr int COC = 32;
    __shared__ float smIn[CB * 2178];           // 33 x 66
    __shared__ float smW[CB * 9 * COC];
    const int Hout = Hin >> 1, Wout = Win >> 1;
    const int tid = threadIdx.x;
    int b = blockIdx.x;
    const int chunks = COUT / COC;
    const int tX = Wout / 32, tY = Hout / 16;
    const int ch = b % chunks; b /= chunks;
    const int tx = b % tX; b /= tX;
    const int ty = b % tY; const int n = b / tY;
    const int cobase = ch * COC;
    const int r = tid >> 4, c = tid & 15;
    const int gy0 = ty * 32 - 1, gx0 = tx * 64 - 1;

    v4f acc[16];
#pragma unroll
    for (int g = 0; g < 8; ++g) {
        v4f bv = *(const v4f*)&bias[cobase + 4 * g];
        acc[g] = bv; acc[8 + g] = bv;
    }

    const size_t plane = (size_t)Hin * Win;
    const float* ip0 = in + (size_t)n * CIN * plane;
    const float* wp0 = wp + cobase;

    for (int ci0 = 0; ci0 < CIN; ci0 += CB) {
        __syncthreads();
        for (int idx = tid; idx < CB * 2178; idx += 256) {
            int ci = idx / 2178, rem = idx - ci * 2178;
            int rr = rem / 66, cc = rem - rr * 66;
            int gy = gy0 + rr, gx = gx0 + cc;
            float v = 0.f;
            if (gy >= 0 && gy < Hin && gx >= 0 && gx < Win)
                v = ip0[(size_t)(ci0 + ci) * plane + (size_t)gy * Win + gx];
            smIn[idx] = v;
        }
        for (int idx = tid; idx < CB * 9 * COC; idx += 256) {
            int q2 = idx >> 5, co = idx & 31;
            smW[idx] = wp0[((size_t)ci0 * 9 + q2) * COUT + co];
        }
        __syncthreads();

#pragma unroll 1
        for (int ci = 0; ci < CB; ++ci) {
            float p[15];
            const float* sp = &smIn[ci * 2178 + 2 * r * 66 + 4 * c];
#pragma unroll
            for (int i = 0; i < 3; ++i)
#pragma unroll
                for (int j = 0; j < 5; ++j)
                    p[i * 5 + j] = sp[i * 66 + j];
            const float* wrow = &smW[ci * 288];
#pragma unroll
            for (int k = 0; k < 9; ++k) {
                const int ky = k / 3, kx = k % 3;
#pragma unroll
                for (int g = 0; g < 8; ++g) {
                    v4f wv = *(const v4f*)&wrow[k * 32 + 4 * g];
                    fma4(acc[g],     p[ky * 5 + kx],     wv);
                    fma4(acc[8 + g], p[ky * 5 + kx + 2], wv);
                }
            }
        }
    }

    // channels-last epilogue: two cells (oy,ox), (oy,ox+1), 32 co contiguous
    const int oy = ty * 16 + r, ox = tx * 32 + 2 * c;
    size_t cellBase = (((size_t)n * Hout + oy) * Wout + ox) * COUT + cobase;
#pragma unroll
    for (int g = 0; g < 8; ++g) {
        v4f v0 = acc[g], v1 = acc[8 + g];
        if (RELU) {
#pragma unroll
            for (int e = 0; e < 4; ++e) { v0[e] = fmaxf(v0[e], 0.f); v1[e] = fmaxf(v1[e], 0.f); }
        }
        *(v4f*)&out[cellBase + 4 * g] = v0;
        *(v4f*)&out[cellBase + COUT + 4 * g] = v1;
    }
}

// =========== ConvTranspose k3 s2 p1 op1 — fp32, 2 quads/thread ==============
template<int CIN, int CB, int COC, bool RELU>
__launch_bounds__(256, 3)
__global__ void deconv2_k(const float* __restrict__ in, const float* __restrict__ wp,
                          const float* __restrict__ bias, float* __restrict__ out,
                          int COUTR, int COUTP, int Hin, int Win)
{
    constexpr int RW = 33, RH = 17;
    __shared__ float smIn[CB * RH * RW];
    __shared__ float smW[CB * 9 * COC];
    const int Wout = Win * 2;
    const int tid = threadIdx.x;
    int b = blockIdx.x;
    const int chunks = COUTP / COC;
    const int qTX = Win / 32, qTY = Hin / 16;
    const int ch = b % chunks; b /= chunks;
    const int qtx = b % qTX; b /= qTX;
    const int qty = b % qTY; const int n = b / qTY;
    const int cobase = ch * COC;
    const int tqy = tid >> 4, tqx = tid & 15;
    const int qby = qty * 16, qbx = qtx * 32;

    v4f acc[8 * COC / 4];
#pragma unroll
    for (int g = 0; g < COC / 4; ++g) {
        v4f bv;
#pragma unroll
        for (int e = 0; e < 4; ++e)
            bv[e] = (cobase + 4 * g + e < COUTR) ? bias[cobase + 4 * g + e] : 0.f;
#pragma unroll
        for (int pt = 0; pt < 8; ++pt) acc[pt * (COC / 4) + g] = bv;
    }

    const size_t plane = (size_t)Hin * Win;
    const float* ip0 = in + (size_t)n * CIN * plane;
    const float* wp0 = wp + cobase;

    for (int ci0 = 0; ci0 < CIN; ci0 += CB) {
        __syncthreads();
        for (int idx = tid; idx < CB * RH * RW; idx += 256) {
            int ci = idx / (RH * RW), rem = idx - ci * (RH * RW);
            int rr = rem / RW, cc = rem - rr * RW;
            int gy = qby + rr, gx = qbx + cc;
            float v = 0.f;
            if (gy < Hin && gx < Win)
                v = ip0[(size_t)(ci0 + ci) * plane + (size_t)gy * Win + gx];
            smIn[idx] = v;
        }
        for (int idx = tid; idx < CB * 9 * COC; idx += 256) {
            int q2 = idx / COC, co = idx % COC;
            smW[idx] = wp0[((size_t)ci0 * 9 + q2) * COUTP + co];
        }
        __syncthreads();

#pragma unroll 1
        for (int ci = 0; ci < CB; ++ci) {
            float p[6];
            const float* sp = &smIn[ci * RH * RW + tqy * RW + 2 * tqx];
#pragma unroll
            for (int i = 0; i < 2; ++i)
#pragma unroll
                for (int j = 0; j < 3; ++j)
                    p[i * 3 + j] = sp[i * RW + j];
            const float* wrow = &smW[ci * 9 * COC];
#pragma unroll
            for (int k = 0; k < 9; ++k) {
                const int ky = k / 3, kx = k % 3;
                const int dy = (ky == 1) ? 0 : 1, iy = (ky == 0) ? 1 : 0;
                const int dx = (kx == 1) ? 0 : 1, ix = (kx == 0) ? 1 : 0;
#pragma unroll
                for (int g = 0; g < COC / 4; ++g) {
                    v4f wv = *(const v4f*)&wrow[k * COC + 4 * g];
                    fma4(acc[(0 + dy * 2 + dx) * (COC / 4) + g], p[iy * 3 + ix],     wv);
                    fma4(acc[(4 + dy * 2 + dx) * (COC / 4) + g], p[iy * 3 + ix + 1], wv);
                }
            }
        }
    }

    const size_t oPlane = (size_t)(Hin * 2) * Wout;
    const int oy = 2 * (qby + tqy), ox = 2 * (qbx + 2 * tqx);
#pragma unroll
    for (int g = 0; g < COC / 4; ++g)
#pragma unroll
        for (int e = 0; e < 4; ++e) {
            int cch = cobase + 4 * g + e;
            if (cch >= COUTR) break;
            float* op = out + ((size_t)n * COUTR + cch) * oPlane + (size_t)oy * Wout + ox;
#pragma unroll
            for (int a2 = 0; a2 < 2; ++a2) {
                float u0 = acc[(0 + a2 * 2 + 0) * (COC / 4) + g][e];
                float u1 = acc[(0 + a2 * 2 + 1) * (COC / 4) + g][e];
                float u2 = acc[(4 + a2 * 2 + 0) * (COC / 4) + g][e];
                float u3 = acc[(4 + a2 * 2 + 1) * (COC / 4) + g][e];
                if (RELU) { u0 = fmaxf(u0, 0.f); u1 = fmaxf(u1, 0.f);
                            u2 = fmaxf(u2, 0.f); u3 = fmaxf(u3, 0.f); }
                *(float4*)&op[(size_t)a2 * Wout] = make_float4(u0, u1, u2, u3);
            }
        }
}

// ===================== 1x1 conv stride S — 1 pos/thread, 32 co ==============
template<int CIN, int S, bool RELU, bool CLIN, bool CLOUT>
__launch_bounds__(256, 4)
__global__ void conv1x1_k(const float* __restrict__ in, const float* __restrict__ w,
                          const float* __restrict__ bias, float* __restrict__ out,
                          int COUT, int Hin, int Win, int Hout, int Wout)
{
    constexpr int COC = 32;
    __shared__ float smW[CIN * COC];
    const int tid = threadIdx.x;
    int b = blockIdx.x;
    const int chunks = COUT / COC;
    const int spB = (Hout * Wout) / 256;
    const int ch = b % chunks; b /= chunks;
    const int sb = b % spB; const int n = b / spB;
    const int cobase = ch * COC;

    for (int idx = tid; idx < CIN * COC; idx += 256) {
        int ci = idx / COC, co = idx - ci * COC;
        smW[idx] = w[(size_t)(cobase + co) * CIN + ci];
    }
    __syncthreads();

    const int pos = sb * 256 + tid;
    const int oy = pos / Wout, ox = pos - oy * Wout;

    v4f acc[8];
#pragma unroll
    for (int g = 0; g < 8; ++g) acc[g] = *(const v4f*)&bias[cobase + 4 * g];

    if (CLIN) {
        const float* ip = in + (((size_t)n * Hin + oy * S) * Win + ox * S) * CIN;
#pragma unroll 1
        for (int c4 = 0; c4 < CIN / 4; ++c4) {
            v4f v = *(const v4f*)&ip[c4 * 4];
#pragma unroll
            for (int e = 0; e < 4; ++e)
#pragma unroll
                for (int g = 0; g < 8; ++g)
                    fma4(acc[g], v[e], *(const v4f*)&smW[(c4 * 4 + e) * COC + 4 * g]);
        }
    } else {
        const size_t inPlane = (size_t)Hin * Win;
        const float* ip = in + (size_t)n * CIN * inPlane + (size_t)(oy * S) * Win + (size_t)(ox * S);
#pragma unroll 1
        for (int ci = 0; ci < CIN; ++ci) {
            float v = ip[(size_t)ci * inPlane];
#pragma unroll
            for (int g = 0; g < 8; ++g)
                fma4(acc[g], v, *(const v4f*)&smW[ci * COC + 4 * g]);
        }
    }
    const size_t outPlane = (size_t)Hout * Wout;
    if (CLOUT) {
        size_t cb2 = ((size_t)n * outPlane + pos) * COUT + cobase;
#pragma unroll
        for (int g = 0; g < 8; ++g) {
            v4f v = acc[g];
            if (RELU) {
#pragma unroll
                for (int e = 0; e < 4; ++e) v[e] = fmaxf(v[e], 0.f);
            }
            *(v4f*)&out[cb2 + 4 * g] = v;
        }
    } else {
        float* op = out + ((size_t)n * COUT + cobase) * outPlane + pos;
#pragma unroll
        for (int g = 0; g < 8; ++g)
#pragma unroll
            for (int e = 0; e < 4; ++e) {
                float v = acc[g][e];
                if (RELU) v = fmaxf(v, 0.f);
                op[(size_t)(4 * g + e) * outPlane] = v;
            }
    }
}

// ==================== MFMA quantize (argmin distance GEMM) ==================
// Input S2 channels-last [pos][64]; output Q channels-last [pos][64].
__launch_bounds__(256, 4)
__global__ void mquant_k(const float* __restrict__ h, const _Float16* __restrict__ QB,
                         const float* __restrict__ cn, const float* __restrict__ cb,
                         float* __restrict__ q)
{
    __shared__ __align__(16) _Float16 AF[2][8192];   // [hl][((mt*2+s)*64+lane)*8+j]
    __shared__ float cns[512];
    __shared__ int bidxs[128];

    const int tid = threadIdx.x;
    const int lane = tid & 63;
    const int wv = tid >> 6;
    const int n16 = lane & 15, qq = lane >> 4;

    const int n = blockIdx.x >> 5;
    const int rem0 = (blockIdx.x & 31) << 7;

    for (int u = tid; u < 1024; u += 256) {
        int posL = u >> 3, grp = u & 7;
        const float* gp = h + ((size_t)n * 4096 + rem0 + posL) * 64 + grp * 8;
        float4 v0 = *(const float4*)gp;
        float4 v1 = *(const float4*)(gp + 4);
        f16x8 hh, ll;
        hh[0] = (_Float16)v0.x; ll[0] = (_Float16)(v0.x - (float)hh[0]);
        hh[1] = (_Float16)v0.y; ll[1] = (_Float16)(v0.y - (float)hh[1]);
        hh[2] = (_Float16)v0.z; ll[2] = (_Float16)(v0.z - (float)hh[2]);
        hh[3] = (_Float16)v0.w; ll[3] = (_Float16)(v0.w - (float)hh[3]);
        hh[4] = (_Float16)v1.x; ll[4] = (_Float16)(v1.x - (float)hh[4]);
        hh[5] = (_Float16)v1.y; ll[5] = (_Float16)(v1.y - (float)hh[5]);
        hh[6] = (_Float16)v1.z; ll[6] = (_Float16)(v1.z - (float)hh[6]);
        hh[7] = (_Float16)v1.w; ll[7] = (_Float16)(v1.w - (float)hh[7]);
        int mt = posL >> 4, s = grp >> 2, qv = grp & 3;
        int a = ((mt * 2 + s) * 64 + (posL & 15) + qv * 16) * 8;
        *(f16x8*)&AF[0][a] = hh;
        *(f16x8*)&AF[1][a] = ll;
    }
    for (int u = tid; u < 512; u += 256) cns[u] = cn[u];
    __syncthreads();

    f16x8 aH[2][2], aL[2][2];
#pragma unroll
    for (int m = 0; m < 2; ++m)
#pragma unroll
        for (int s = 0; s < 2; ++s) {
            int a = (((wv * 2 + m) * 2 + s) * 64 + lane) * 8;
            aH[m][s] = *(const f16x8*)&AF[0][a];
            aL[m][s] = *(const f16x8*)&AF[1][a];
        }

    float best[2][4]; int bi[2][4];
#pragma unroll
    for (int m = 0; m < 2; ++m)
#pragma unroll
        for (int r = 0; r < 4; ++r) { best[m][r] = 3.4e38f; bi[m][r] = 0; }

    const uint4* qbp = (const uint4*)QB;
#pragma unroll 1
    for (int nt = 0; nt < 32; ++nt) {
        uint4 rH0 = qbp[((nt * 2 + 0) * 2 + 0) * 64 + lane];
        uint4 rL0 = qbp[((nt * 2 + 0) * 2 + 1) * 64 + lane];
        uint4 rH1 = qbp[((nt * 2 + 1) * 2 + 0) * 64 + lane];
        uint4 rL1 = qbp[((nt * 2 + 1) * 2 + 1) * 64 + lane];
        f16x8 bH0 = *(const f16x8*)&rH0;
        f16x8 bL0 = *(const f16x8*)&rL0;
        f16x8 bH1 = *(const f16x8*)&rH1;
        f16x8 bL1 = *(const f16x8*)&rL1;
        float cnv = cns[nt * 16 + n16];
        const int code = nt * 16 + n16;
#pragma unroll
        for (int m = 0; m < 2; ++m) {
            v4f acc = {0.f, 0.f, 0.f, 0.f};
            acc = __builtin_amdgcn_mfma_f32_16x16x32_f16(aH[m][0], bH0, acc, 0, 0, 0);
            acc = __builtin_amdgcn_mfma_f32_16x16x32_f16(aL[m][0], bH0, acc, 0, 0, 0);
            acc = __builtin_amdgcn_mfma_f32_16x16x32_f16(aH[m][0], bL0, acc, 0, 0, 0);
            acc = __builtin_amdgcn_mfma_f32_16x16x32_f16(aH[m][1], bH1, acc, 0, 0, 0);
            acc = __builtin_amdgcn_mfma_f32_16x16x32_f16(aL[m][1], bH1, acc, 0, 0, 0);
            acc = __builtin_amdgcn_mfma_f32_16x16x32_f16(aH[m][1], bL1, acc, 0, 0, 0);
#pragma unroll
            for (int r = 0; r < 4; ++r) {
                float d = fmaf(-2.f, acc[r], cnv);
                if (d < best[m][r]) { best[m][r] = d; bi[m][r] = code; }
            }
        }
    }

    // reduce across the 16 lane-columns; first-min tie-break (lowest index)
#pragma unroll
    for (int m = 0; m < 2; ++m)
#pragma unroll
        for (int r = 0; r < 4; ++r) {
#pragma unroll
            for (int msk = 1; msk < 16; msk <<= 1) {
                float ob = __shfl_xor(best[m][r], msk);
                int oi = __shfl_xor(bi[m][r], msk);
                if (ob < best[m][r] || (ob == best[m][r] && oi < bi[m][r])) {
                    best[m][r] = ob; bi[m][r] = oi;
                }
            }
            if (n16 == 0) bidxs[wv * 32 + m * 16 + qq * 4 + r] = bi[m][r];
        }
    __syncthreads();

    const int p = tid & 127, jh = tid >> 7;
    const int code = bidxs[p];
    const float4* crow4 = (const float4*)(cb + (size_t)code * 64);
    float4* qp4 = (float4*)(q + ((size_t)n * 4096 + rem0 + p) * 64);
#pragma unroll
    for (int k = 0; k < 8; ++k)
        qp4[jh * 8 + k] = crow4[jh * 8 + k];
}

extern "C" void kernel_launch(void* const* d_in, const int* in_sizes, int n_in,
                              void* d_out, int out_size, void* d_ws, size_t ws_size,
                              hipStream_t stream)
{
    const float* x    = (const float*)d_in[0];
    const float* e0w1 = (const float*)d_in[1];  const float* e0b1 = (const float*)d_in[2];
    const float* e0w2 = (const float*)d_in[3];  const float* e0b2 = (const float*)d_in[4];
    const float* e0wd = (const float*)d_in[5];  const float* e0bd = (const float*)d_in[6];
    const float* e1w1 = (const float*)d_in[7];  const float* e1b1 = (const float*)d_in[8];
    const float* e1w2 = (const float*)d_in[9];  const float* e1b2 = (const float*)d_in[10];
    const float* e1wd = (const float*)d_in[11]; const float* e1bd = (const float*)d_in[12];
    const float* e2w1 = (const float*)d_in[13]; const float* e2b1 = (const float*)d_in[14];
    const float* e2w2 = (const float*)d_in[15]; const float* e2b2 = (const float*)d_in[16];
    const float* e2wd = (const float*)d_in[17]; const float* e2bd = (const float*)d_in[18];
    const float* d0w  = (const float*)d_in[19]; const float* d0b  = (const float*)d_in[20];
    const float* d1w  = (const float*)d_in[21]; const float* d1b  = (const float*)d_in[22];
    const float* d2w  = (const float*)d_in[23]; const float* d2b  = (const float*)d_in[24];
    const float* cb   = (const float*)d_in[25];
    float* out = (float*)d_out;
    float* ws  = (float*)d_ws;

    // ---- packs in d_out slack (d_out only written by the final dec2) ----
    float* P_e0w1 = out + 0;            // fp32 pack, 1728
    _Float16* Bh_d1   = (_Float16*)(out + 1728);     // 73728 halves
    _Float16* Bl_d1   = (_Float16*)(out + 38592);    // 73728 halves
    _Float16* Bh_e0c2 = (_Float16*)(out + 77760);
    _Float16* Bl_e0c2 = (_Float16*)(out + 96192);
    _Float16* Bh_e1c2 = (_Float16*)(out + 114624);
    _Float16* Bl_e1c2 = (_Float16*)(out + 188352);
    _Float16* Bh_e2c1 = (_Float16*)(out + 262080);
    _Float16* Bl_e2c1 = (_Float16*)(out + 298944);
    _Float16* Bh_e2c2 = (_Float16*)(out + 335808);
    _Float16* Bl_e2c2 = (_Float16*)(out + 354240);
    _Float16* Bh_d0   = (_Float16*)(out + 372672);
    _Float16* Bl_d0   = (_Float16*)(out + 409536);
    _Float16* Bh_e1c1 = (_Float16*)(out + 446400);   // 73728 halves
    _Float16* Bl_e1c1 = (_Float16*)(out + 483264);   // 73728 halves
    _Float16* QB = (_Float16*)(out + 520128);
    float* CN = out + 552896;
    float* P_d2w  = ws + 50405376;      // fp32 pack; written after S1 is dead

    // ---- ws activation layout (floats), liveness-planned ----
    // ALL activations channels-last except x (input) and D1.
    float* S0 = ws;                     // CL [n][128][128][64], enc0 out
    float* T1 = ws + 33554432;          // CL, enc0 conv1 out
    float* T3 = ws + 33554432;          // CL, enc1 conv1 out
    float* S1 = ws + 50331648;          // CL [n][64][64][128], enc1 out
    float* S2 = ws;                     // CL, enc2 out
    float* T5 = ws + 8388608;           // CL
    float* Q  = ws + 16777216;          // CL
    float* D0 = ws + 33554432;          // CL, dec0 out
    float* D1 = ws;                     // NCHW, dec1 out

    dim3 blk(256);
    auto rp = [&](const float* src, float* dst, int cout, int coutR, int cin, int flip, int dec) {
        int tot = cin * 9 * cout;
        repack_k<<<dim3((tot + 255) / 256), blk, 0, stream>>>(src, dst, cout, coutR, cin, flip, dec);
    };
    auto rpB = [&](const float* src, _Float16* bh, _Float16* bl, int cout, int cin, int dec) {
        int tot = 9 * cin * cout;
        repackB16_k<<<dim3((tot + 255) / 256), blk, 0, stream>>>(src, bh, bl, cout, cin, dec);
    };

    rp(e0w1, P_e0w1, 64, 64, 3, 0, 0);
    rpB(e0w2, Bh_e0c2, Bl_e0c2, 64, 64, 0);
    rpB(e1w1, Bh_e1c1, Bl_e1c1, 128, 64, 0);
    rpB(e1w2, Bh_e1c2, Bl_e1c2, 128, 128, 0);
    rpB(e2w1, Bh_e2c1, Bl_e2c1, 64, 128, 0);
    rpB(e2w2, Bh_e2c2, Bl_e2c2, 64, 64, 0);
    rpB(d0w,  Bh_d0,   Bl_d0,   128, 64, 1);   // ConvT s1 == flipped conv
    rpB(d1w,  Bh_d1,   Bl_d1,   64, 128, 1);   // ConvT s2, flipped-tap pack
    repackQ_k<<<dim3(256), blk, 0, stream>>>(cb, QB);
    cbnorm_k<<<dim3(2), blk, 0, stream>>>(cb, CN);

    // --- enc0 (3 -> 64, s2): 256 -> 128 ---
    conv1x1_k<3, 2, false, false, true><<<dim3(32 * 64 * 2), blk, 0, stream>>>(
        x, e0wd, e0bd, S0, 64, 256, 256, 128, 128);
    conv3s2_k<3, 3, true><<<dim3(32 * 8 * 4 * 2), blk, 0, stream>>>(
        x, P_e0w1, e0b1, T1, 64, 256, 256);
    mconv3s1_k<64, true, 2, true, true><<<dim3(32 * 8 * 8 * 1), blk, 0, stream>>>(
        T1, Bh_e0c2, Bl_e0c2, e0b2, S0, S0, 64, 128, 128);

    // --- enc1 (64 -> 128, s2): 128 -> 64 ---
    conv1x1_k<64, 2, false, true, true><<<dim3(32 * 16 * 4), blk, 0, stream>>>(
        S0, e1wd, e1bd, S1, 128, 128, 128, 64, 64);
    mconv3s2_k<64, 8, true><<<dim3(32 * 16 * 4), blk, 0, stream>>>(
        S0, Bh_e1c1, Bl_e1c1, e1b1, T3, 128, 128, 128);
    mconv3s1_k<128, true, 2, true, true><<<dim3(32 * 4 * 4 * 2), blk, 0, stream>>>(
        T3, Bh_e1c2, Bl_e1c2, e1b2, S1, S1, 128, 64, 64);

    // --- enc2 (128 -> 64, s1) ---
    conv1x1_k<128, 1, false, true, true><<<dim3(32 * 16 * 2), blk, 0, stream>>>(
        S1, e2wd, e2bd, S2, 64, 64, 64, 64, 64);
    mconv3s1_k<128, true, 0, true, true><<<dim3(32 * 4 * 4 * 1), blk, 0, stream>>>(
        S1, Bh_e2c1, Bl_e2c1, e2b1, T5, nullptr, 64, 64, 64);
    rp(d2w, P_d2w, 4, 3, 64, 0, 1);             // S1 dead after the two reads above
    mconv3s1_k<64, true, 2, true, true><<<dim3(32 * 4 * 4 * 1), blk, 0, stream>>>(
        T5, Bh_e2c2, Bl_e2c2, e2b2, S2, S2, 64, 64, 64);

    // --- quantize (MFMA argmin), CL in/out ---
    mquant_k<<<dim3(1024), blk, 0, stream>>>(S2, QB, CN, cb, Q);

    // --- dec0: ConvT s1 (64 -> 128) as flipped conv, ReLU, CL in/out ---
    mconv3s1_k<64, true, 0, true, true><<<dim3(32 * 4 * 4 * 2), blk, 0, stream>>>(
        Q, Bh_d0, Bl_d0, d0b, D0, nullptr, 128, 64, 64);

    // --- dec1: ConvT s2 (128 -> 64), ReLU: 64 -> 128 (MFMA, 4-phase, CL in) ---
    mdeconv2_k<128, true><<<dim3(32 * 16 * 4), blk, 0, stream>>>(
        D0, Bh_d1, Bl_d1, d1b, D1, 64, 64, 64);

    // --- dec2: ConvT s2 (64 -> 3): 128 -> 256 ---
    deconv2_k<64, 8, 4, false><<<dim3(32 * 4 * 8), blk, 0, stream>>>(
        D1, P_d2w, d2b, out, 3, 4, 128, 128);
}

// Round 9
// 1452.510 us; speedup vs baseline: 1.2542x; 1.0863x over previous
//
#include <hip/hip_runtime.h>
#include <cstddef>

// ---------------------------------------------------------------------------
// VQ-VAE forward. Round 15: revert to R12 structure (best: 1510us) — R13/R14
// both regressed (direct-global B missed L1; reg-prefetch spilled to scratch,
// +170MB writes). Single low-risk addition: T5 s_setprio(1) around MFMA
// clusters (phase diversity exists: 2-3 independent blocks/CU).
// ---------------------------------------------------------------------------

typedef float v4f __attribute__((ext_vector_type(4)));
typedef _Float16 f16x8 __attribute__((ext_vector_type(8)));
typedef _Float16 f16x4 __attribute__((ext_vector_type(4)));

__device__ __forceinline__ void fma4(v4f& a, float p, const v4f& w) {
    a.x = fmaf(p, w.x, a.x); a.y = fmaf(p, w.y, a.y);
    a.z = fmaf(p, w.z, a.z); a.w = fmaf(p, w.w, a.w);
}

// Repack conv/deconv weights to fp32 [ci][9][cout] (for fp32 kernels).
__global__ void repack_k(const float* __restrict__ src, float* __restrict__ dst,
                         int cout, int coutR, int cin, int flip, int deconv)
{
    int t = blockIdx.x * 256 + threadIdx.x;
    int tot = cin * 9 * cout;
    if (t >= tot) return;
    int co = t % cout; int k = (t / cout) % 9; int ci = t / (9 * cout);
    float v = 0.f;
    if (co < coutR) {
        int ks = flip ? 8 - k : k;
        v = deconv ? src[((size_t)ci * coutR + co) * 9 + ks]
                   : src[((size_t)co * cin + ci) * 9 + ks];
    }
    dst[t] = v;
}

// Prepack weights to fp16 hi/lo MFMA B-fragment order.
__global__ void repackB16_k(const float* __restrict__ src, _Float16* __restrict__ bh,
                            _Float16* __restrict__ bl, int COUT, int CIN, int deconv)
{
    int t = blockIdx.x * 256 + threadIdx.x;
    int tot = 9 * CIN * COUT;
    if (t >= tot) return;
    int NGtot = COUT >> 4, C32 = CIN >> 5;
    int j = t & 7;
    int lane = (t >> 3) & 63;
    int blk = t >> 9;
    int ng = blk % NGtot; blk /= NGtot;
    int c32 = blk % C32;
    int tap = blk / C32;
    int co = ng * 16 + (lane & 15);
    int ci = c32 * 32 + ((lane >> 4) & 3) * 8 + j;
    float v = deconv ? src[((size_t)ci * COUT + co) * 9 + (8 - tap)]
                     : src[((size_t)co * CIN + ci) * 9 + tap];
    _Float16 h = (_Float16)v;
    _Float16 l = (_Float16)(v - (float)h);
    bh[t] = h; bl[t] = l;
}

// Pack codebook (512 x 64) to fp16 hi/lo B-fragment order.
__global__ void repackQ_k(const float* __restrict__ cb, _Float16* __restrict__ qb)
{
    int t = blockIdx.x * 256 + threadIdx.x;
    if (t >= 65536) return;
    int j = t & 7;
    int lane = (t >> 3) & 63;
    int hl = (t >> 9) & 1;
    int s = (t >> 10) & 1;
    int nt = t >> 11;
    int code = nt * 16 + (lane & 15);
    int ci = s * 32 + ((lane >> 4) & 3) * 8 + j;
    float v = cb[(size_t)code * 64 + ci];
    _Float16 h = (_Float16)v;
    qb[t] = hl ? (_Float16)(v - (float)h) : h;
}

// Codebook squared norms.
__global__ void cbnorm_k(const float* __restrict__ cb, float* __restrict__ cn)
{
    int i = blockIdx.x * 256 + threadIdx.x;
    if (i >= 512) return;
    float s = 0.f;
#pragma unroll
    for (int j = 0; j < 64; ++j) { float v = cb[i * 64 + j]; s = fmaf(v, v, s); }
    cn[i] = s;
}

// ================= MFMA 3x3 conv s1 p1 (fp16 hi/lo split) ===================
// Block: 256 positions (16x16) x 64 co. Wave: 4 rows x 64 co.
// ADDMODE: 0 none, 1 NCHW addend, 2 channels-last addend.
// CLIN: input is [n][H][W][CIN] fp32; CLOUT: output is [n][H][W][COUT].
template<int CIN, bool RELU, int ADDMODE, bool CLIN, bool CLOUT>
__launch_bounds__(256, 2)
__global__ void mconv3s1_k(const float* __restrict__ in,
                           const _Float16* __restrict__ Bh, const _Float16* __restrict__ Bl,
                           const float* __restrict__ bias, float* __restrict__ out,
                           const float* __restrict__ addend,
                           int COUT, int H, int W)
{
    constexpr int C32 = CIN / 32;
    __shared__ __align__(16) unsigned char smBuf[76416];
    _Float16* AH = (_Float16*)smBuf;        // [18][18][40] = 12960 halves
    _Float16* AL = AH + 12960;              // 12960
    _Float16* BW = AL + 12960;              // [tapL3][ng4][hl2][lane64][8] = 12288
    float* smO = (float*)smBuf;             // [64][257] epilogue overlay (65784 B)

    const int tid = threadIdx.x;
    const int lane = tid & 63, yb = tid >> 6;
    const int n16 = lane & 15, q = lane >> 4;

    int b = blockIdx.x;
    const int chunks = COUT >> 6;
    const int coch = b % chunks; b /= chunks;
    const int tX = W >> 4; const int tx = b % tX; b /= tX;
    const int tY = H >> 4; const int ty = b % tY; const int n = b / tY;
    const int x0 = tx * 16, y0 = ty * 16;
    const int NGtot = COUT >> 4;
    const int ngbase = coch * 4, cobase = coch * 64;

    v4f acc[4][4];
#pragma unroll
    for (int ng = 0; ng < 4; ++ng) {
        float bb = bias[cobase + ng * 16 + n16];
        v4f bv = {bb, bb, bb, bb};
#pragma unroll
        for (int mg = 0; mg < 4; ++mg) acc[mg][ng] = bv;
    }

    for (int c32 = 0; c32 < C32; ++c32) {
        __syncthreads();
        if (CLIN) {
            // ---- stage A from channels-last: float4 loads, b64 LDS writes ----
            for (int u = tid; u < 2592; u += 256) {
                int cell = u >> 3, f4 = u & 7;
                int yy = cell / 18, xx = cell - yy * 18;
                int gy = y0 - 1 + yy, gx = x0 - 1 + xx;
                float4 v = make_float4(0.f, 0.f, 0.f, 0.f);
                if (gy >= 0 && gy < H && gx >= 0 && gx < W)
                    v = *(const float4*)&in[(((size_t)n * H + gy) * W + gx) * CIN + c32 * 32 + f4 * 4];
                f16x4 h4, l4;
                h4[0] = (_Float16)v.x; l4[0] = (_Float16)(v.x - (float)h4[0]);
                h4[1] = (_Float16)v.y; l4[1] = (_Float16)(v.y - (float)h4[1]);
                h4[2] = (_Float16)v.z; l4[2] = (_Float16)(v.z - (float)h4[2]);
                h4[3] = (_Float16)v.w; l4[3] = (_Float16)(v.w - (float)h4[3]);
                int a = (yy * 18 + xx) * 40 + f4 * 4;
                *(f16x4*)&AH[a] = h4; *(f16x4*)&AL[a] = l4;
            }
        } else {
            // ---- stage A from NCHW: scalar gather ----
            for (int u = tid; u < 10368; u += 256) {
                int ci = u / 324, rem = u - ci * 324;
                int yy = rem / 18, xx = rem - yy * 18;
                int gy = y0 - 1 + yy, gx = x0 - 1 + xx;
                float v = 0.f;
                if (gy >= 0 && gy < H && gx >= 0 && gx < W)
                    v = in[(((size_t)n * CIN + c32 * 32 + ci) * H + gy) * W + gx];
                _Float16 h = (_Float16)v;
                _Float16 l = (_Float16)(v - (float)h);
                int a = (yy * 18 + xx) * 40 + ci;
                AH[a] = h; AL[a] = l;
            }
        }
        for (int ky = 0; ky < 3; ++ky) {
            __syncthreads();
            // ---- stage B row: 3 taps x 4 ng x hi/lo, 1536 x 16B ----
            for (int u = tid; u < 1536; u += 256) {
                int lu = u & 63;
                int rest = u >> 6;
                int hl = rest & 1; rest >>= 1;
                int ng = rest & 3;
                int tapL = rest >> 2;
                const uint4* srcp = (const uint4*)(hl ? Bl : Bh);
                size_t sidx = (((size_t)(ky * 3 + tapL) * C32 + c32) * NGtot + ngbase + ng) * 64 + lu;
                ((uint4*)BW)[u] = srcp[sidx];
            }
            __syncthreads();
#pragma unroll
            for (int kx = 0; kx < 3; ++kx) {
                f16x8 aH[4], aL[4];
#pragma unroll
                for (int mg = 0; mg < 4; ++mg) {
                    int aoff = ((4 * yb + mg + ky) * 18 + n16 + kx) * 40 + q * 8;
                    aH[mg] = *(const f16x8*)&AH[aoff];
                    aL[mg] = *(const f16x8*)&AL[aoff];
                }
                __builtin_amdgcn_s_setprio(1);
#pragma unroll
                for (int ng = 0; ng < 4; ++ng) {
                    int boff = ((kx * 4 + ng) * 2) * 512 + lane * 8;
                    f16x8 bH = *(const f16x8*)&BW[boff];
                    f16x8 bL = *(const f16x8*)&BW[boff + 512];
#pragma unroll
                    for (int mg = 0; mg < 4; ++mg) {
                        acc[mg][ng] = __builtin_amdgcn_mfma_f32_16x16x32_f16(aH[mg], bH, acc[mg][ng], 0, 0, 0);
                        acc[mg][ng] = __builtin_amdgcn_mfma_f32_16x16x32_f16(aL[mg], bH, acc[mg][ng], 0, 0, 0);
                        acc[mg][ng] = __builtin_amdgcn_mfma_f32_16x16x32_f16(aH[mg], bL, acc[mg][ng], 0, 0, 0);
                    }
                }
                __builtin_amdgcn_s_setprio(0);
            }
        }
    }

    // ---- epilogue: LDS transpose -> coalesced stores ----
    __syncthreads();
#pragma unroll
    for (int mg = 0; mg < 4; ++mg)
#pragma unroll
        for (int ng = 0; ng < 4; ++ng) {
            int p = (4 * yb + mg) * 16 + q * 4;
            int co = ng * 16 + n16;
#pragma unroll
            for (int r = 0; r < 4; ++r)
                smO[co * 257 + p + r] = acc[mg][ng][r];
        }
    __syncthreads();
    if (CLOUT) {
        const int p = tid;
        const int py = p >> 4, px = p & 15;
        size_t cellBase = (((size_t)n * H + (y0 + py)) * W + (x0 + px)) * COUT + cobase;
        float* cellp = out + cellBase;
        const float* acell = (ADDMODE == 2) ? addend + cellBase : nullptr;
#pragma unroll
        for (int g = 0; g < 16; ++g) {
            float4 v;
            v.x = smO[(4 * g + 0) * 257 + p];
            v.y = smO[(4 * g + 1) * 257 + p];
            v.z = smO[(4 * g + 2) * 257 + p];
            v.w = smO[(4 * g + 3) * 257 + p];
            if (ADDMODE == 2) {
                float4 a4 = *(const float4*)&acell[4 * g];
                v.x += a4.x; v.y += a4.y; v.z += a4.z; v.w += a4.w;
            }
            if (RELU) {
                v.x = fmaxf(v.x, 0.f); v.y = fmaxf(v.y, 0.f);
                v.z = fmaxf(v.z, 0.f); v.w = fmaxf(v.w, 0.f);
            }
            *(float4*)&cellp[4 * g] = v;
        }
    } else {
        const size_t plane = (size_t)H * W;
        float* ob = out + ((size_t)n * COUT + cobase) * plane;
        const float* ab = (ADDMODE == 1) ? addend + ((size_t)n * COUT + cobase) * plane : nullptr;
#pragma unroll
        for (int k = 0; k < 64; ++k) {
            int e = tid + 256 * k;
            int co = e >> 8, p = e & 255;
            int py = p >> 4, px = p & 15;
            size_t g = (size_t)co * plane + (size_t)(y0 + py) * W + x0 + px;
            float v = smO[co * 257 + p];
            if (ADDMODE == 1) v += ab[g];
            if (RELU) v = fmaxf(v, 0.f);
            ob[g] = v;
        }
    }
}

// ============== MFMA 3x3 conv s2 p1 (fp16 hi/lo split) ======================
// Input channels-last [n][Hin][Win][CIN]; output channels-last.
// A-tile 9x33 halo, column-parity-split. B fragments loaded DIRECTLY from
// global (coalesced dwordx4, L1/L2-resident) — no B LDS, no per-tap barriers.
template<int CIN, int NG, bool RELU>
__launch_bounds__(256, 3)
__global__ void mconv3s2_k(const float* __restrict__ in,
                           const _Float16* __restrict__ Bh, const _Float16* __restrict__ Bl,
                           const float* __restrict__ bias, float* __restrict__ out,
                           int COUT, int Hin, int Win)
{
    constexpr int C32 = CIN / 32;
    constexpr int ASZ = 9 * 2 * 17 * 40;        // 12240 halves per H/L
    __shared__ __align__(16) unsigned char smBuf[2 * ASZ * 2];   // 48960 B
    _Float16* AH = (_Float16*)smBuf;
    _Float16* AL = AH + ASZ;
    float* smO = (float*)smBuf;                 // [NG*16][65] overlay (33280 B)

    const int tid = threadIdx.x;
    const int lane = tid & 63, yb = tid >> 6;
    const int n16 = lane & 15, q = lane >> 4;

    const int Hout = Hin >> 1, Wout = Win >> 1;
    int b = blockIdx.x;
    const int chunks = COUT / (NG * 16);
    const int coch = b % chunks; b /= chunks;
    const int tX = Wout >> 4; const int tx = b % tX; b /= tX;
    const int tY = Hout >> 2; const int ty = b % tY; const int n = b / tY;
    const int x0 = tx * 16, y0 = ty * 4;
    const int gx0 = 2 * x0 - 1, gy0 = 2 * y0 - 1;
    const int NGtot = COUT >> 4;
    const int ngbase = coch * NG, cobase = coch * NG * 16;

    v4f acc[NG];
#pragma unroll
    for (int ng = 0; ng < NG; ++ng) {
        float bb = bias[cobase + ng * 16 + n16];
        v4f bv = {bb, bb, bb, bb};
        acc[ng] = bv;
    }

    const uint4* bhp = (const uint4*)Bh;
    const uint4* blp = (const uint4*)Bl;

    for (int c32 = 0; c32 < C32; ++c32) {
        __syncthreads();
        // ---- stage A from CL: 297 cells x 8 float4, parity-split columns ----
        for (int u = tid; u < 2376; u += 256) {
            int cell = u >> 3, f4 = u & 7;
            int yy = cell / 33, xx = cell - yy * 33;
            int gy = gy0 + yy, gx = gx0 + xx;
            float4 v = make_float4(0.f, 0.f, 0.f, 0.f);
            if (gy >= 0 && gy < Hin && gx >= 0 && gx < Win)
                v = *(const float4*)&in[(((size_t)n * Hin + gy) * Win + gx) * CIN + c32 * 32 + f4 * 4];
            f16x4 h4, l4;
            h4[0] = (_Float16)v.x; l4[0] = (_Float16)(v.x - (float)h4[0]);
            h4[1] = (_Float16)v.y; l4[1] = (_Float16)(v.y - (float)h4[1]);
            h4[2] = (_Float16)v.z; l4[2] = (_Float16)(v.z - (float)h4[2]);
            h4[3] = (_Float16)v.w; l4[3] = (_Float16)(v.w - (float)h4[3]);
            int a = ((yy * 2 + (xx & 1)) * 17 + (xx >> 1)) * 40 + f4 * 4;
            *(f16x4*)&AH[a] = h4; *(f16x4*)&AL[a] = l4;
        }
        __syncthreads();
#pragma unroll
        for (int ky = 0; ky < 3; ++ky) {
#pragma unroll
            for (int kx = 0; kx < 3; ++kx) {
                const int par = kx & 1, xs = kx >> 1;
                int aoff = (((2 * yb + ky) * 2 + par) * 17 + n16 + xs) * 40 + q * 8;
                f16x8 aH = *(const f16x8*)&AH[aoff];
                f16x8 aL = *(const f16x8*)&AL[aoff];
                size_t sb0 = (((size_t)(ky * 3 + kx) * C32 + c32) * NGtot + ngbase) * 64 + lane;
                __builtin_amdgcn_s_setprio(1);
#pragma unroll
                for (int ng = 0; ng < NG; ++ng) {
                    uint4 rH = bhp[sb0 + (size_t)ng * 64];
                    uint4 rL = blp[sb0 + (size_t)ng * 64];
                    f16x8 bH = *(const f16x8*)&rH;
                    f16x8 bL = *(const f16x8*)&rL;
                    acc[ng] = __builtin_amdgcn_mfma_f32_16x16x32_f16(aH, bH, acc[ng], 0, 0, 0);
                    acc[ng] = __builtin_amdgcn_mfma_f32_16x16x32_f16(aL, bH, acc[ng], 0, 0, 0);
                    acc[ng] = __builtin_amdgcn_mfma_f32_16x16x32_f16(aH, bL, acc[ng], 0, 0, 0);
                }
                __builtin_amdgcn_s_setprio(0);
            }
        }
    }

    // ---- epilogue: LDS transpose -> channels-last float4 stores ----
    __syncthreads();
#pragma unroll
    for (int ng = 0; ng < NG; ++ng) {
        int co = ng * 16 + n16;
        int p = yb * 16 + q * 4;
#pragma unroll
        for (int r = 0; r < 4; ++r)
            smO[co * 65 + p + r] = acc[ng][r];
    }
    __syncthreads();
    const int p2 = tid >> 2, s2 = tid & 3;
    const int py = p2 >> 4, px = p2 & 15;
    float* cellp = out + ((((size_t)n * Hout + (y0 + py)) * Wout + (x0 + px)) * COUT + s2 * 32);
#pragma unroll
    for (int k = 0; k < 8; ++k) {
        float4 v;
        v.x = smO[(s2 * 32 + 4 * k + 0) * 65 + p2];
        v.y = smO[(s2 * 32 + 4 * k + 1) * 65 + p2];
        v.z = smO[(s2 * 32 + 4 * k + 2) * 65 + p2];
        v.w = smO[(s2 * 32 + 4 * k + 3) * 65 + p2];
        if (RELU) {
            v.x = fmaxf(v.x, 0.f); v.y = fmaxf(v.y, 0.f);
            v.z = fmaxf(v.z, 0.f); v.w = fmaxf(v.w, 0.f);
        }
        *(float4*)&cellp[4 * k] = v;
    }
}

// ======== MFMA ConvT k3 s2 p1 op1 (fp16 hi/lo), 4-phase decomposition =======
// Input D0 channels-last [n][Hin][Win][CIN]; output D1 NCHW.
template<int CIN, bool RELU>
__launch_bounds__(256, 3)
__global__ void mdeconv2_k(const float* __restrict__ in,
                           const _Float16* __restrict__ Bh, const _Float16* __restrict__ Bl,
                           const float* __restrict__ bias, float* __restrict__ out,
                           int COUT, int Hin, int Win)
{
    constexpr int C32 = CIN / 32;
    __shared__ __align__(16) unsigned char smBuf[38976];
    _Float16* AH = (_Float16*)smBuf;        // [5][18][40] = 3600 halves
    _Float16* AL = AH + 3600;               // 3600
    _Float16* BW = AL + 3600;               // [tapL3][ng4][hl2][lane64][8] = 12288
    float* smO = (float*)smBuf;             // [32][257] epilogue overlay = 32896B

    const int tid = threadIdx.x;
    const int lane = tid & 63, yb = tid >> 6;   // wave = one input row
    const int n16 = lane & 15, q = lane >> 4;

    int b = blockIdx.x;
    const int chunks = COUT >> 6;
    const int coch = b % chunks; b /= chunks;
    const int tX = Win >> 4; const int tx = b % tX; b /= tX;
    const int tY = Hin >> 2; const int ty = b % tY; const int n = b / tY;
    const int x0 = tx * 16, y0 = ty * 4;
    const int NGtot = COUT >> 4;
    const int ngbase = coch * 4, cobase = coch * 64;

    v4f acc[4][4];                              // [phase dy*2+dx][ng]
#pragma unroll
    for (int ng = 0; ng < 4; ++ng) {
        float bb = bias[cobase + ng * 16 + n16];
        v4f bv = {bb, bb, bb, bb};
#pragma unroll
        for (int ph = 0; ph < 4; ++ph) acc[ph][ng] = bv;
    }

    for (int c32 = 0; c32 < C32; ++c32) {
        __syncthreads();
        // ---- stage A (channels-last): 5 rows x 17 cols x 32 ci ----
        for (int u = tid; u < 680; u += 256) {
            int cell = u >> 3, f4 = u & 7;
            int yy = cell / 17, xx = cell - yy * 17;
            int gy = y0 + yy, gx = x0 + xx;
            float4 v = make_float4(0.f, 0.f, 0.f, 0.f);
            if (gy < Hin && gx < Win)
                v = *(const float4*)&in[(((size_t)n * Hin + gy) * Win + gx) * CIN + c32 * 32 + f4 * 4];
            f16x4 h4, l4;
            h4[0] = (_Float16)v.x; l4[0] = (_Float16)(v.x - (float)h4[0]);
            h4[1] = (_Float16)v.y; l4[1] = (_Float16)(v.y - (float)h4[1]);
            h4[2] = (_Float16)v.z; l4[2] = (_Float16)(v.z - (float)h4[2]);
            h4[3] = (_Float16)v.w; l4[3] = (_Float16)(v.w - (float)h4[3]);
            int a = (yy * 18 + xx) * 40 + f4 * 4;
            *(f16x4*)&AH[a] = h4; *(f16x4*)&AL[a] = l4;
        }
        for (int ky = 0; ky < 3; ++ky) {
            __syncthreads();
            // ---- stage B row: 3 taps x 4 ng x hi/lo, 1536 x 16B ----
            for (int u = tid; u < 1536; u += 256) {
                int lu = u & 63;
                int rest = u >> 6;
                int hl = rest & 1; rest >>= 1;
                int ng = rest & 3;
                int tapL = rest >> 2;
                const uint4* srcp = (const uint4*)(hl ? Bl : Bh);
                size_t sidx = (((size_t)(ky * 3 + tapL) * C32 + c32) * NGtot + ngbase + ng) * 64 + lu;
                ((uint4*)BW)[u] = srcp[sidx];
            }
            __syncthreads();
            const int iy = (ky == 2) ? 1 : 0;
            const int phy = (ky == 1) ? 0 : 2;
#pragma unroll
            for (int kx = 0; kx < 3; ++kx) {
                const int ix = (kx == 2) ? 1 : 0;
                const int ph = phy + ((kx == 1) ? 0 : 1);
                int aoff = ((yb + iy) * 18 + n16 + ix) * 40 + q * 8;
                f16x8 aH = *(const f16x8*)&AH[aoff];
                f16x8 aL = *(const f16x8*)&AL[aoff];
                __builtin_amdgcn_s_setprio(1);
#pragma unroll
                for (int ng = 0; ng < 4; ++ng) {
                    int boff = ((kx * 4 + ng) * 2) * 512 + lane * 8;
                    f16x8 bH = *(const f16x8*)&BW[boff];
                    f16x8 bL = *(const f16x8*)&BW[boff + 512];
                    acc[ph][ng] = __builtin_amdgcn_mfma_f32_16x16x32_f16(aH, bH, acc[ph][ng], 0, 0, 0);
                    acc[ph][ng] = __builtin_amdgcn_mfma_f32_16x16x32_f16(aL, bH, acc[ph][ng], 0, 0, 0);
                    acc[ph][ng] = __builtin_amdgcn_mfma_f32_16x16x32_f16(aH, bL, acc[ph][ng], 0, 0, 0);
                }
                __builtin_amdgcn_s_setprio(0);
            }
        }
    }

    // ---- epilogue: 2 half-cout passes through [32][257] LDS transpose ----
    const int Wout = Win * 2;
    const size_t plane = (size_t)(Hin * 2) * (size_t)Wout;
    float* ob = out + ((size_t)n * COUT + cobase) * plane;
    const int oy0 = 2 * y0, ox0 = 2 * x0;
#pragma unroll
    for (int half = 0; half < 2; ++half) {
        __syncthreads();
#pragma unroll
        for (int ph = 0; ph < 4; ++ph) {
            const int dy = ph >> 1, dx = ph & 1;
#pragma unroll
            for (int g = 0; g < 2; ++g) {
                int ng = half * 2 + g;
#pragma unroll
                for (int r = 0; r < 4; ++r)
                    smO[(g * 16 + n16) * 257 + (2 * yb + dy) * 32 + 2 * (q * 4 + r) + dx] = acc[ph][ng][r];
            }
        }
        __syncthreads();
#pragma unroll
        for (int k = 0; k < 32; ++k) {
            int pos = tid;
            int oyl = pos >> 5, oxl = pos & 31;
            float v = smO[k * 257 + pos];
            if (RELU) v = fmaxf(v, 0.f);
            ob[(size_t)(half * 32 + k) * plane + (size_t)(oy0 + oyl) * Wout + ox0 + oxl] = v;
        }
    }
}

// ===================== 3x3 conv s2 p1 — fp32, 1x2 out x 32 co ===============
// Output channels-last (only used for enc0 conv1 -> T1).
template<int CIN, int CB, bool RELU>
__launch_bounds__(256, 4)
__global__ void conv3s2_k(const float* __restrict__ in, const float* __restrict__ wp,
                          const float* __restrict__ bias, float* __restrict__ out,
                          int COUT, int Hin, int Win)
{
    constexpr int COC = 32;
    __shared__ float smIn[CB * 2178];           // 33 x 66
    __shared__ float smW[CB * 9 * COC];
    const int Hout = Hin >> 1, Wout = Win >> 1;
    const int tid = threadIdx.x;
    int b = blockIdx.x;
    const int chunks = COUT / COC;
    const int tX = Wout / 32, tY = Hout / 16;
    const int ch = b % chunks; b /= chunks;
    const int tx = b % tX; b /= tX;
    const int ty = b % tY; const int n = b / tY;
    const int cobase = ch * COC;
    const int r = tid >> 4, c = tid & 15;
    const int gy0 = ty * 32 - 1, gx0 = tx * 64 - 1;

    v4f acc[16];
#pragma unroll
    for (int g = 0; g < 8; ++g) {
        v4f bv = *(const v4f*)&bias[cobase + 4 * g];
        acc[g] = bv; acc[8 + g] = bv;
    }

    const size_t plane = (size_t)Hin * Win;
    const float* ip0 = in + (size_t)n * CIN * plane;
    const float* wp0 = wp + cobase;

    for (int ci0 = 0; ci0 < CIN; ci0 += CB) {
        __syncthreads();
        for (int idx = tid; idx < CB * 2178; idx += 256) {
            int ci = idx / 2178, rem = idx - ci * 2178;
            int rr = rem / 66, cc = rem - rr * 66;
            int gy = gy0 + rr, gx = gx0 + cc;
            float v = 0.f;
            if (gy >= 0 && gy < Hin && gx >= 0 && gx < Win)
                v = ip0[(size_t)(ci0 + ci) * plane + (size_t)gy * Win + gx];
            smIn[idx] = v;
        }
        for (int idx = tid; idx < CB * 9 * COC; idx += 256) {
            int q2 = idx >> 5, co = idx & 31;
            smW[idx] = wp0[((size_t)ci0 * 9 + q2) * COUT + co];
        }
        __syncthreads();

#pragma unroll 1
        for (int ci = 0; ci < CB; ++ci) {
            float p[15];
            const float* sp = &smIn[ci * 2178 + 2 * r * 66 + 4 * c];
#pragma unroll
            for (int i = 0; i < 3; ++i)
#pragma unroll
                for (int j = 0; j < 5; ++j)
                    p[i * 5 + j] = sp[i * 66 + j];
            const float* wrow = &smW[ci * 288];
#pragma unroll
            for (int k = 0; k < 9; ++k) {
                const int ky = k / 3, kx = k % 3;
#pragma unroll
                for (int g = 0; g < 8; ++g) {
                    v4f wv = *(const v4f*)&wrow[k * 32 + 4 * g];
                    fma4(acc[g],     p[ky * 5 + kx],     wv);
                    fma4(acc[8 + g], p[ky * 5 + kx + 2], wv);
                }
            }
        }
    }

    // channels-last epilogue: two cells (oy,ox), (oy,ox+1), 32 co contiguous
    const int oy = ty * 16 + r, ox = tx * 32 + 2 * c;
    size_t cellBase = (((size_t)n * Hout + oy) * Wout + ox) * COUT + cobase;
#pragma unroll
    for (int g = 0; g < 8; ++g) {
        v4f v0 = acc[g], v1 = acc[8 + g];
        if (RELU) {
#pragma unroll
            for (int e = 0; e < 4; ++e) { v0[e] = fmaxf(v0[e], 0.f); v1[e] = fmaxf(v1[e], 0.f); }
        }
        *(v4f*)&out[cellBase + 4 * g] = v0;
        *(v4f*)&out[cellBase + COUT + 4 * g] = v1;
    }
}

// =========== ConvTranspose k3 s2 p1 op1 — fp32, 2 quads/thread ==============
template<int CIN, int CB, int COC, bool RELU>
__launch_bounds__(256, 3)
__global__ void deconv2_k(const float* __restrict__ in, const float* __restrict__ wp,
                          const float* __restrict__ bias, float* __restrict__ out,
                          int COUTR, int COUTP, int Hin, int Win)
{
    constexpr int RW = 33, RH = 17;
    __shared__ float smIn[CB * RH * RW];
    __shared__ float smW[CB * 9 * COC];
    const int Wout = Win * 2;
    const int tid = threadIdx.x;
    int b = blockIdx.x;
    const int chunks = COUTP / COC;
    const int qTX = Win / 32, qTY = Hin / 16;
    const int ch = b % chunks; b /= chunks;
    const int qtx = b % qTX; b /= qTX;
    const int qty = b % qTY; const int n = b / qTY;
    const int cobase = ch * COC;
    const int tqy = tid >> 4, tqx = tid & 15;
    const int qby = qty * 16, qbx = qtx * 32;

    v4f acc[8 * COC / 4];
#pragma unroll
    for (int g = 0; g < COC / 4; ++g) {
        v4f bv;
#pragma unroll
        for (int e = 0; e < 4; ++e)
            bv[e] = (cobase + 4 * g + e < COUTR) ? bias[cobase + 4 * g + e] : 0.f;
#pragma unroll
        for (int pt = 0; pt < 8; ++pt) acc[pt * (COC / 4) + g] = bv;
    }

    const size_t plane = (size_t)Hin * Win;
    const float* ip0 = in + (size_t)n * CIN * plane;
    const float* wp0 = wp + cobase;

    for (int ci0 = 0; ci0 < CIN; ci0 += CB) {
        __syncthreads();
        for (int idx = tid; idx < CB * RH * RW; idx += 256) {
            int ci = idx / (RH * RW), rem = idx - ci * (RH * RW);
            int rr = rem / RW, cc = rem - rr * RW;
            int gy = qby + rr, gx = qbx + cc;
            float v = 0.f;
            if (gy < Hin && gx < Win)
                v = ip0[(size_t)(ci0 + ci) * plane + (size_t)gy * Win + gx];
            smIn[idx] = v;
        }
        for (int idx = tid; idx < CB * 9 * COC; idx += 256) {
            int q2 = idx / COC, co = idx % COC;
            smW[idx] = wp0[((size_t)ci0 * 9 + q2) * COUTP + co];
        }
        __syncthreads();

#pragma unroll 1
        for (int ci = 0; ci < CB; ++ci) {
            float p[6];
            const float* sp = &smIn[ci * RH * RW + tqy * RW + 2 * tqx];
#pragma unroll
            for (int i = 0; i < 2; ++i)
#pragma unroll
                for (int j = 0; j < 3; ++j)
                    p[i * 3 + j] = sp[i * RW + j];
            const float* wrow = &smW[ci * 9 * COC];
#pragma unroll
            for (int k = 0; k < 9; ++k) {
                const int ky = k / 3, kx = k % 3;
                const int dy = (ky == 1) ? 0 : 1, iy = (ky == 0) ? 1 : 0;
                const int dx = (kx == 1) ? 0 : 1, ix = (kx == 0) ? 1 : 0;
#pragma unroll
                for (int g = 0; g < COC / 4; ++g) {
                    v4f wv = *(const v4f*)&wrow[k * COC + 4 * g];
                    fma4(acc[(0 + dy * 2 + dx) * (COC / 4) + g], p[iy * 3 + ix],     wv);
                    fma4(acc[(4 + dy * 2 + dx) * (COC / 4) + g], p[iy * 3 + ix + 1], wv);
                }
            }
        }
    }

    const size_t oPlane = (size_t)(Hin * 2) * Wout;
    const int oy = 2 * (qby + tqy), ox = 2 * (qbx + 2 * tqx);
#pragma unroll
    for (int g = 0; g < COC / 4; ++g)
#pragma unroll
        for (int e = 0; e < 4; ++e) {
            int cch = cobase + 4 * g + e;
            if (cch >= COUTR) break;
            float* op = out + ((size_t)n * COUTR + cch) * oPlane + (size_t)oy * Wout + ox;
#pragma unroll
            for (int a2 = 0; a2 < 2; ++a2) {
                float u0 = acc[(0 + a2 * 2 + 0) * (COC / 4) + g][e];
                float u1 = acc[(0 + a2 * 2 + 1) * (COC / 4) + g][e];
                float u2 = acc[(4 + a2 * 2 + 0) * (COC / 4) + g][e];
                float u3 = acc[(4 + a2 * 2 + 1) * (COC / 4) + g][e];
                if (RELU) { u0 = fmaxf(u0, 0.f); u1 = fmaxf(u1, 0.f);
                            u2 = fmaxf(u2, 0.f); u3 = fmaxf(u3, 0.f); }
                *(float4*)&op[(size_t)a2 * Wout] = make_float4(u0, u1, u2, u3);
            }
        }
}

// ===================== 1x1 conv stride S — 1 pos/thread, 32 co ==============
template<int CIN, int S, bool RELU, bool CLIN, bool CLOUT>
__launch_bounds__(256, 4)
__global__ void conv1x1_k(const float* __restrict__ in, const float* __restrict__ w,
                          const float* __restrict__ bias, float* __restrict__ out,
                          int COUT, int Hin, int Win, int Hout, int Wout)
{
    constexpr int COC = 32;
    __shared__ float smW[CIN * COC];
    const int tid = threadIdx.x;
    int b = blockIdx.x;
    const int chunks = COUT / COC;
    const int spB = (Hout * Wout) / 256;
    const int ch = b % chunks; b /= chunks;
    const int sb = b % spB; const int n = b / spB;
    const int cobase = ch * COC;

    for (int idx = tid; idx < CIN * COC; idx += 256) {
        int ci = idx / COC, co = idx - ci * COC;
        smW[idx] = w[(size_t)(cobase + co) * CIN + ci];
    }
    __syncthreads();

    const int pos = sb * 256 + tid;
    const int oy = pos / Wout, ox = pos - oy * Wout;

    v4f acc[8];
#pragma unroll
    for (int g = 0; g < 8; ++g) acc[g] = *(const v4f*)&bias[cobase + 4 * g];

    if (CLIN) {
        const float* ip = in + (((size_t)n * Hin + oy * S) * Win + ox * S) * CIN;
#pragma unroll 1
        for (int c4 = 0; c4 < CIN / 4; ++c4) {
            v4f v = *(const v4f*)&ip[c4 * 4];
#pragma unroll
            for (int e = 0; e < 4; ++e)
#pragma unroll
                for (int g = 0; g < 8; ++g)
                    fma4(acc[g], v[e], *(const v4f*)&smW[(c4 * 4 + e) * COC + 4 * g]);
        }
    } else {
        const size_t inPlane = (size_t)Hin * Win;
        const float* ip = in + (size_t)n * CIN * inPlane + (size_t)(oy * S) * Win + (size_t)(ox * S);
#pragma unroll 1
        for (int ci = 0; ci < CIN; ++ci) {
            float v = ip[(size_t)ci * inPlane];
#pragma unroll
            for (int g = 0; g < 8; ++g)
                fma4(acc[g], v, *(const v4f*)&smW[ci * COC + 4 * g]);
        }
    }
    const size_t outPlane = (size_t)Hout * Wout;
    if (CLOUT) {
        size_t cb2 = ((size_t)n * outPlane + pos) * COUT + cobase;
#pragma unroll
        for (int g = 0; g < 8; ++g) {
            v4f v = acc[g];
            if (RELU) {
#pragma unroll
                for (int e = 0; e < 4; ++e) v[e] = fmaxf(v[e], 0.f);
            }
            *(v4f*)&out[cb2 + 4 * g] = v;
        }
    } else {
        float* op = out + ((size_t)n * COUT + cobase) * outPlane + pos;
#pragma unroll
        for (int g = 0; g < 8; ++g)
#pragma unroll
            for (int e = 0; e < 4; ++e) {
                float v = acc[g][e];
                if (RELU) v = fmaxf(v, 0.f);
                op[(size_t)(4 * g + e) * outPlane] = v;
            }
    }
}

// ==================== MFMA quantize (argmin distance GEMM) ==================
// Input S2 channels-last [pos][64]; output Q channels-last [pos][64].
__launch_bounds__(256, 4)
__global__ void mquant_k(const float* __restrict__ h, const _Float16* __restrict__ QB,
                         const float* __restrict__ cn, const float* __restrict__ cb,
                         float* __restrict__ q)
{
    __shared__ __align__(16) _Float16 AF[2][8192];   // [hl][((mt*2+s)*64+lane)*8+j]
    __shared__ float cns[512];
    __shared__ int bidxs[128];

    const int tid = threadIdx.x;
    const int lane = tid & 63;
    const int wv = tid >> 6;
    const int n16 = lane & 15, qq = lane >> 4;

    const int n = blockIdx.x >> 5;
    const int rem0 = (blockIdx.x & 31) << 7;

    for (int u = tid; u < 1024; u += 256) {
        int posL = u >> 3, grp = u & 7;
        const float* gp = h + ((size_t)n * 4096 + rem0 + posL) * 64 + grp * 8;
        float4 v0 = *(const float4*)gp;
        float4 v1 = *(const float4*)(gp + 4);
        f16x8 hh, ll;
        hh[0] = (_Float16)v0.x; ll[0] = (_Float16)(v0.x - (float)hh[0]);
        hh[1] = (_Float16)v0.y; ll[1] = (_Float16)(v0.y - (float)hh[1]);
        hh[2] = (_Float16)v0.z; ll[2] = (_Float16)(v0.z - (float)hh[2]);
        hh[3] = (_Float16)v0.w; ll[3] = (_Float16)(v0.w - (float)hh[3]);
        hh[4] = (_Float16)v1.x; ll[4] = (_Float16)(v1.x - (float)hh[4]);
        hh[5] = (_Float16)v1.y; ll[5] = (_Float16)(v1.y - (float)hh[5]);
        hh[6] = (_Float16)v1.z; ll[6] = (_Float16)(v1.z - (float)hh[6]);
        hh[7] = (_Float16)v1.w; ll[7] = (_Float16)(v1.w - (float)hh[7]);
        int mt = posL >> 4, s = grp >> 2, qv = grp & 3;
        int a = ((mt * 2 + s) * 64 + (posL & 15) + qv * 16) * 8;
        *(f16x8*)&AF[0][a] = hh;
        *(f16x8*)&AF[1][a] = ll;
    }
    for (int u = tid; u < 512; u += 256) cns[u] = cn[u];
    __syncthreads();

    f16x8 aH[2][2], aL[2][2];
#pragma unroll
    for (int m = 0; m < 2; ++m)
#pragma unroll
        for (int s = 0; s < 2; ++s) {
            int a = (((wv * 2 + m) * 2 + s) * 64 + lane) * 8;
            aH[m][s] = *(const f16x8*)&AF[0][a];
            aL[m][s] = *(const f16x8*)&AF[1][a];
        }

    float best[2][4]; int bi[2][4];
#pragma unroll
    for (int m = 0; m < 2; ++m)
#pragma unroll
        for (int r = 0; r < 4; ++r) { best[m][r] = 3.4e38f; bi[m][r] = 0; }

    const uint4* qbp = (const uint4*)QB;
#pragma unroll 1
    for (int nt = 0; nt < 32; ++nt) {
        uint4 rH0 = qbp[((nt * 2 + 0) * 2 + 0) * 64 + lane];
        uint4 rL0 = qbp[((nt * 2 + 0) * 2 + 1) * 64 + lane];
        uint4 rH1 = qbp[((nt * 2 + 1) * 2 + 0) * 64 + lane];
        uint4 rL1 = qbp[((nt * 2 + 1) * 2 + 1) * 64 + lane];
        f16x8 bH0 = *(const f16x8*)&rH0;
        f16x8 bL0 = *(const f16x8*)&rL0;
        f16x8 bH1 = *(const f16x8*)&rH1;
        f16x8 bL1 = *(const f16x8*)&rL1;
        float cnv = cns[nt * 16 + n16];
        const int code = nt * 16 + n16;
        __builtin_amdgcn_s_setprio(1);
#pragma unroll
        for (int m = 0; m < 2; ++m) {
            v4f acc = {0.f, 0.f, 0.f, 0.f};
            acc = __builtin_amdgcn_mfma_f32_16x16x32_f16(aH[m][0], bH0, acc, 0, 0, 0);
            acc = __builtin_amdgcn_mfma_f32_16x16x32_f16(aL[m][0], bH0, acc, 0, 0, 0);
            acc = __builtin_amdgcn_mfma_f32_16x16x32_f16(aH[m][0], bL0, acc, 0, 0, 0);
            acc = __builtin_amdgcn_mfma_f32_16x16x32_f16(aH[m][1], bH1, acc, 0, 0, 0);
            acc = __builtin_amdgcn_mfma_f32_16x16x32_f16(aL[m][1], bH1, acc, 0, 0, 0);
            acc = __builtin_amdgcn_mfma_f32_16x16x32_f16(aH[m][1], bL1, acc, 0, 0, 0);
#pragma unroll
            for (int r = 0; r < 4; ++r) {
                float d = fmaf(-2.f, acc[r], cnv);
                if (d < best[m][r]) { best[m][r] = d; bi[m][r] = code; }
            }
        }
        __builtin_amdgcn_s_setprio(0);
    }

    // reduce across the 16 lane-columns; first-min tie-break (lowest index)
#pragma unroll
    for (int m = 0; m < 2; ++m)
#pragma unroll
        for (int r = 0; r < 4; ++r) {
#pragma unroll
            for (int msk = 1; msk < 16; msk <<= 1) {
                float ob = __shfl_xor(best[m][r], msk);
                int oi = __shfl_xor(bi[m][r], msk);
                if (ob < best[m][r] || (ob == best[m][r] && oi < bi[m][r])) {
                    best[m][r] = ob; bi[m][r] = oi;
                }
            }
            if (n16 == 0) bidxs[wv * 32 + m * 16 + qq * 4 + r] = bi[m][r];
        }
    __syncthreads();

    const int p = tid & 127, jh = tid >> 7;
    const int code = bidxs[p];
    const float4* crow4 = (const float4*)(cb + (size_t)code * 64);
    float4* qp4 = (float4*)(q + ((size_t)n * 4096 + rem0 + p) * 64);
#pragma unroll
    for (int k = 0; k < 8; ++k)
        qp4[jh * 8 + k] = crow4[jh * 8 + k];
}

extern "C" void kernel_launch(void* const* d_in, const int* in_sizes, int n_in,
                              void* d_out, int out_size, void* d_ws, size_t ws_size,
                              hipStream_t stream)
{
    const float* x    = (const float*)d_in[0];
    const float* e0w1 = (const float*)d_in[1];  const float* e0b1 = (const float*)d_in[2];
    const float* e0w2 = (const float*)d_in[3];  const float* e0b2 = (const float*)d_in[4];
    const float* e0wd = (const float*)d_in[5];  const float* e0bd = (const float*)d_in[6];
    const float* e1w1 = (const float*)d_in[7];  const float* e1b1 = (const float*)d_in[8];
    const float* e1w2 = (const float*)d_in[9];  const float* e1b2 = (const float*)d_in[10];
    const float* e1wd = (const float*)d_in[11]; const float* e1bd = (const float*)d_in[12];
    const float* e2w1 = (const float*)d_in[13]; const float* e2b1 = (const float*)d_in[14];
    const float* e2w2 = (const float*)d_in[15]; const float* e2b2 = (const float*)d_in[16];
    const float* e2wd = (const float*)d_in[17]; const float* e2bd = (const float*)d_in[18];
    const float* d0w  = (const float*)d_in[19]; const float* d0b  = (const float*)d_in[20];
    const float* d1w  = (const float*)d_in[21]; const float* d1b  = (const float*)d_in[22];
    const float* d2w  = (const float*)d_in[23]; const float* d2b  = (const float*)d_in[24];
    const float* cb   = (const float*)d_in[25];
    float* out = (float*)d_out;
    float* ws  = (float*)d_ws;

    // ---- packs in d_out slack (d_out only written by the final dec2) ----
    float* P_e0w1 = out + 0;            // fp32 pack, 1728
    _Float16* Bh_d1   = (_Float16*)(out + 1728);     // 73728 halves
    _Float16* Bl_d1   = (_Float16*)(out + 38592);    // 73728 halves
    _Float16* Bh_e0c2 = (_Float16*)(out + 77760);
    _Float16* Bl_e0c2 = (_Float16*)(out + 96192);
    _Float16* Bh_e1c2 = (_Float16*)(out + 114624);
    _Float16* Bl_e1c2 = (_Float16*)(out + 188352);
    _Float16* Bh_e2c1 = (_Float16*)(out + 262080);
    _Float16* Bl_e2c1 = (_Float16*)(out + 298944);
    _Float16* Bh_e2c2 = (_Float16*)(out + 335808);
    _Float16* Bl_e2c2 = (_Float16*)(out + 354240);
    _Float16* Bh_d0   = (_Float16*)(out + 372672);
    _Float16* Bl_d0   = (_Float16*)(out + 409536);
    _Float16* Bh_e1c1 = (_Float16*)(out + 446400);   // 73728 halves
    _Float16* Bl_e1c1 = (_Float16*)(out + 483264);   // 73728 halves
    _Float16* QB = (_Float16*)(out + 520128);
    float* CN = out + 552896;
    float* P_d2w  = ws + 50405376;      // fp32 pack; written after S1 is dead

    // ---- ws activation layout (floats), liveness-planned ----
    // ALL activations channels-last except x (input) and D1.
    float* S0 = ws;                     // CL [n][128][128][64], enc0 out
    float* T1 = ws + 33554432;          // CL, enc0 conv1 out
    float* T3 = ws + 33554432;          // CL, enc1 conv1 out
    float* S1 = ws + 50331648;          // CL [n][64][64][128], enc1 out
    float* S2 = ws;                     // CL, enc2 out
    float* T5 = ws + 8388608;           // CL
    float* Q  = ws + 16777216;          // CL
    float* D0 = ws + 33554432;          // CL, dec0 out
    float* D1 = ws;                     // NCHW, dec1 out

    dim3 blk(256);
    auto rp = [&](const float* src, float* dst, int cout, int coutR, int cin, int flip, int dec) {
        int tot = cin * 9 * cout;
        repack_k<<<dim3((tot + 255) / 256), blk, 0, stream>>>(src, dst, cout, coutR, cin, flip, dec);
    };
    auto rpB = [&](const float* src, _Float16* bh, _Float16* bl, int cout, int cin, int dec) {
        int tot = 9 * cin * cout;
        repackB16_k<<<dim3((tot + 255) / 256), blk, 0, stream>>>(src, bh, bl, cout, cin, dec);
    };

    rp(e0w1, P_e0w1, 64, 64, 3, 0, 0);
    rpB(e0w2, Bh_e0c2, Bl_e0c2, 64, 64, 0);
    rpB(e1w1, Bh_e1c1, Bl_e1c1, 128, 64, 0);
    rpB(e1w2, Bh_e1c2, Bl_e1c2, 128, 128, 0);
    rpB(e2w1, Bh_e2c1, Bl_e2c1, 64, 128, 0);
    rpB(e2w2, Bh_e2c2, Bl_e2c2, 64, 64, 0);
    rpB(d0w,  Bh_d0,   Bl_d0,   128, 64, 1);   // ConvT s1 == flipped conv
    rpB(d1w,  Bh_d1,   Bl_d1,   64, 128, 1);   // ConvT s2, flipped-tap pack
    repackQ_k<<<dim3(256), blk, 0, stream>>>(cb, QB);
    cbnorm_k<<<dim3(2), blk, 0, stream>>>(cb, CN);

    // --- enc0 (3 -> 64, s2): 256 -> 128 ---
    conv1x1_k<3, 2, false, false, true><<<dim3(32 * 64 * 2), blk, 0, stream>>>(
        x, e0wd, e0bd, S0, 64, 256, 256, 128, 128);
    conv3s2_k<3, 3, true><<<dim3(32 * 8 * 4 * 2), blk, 0, stream>>>(
        x, P_e0w1, e0b1, T1, 64, 256, 256);
    mconv3s1_k<64, true, 2, true, true><<<dim3(32 * 8 * 8 * 1), blk, 0, stream>>>(
        T1, Bh_e0c2, Bl_e0c2, e0b2, S0, S0, 64, 128, 128);

    // --- enc1 (64 -> 128, s2): 128 -> 64 ---
    conv1x1_k<64, 2, false, true, true><<<dim3(32 * 16 * 4), blk, 0, stream>>>(
        S0, e1wd, e1bd, S1, 128, 128, 128, 64, 64);
    mconv3s2_k<64, 8, true><<<dim3(32 * 16 * 4), blk, 0, stream>>>(
        S0, Bh_e1c1, Bl_e1c1, e1b1, T3, 128, 128, 128);
    mconv3s1_k<128, true, 2, true, true><<<dim3(32 * 4 * 4 * 2), blk, 0, stream>>>(
        T3, Bh_e1c2, Bl_e1c2, e1b2, S1, S1, 128, 64, 64);

    // --- enc2 (128 -> 64, s1) ---
    conv1x1_k<128, 1, false, true, true><<<dim3(32 * 16 * 2), blk, 0, stream>>>(
        S1, e2wd, e2bd, S2, 64, 64, 64, 64, 64);
    mconv3s1_k<128, true, 0, true, true><<<dim3(32 * 4 * 4 * 1), blk, 0, stream>>>(
        S1, Bh_e2c1, Bl_e2c1, e2b1, T5, nullptr, 64, 64, 64);
    rp(d2w, P_d2w, 4, 3, 64, 0, 1);             // S1 dead after the two reads above
    mconv3s1_k<64, true, 2, true, true><<<dim3(32 * 4 * 4 * 1), blk, 0, stream>>>(
        T5, Bh_e2c2, Bl_e2c2, e2b2, S2, S2, 64, 64, 64);

    // --- quantize (MFMA argmin), CL in/out ---
    mquant_k<<<dim3(1024), blk, 0, stream>>>(S2, QB, CN, cb, Q);

    // --- dec0: ConvT s1 (64 -> 128) as flipped conv, ReLU, CL in/out ---
    mconv3s1_k<64, true, 0, true, true><<<dim3(32 * 4 * 4 * 2), blk, 0, stream>>>(
        Q, Bh_d0, Bl_d0, d0b, D0, nullptr, 128, 64, 64);

    // --- dec1: ConvT s2 (128 -> 64), ReLU: 64 -> 128 (MFMA, 4-phase, CL in) ---
    mdeconv2_k<128, true><<<dim3(32 * 16 * 4), blk, 0, stream>>>(
        D0, Bh_d1, Bl_d1, d1b, D1, 64, 64, 64);

    // --- dec2: ConvT s2 (64 -> 3): 128 -> 256 ---
    deconv2_k<64, 8, 4, false><<<dim3(32 * 4 * 8), blk, 0, stream>>>(
        D1, P_d2w, d2b, out, 3, 4, 128, 128);
}

// Round 10
// 1308.531 us; speedup vs baseline: 1.3922x; 1.1100x over previous
//
#include <hip/hip_runtime.h>
#include <cstddef>

// ---------------------------------------------------------------------------
// VQ-VAE forward. Round 16: fuse the 1x1 downsample convs into sibling
// kernels that already stage the same input. conv1x1_e0 -> conv3s2_k epilogue
// (fp32, bitwise-identical order); conv1x1_e1 -> mconv3s2_k as a 10th tap
// (center A-frag == 1x1 input). Base structure = R15 (best, 1452us).
// ---------------------------------------------------------------------------

typedef float v4f __attribute__((ext_vector_type(4)));
typedef _Float16 f16x8 __attribute__((ext_vector_type(8)));
typedef _Float16 f16x4 __attribute__((ext_vector_type(4)));

__device__ __forceinline__ void fma4(v4f& a, float p, const v4f& w) {
    a.x = fmaf(p, w.x, a.x); a.y = fmaf(p, w.y, a.y);
    a.z = fmaf(p, w.z, a.z); a.w = fmaf(p, w.w, a.w);
}

// Repack conv/deconv weights to fp32 [ci][9][cout] (for fp32 kernels).
__global__ void repack_k(const float* __restrict__ src, float* __restrict__ dst,
                         int cout, int coutR, int cin, int flip, int deconv)
{
    int t = blockIdx.x * 256 + threadIdx.x;
    int tot = cin * 9 * cout;
    if (t >= tot) return;
    int co = t % cout; int k = (t / cout) % 9; int ci = t / (9 * cout);
    float v = 0.f;
    if (co < coutR) {
        int ks = flip ? 8 - k : k;
        v = deconv ? src[((size_t)ci * coutR + co) * 9 + ks]
                   : src[((size_t)co * cin + ci) * 9 + ks];
    }
    dst[t] = v;
}

// Prepack weights to fp16 hi/lo MFMA B-fragment order.
__global__ void repackB16_k(const float* __restrict__ src, _Float16* __restrict__ bh,
                            _Float16* __restrict__ bl, int COUT, int CIN, int deconv)
{
    int t = blockIdx.x * 256 + threadIdx.x;
    int tot = 9 * CIN * COUT;
    if (t >= tot) return;
    int NGtot = COUT >> 4, C32 = CIN >> 5;
    int j = t & 7;
    int lane = (t >> 3) & 63;
    int blk = t >> 9;
    int ng = blk % NGtot; blk /= NGtot;
    int c32 = blk % C32;
    int tap = blk / C32;
    int co = ng * 16 + (lane & 15);
    int ci = c32 * 32 + ((lane >> 4) & 3) * 8 + j;
    float v = deconv ? src[((size_t)ci * COUT + co) * 9 + (8 - tap)]
                     : src[((size_t)co * CIN + ci) * 9 + tap];
    _Float16 h = (_Float16)v;
    _Float16 l = (_Float16)(v - (float)h);
    bh[t] = h; bl[t] = l;
}

// Prepack 1x1 weights (COUT, CIN) to fp16 hi/lo fragment order.
__global__ void repackW16_k(const float* __restrict__ src, _Float16* __restrict__ wh,
                            _Float16* __restrict__ wl, int COUT, int CIN)
{
    int t = blockIdx.x * 256 + threadIdx.x;
    int tot = CIN * COUT;
    if (t >= tot) return;
    int NGtot = COUT >> 4;
    int j = t & 7;
    int lane = (t >> 3) & 63;
    int blk = t >> 9;
    int ng = blk % NGtot;
    int c32 = blk / NGtot;
    int co = ng * 16 + (lane & 15);
    int ci = c32 * 32 + ((lane >> 4) & 3) * 8 + j;
    float v = src[(size_t)co * CIN + ci];
    _Float16 h = (_Float16)v;
    wh[t] = h; wl[t] = (_Float16)(v - (float)h);
}

// Pack codebook (512 x 64) to fp16 hi/lo B-fragment order.
__global__ void repackQ_k(const float* __restrict__ cb, _Float16* __restrict__ qb)
{
    int t = blockIdx.x * 256 + threadIdx.x;
    if (t >= 65536) return;
    int j = t & 7;
    int lane = (t >> 3) & 63;
    int hl = (t >> 9) & 1;
    int s = (t >> 10) & 1;
    int nt = t >> 11;
    int code = nt * 16 + (lane & 15);
    int ci = s * 32 + ((lane >> 4) & 3) * 8 + j;
    float v = cb[(size_t)code * 64 + ci];
    _Float16 h = (_Float16)v;
    qb[t] = hl ? (_Float16)(v - (float)h) : h;
}

// Codebook squared norms.
__global__ void cbnorm_k(const float* __restrict__ cb, float* __restrict__ cn)
{
    int i = blockIdx.x * 256 + threadIdx.x;
    if (i >= 512) return;
    float s = 0.f;
#pragma unroll
    for (int j = 0; j < 64; ++j) { float v = cb[i * 64 + j]; s = fmaf(v, v, s); }
    cn[i] = s;
}

// ================= MFMA 3x3 conv s1 p1 (fp16 hi/lo split) ===================
// Block: 256 positions (16x16) x 64 co. Wave: 4 rows x 64 co.
// ADDMODE: 0 none, 1 NCHW addend, 2 channels-last addend.
template<int CIN, bool RELU, int ADDMODE, bool CLIN, bool CLOUT>
__launch_bounds__(256, 2)
__global__ void mconv3s1_k(const float* __restrict__ in,
                           const _Float16* __restrict__ Bh, const _Float16* __restrict__ Bl,
                           const float* __restrict__ bias, float* __restrict__ out,
                           const float* __restrict__ addend,
                           int COUT, int H, int W)
{
    constexpr int C32 = CIN / 32;
    __shared__ __align__(16) unsigned char smBuf[76416];
    _Float16* AH = (_Float16*)smBuf;        // [18][18][40] = 12960 halves
    _Float16* AL = AH + 12960;              // 12960
    _Float16* BW = AL + 12960;              // [tapL3][ng4][hl2][lane64][8] = 12288
    float* smO = (float*)smBuf;             // [64][257] epilogue overlay (65784 B)

    const int tid = threadIdx.x;
    const int lane = tid & 63, yb = tid >> 6;
    const int n16 = lane & 15, q = lane >> 4;

    int b = blockIdx.x;
    const int chunks = COUT >> 6;
    const int coch = b % chunks; b /= chunks;
    const int tX = W >> 4; const int tx = b % tX; b /= tX;
    const int tY = H >> 4; const int ty = b % tY; const int n = b / tY;
    const int x0 = tx * 16, y0 = ty * 16;
    const int NGtot = COUT >> 4;
    const int ngbase = coch * 4, cobase = coch * 64;

    v4f acc[4][4];
#pragma unroll
    for (int ng = 0; ng < 4; ++ng) {
        float bb = bias[cobase + ng * 16 + n16];
        v4f bv = {bb, bb, bb, bb};
#pragma unroll
        for (int mg = 0; mg < 4; ++mg) acc[mg][ng] = bv;
    }

    for (int c32 = 0; c32 < C32; ++c32) {
        __syncthreads();
        if (CLIN) {
            // ---- stage A from channels-last: float4 loads, b64 LDS writes ----
            for (int u = tid; u < 2592; u += 256) {
                int cell = u >> 3, f4 = u & 7;
                int yy = cell / 18, xx = cell - yy * 18;
                int gy = y0 - 1 + yy, gx = x0 - 1 + xx;
                float4 v = make_float4(0.f, 0.f, 0.f, 0.f);
                if (gy >= 0 && gy < H && gx >= 0 && gx < W)
                    v = *(const float4*)&in[(((size_t)n * H + gy) * W + gx) * CIN + c32 * 32 + f4 * 4];
                f16x4 h4, l4;
                h4[0] = (_Float16)v.x; l4[0] = (_Float16)(v.x - (float)h4[0]);
                h4[1] = (_Float16)v.y; l4[1] = (_Float16)(v.y - (float)h4[1]);
                h4[2] = (_Float16)v.z; l4[2] = (_Float16)(v.z - (float)h4[2]);
                h4[3] = (_Float16)v.w; l4[3] = (_Float16)(v.w - (float)h4[3]);
                int a = (yy * 18 + xx) * 40 + f4 * 4;
                *(f16x4*)&AH[a] = h4; *(f16x4*)&AL[a] = l4;
            }
        } else {
            // ---- stage A from NCHW: scalar gather ----
            for (int u = tid; u < 10368; u += 256) {
                int ci = u / 324, rem = u - ci * 324;
                int yy = rem / 18, xx = rem - yy * 18;
                int gy = y0 - 1 + yy, gx = x0 - 1 + xx;
                float v = 0.f;
                if (gy >= 0 && gy < H && gx >= 0 && gx < W)
                    v = in[(((size_t)n * CIN + c32 * 32 + ci) * H + gy) * W + gx];
                _Float16 h = (_Float16)v;
                _Float16 l = (_Float16)(v - (float)h);
                int a = (yy * 18 + xx) * 40 + ci;
                AH[a] = h; AL[a] = l;
            }
        }
        for (int ky = 0; ky < 3; ++ky) {
            __syncthreads();
            // ---- stage B row: 3 taps x 4 ng x hi/lo, 1536 x 16B ----
            for (int u = tid; u < 1536; u += 256) {
                int lu = u & 63;
                int rest = u >> 6;
                int hl = rest & 1; rest >>= 1;
                int ng = rest & 3;
                int tapL = rest >> 2;
                const uint4* srcp = (const uint4*)(hl ? Bl : Bh);
                size_t sidx = (((size_t)(ky * 3 + tapL) * C32 + c32) * NGtot + ngbase + ng) * 64 + lu;
                ((uint4*)BW)[u] = srcp[sidx];
            }
            __syncthreads();
#pragma unroll
            for (int kx = 0; kx < 3; ++kx) {
                f16x8 aH[4], aL[4];
#pragma unroll
                for (int mg = 0; mg < 4; ++mg) {
                    int aoff = ((4 * yb + mg + ky) * 18 + n16 + kx) * 40 + q * 8;
                    aH[mg] = *(const f16x8*)&AH[aoff];
                    aL[mg] = *(const f16x8*)&AL[aoff];
                }
                __builtin_amdgcn_s_setprio(1);
#pragma unroll
                for (int ng = 0; ng < 4; ++ng) {
                    int boff = ((kx * 4 + ng) * 2) * 512 + lane * 8;
                    f16x8 bH = *(const f16x8*)&BW[boff];
                    f16x8 bL = *(const f16x8*)&BW[boff + 512];
#pragma unroll
                    for (int mg = 0; mg < 4; ++mg) {
                        acc[mg][ng] = __builtin_amdgcn_mfma_f32_16x16x32_f16(aH[mg], bH, acc[mg][ng], 0, 0, 0);
                        acc[mg][ng] = __builtin_amdgcn_mfma_f32_16x16x32_f16(aL[mg], bH, acc[mg][ng], 0, 0, 0);
                        acc[mg][ng] = __builtin_amdgcn_mfma_f32_16x16x32_f16(aH[mg], bL, acc[mg][ng], 0, 0, 0);
                    }
                }
                __builtin_amdgcn_s_setprio(0);
            }
        }
    }

    // ---- epilogue: LDS transpose -> coalesced stores ----
    __syncthreads();
#pragma unroll
    for (int mg = 0; mg < 4; ++mg)
#pragma unroll
        for (int ng = 0; ng < 4; ++ng) {
            int p = (4 * yb + mg) * 16 + q * 4;
            int co = ng * 16 + n16;
#pragma unroll
            for (int r = 0; r < 4; ++r)
                smO[co * 257 + p + r] = acc[mg][ng][r];
        }
    __syncthreads();
    if (CLOUT) {
        const int p = tid;
        const int py = p >> 4, px = p & 15;
        size_t cellBase = (((size_t)n * H + (y0 + py)) * W + (x0 + px)) * COUT + cobase;
        float* cellp = out + cellBase;
        const float* acell = (ADDMODE == 2) ? addend + cellBase : nullptr;
#pragma unroll
        for (int g = 0; g < 16; ++g) {
            float4 v;
            v.x = smO[(4 * g + 0) * 257 + p];
            v.y = smO[(4 * g + 1) * 257 + p];
            v.z = smO[(4 * g + 2) * 257 + p];
            v.w = smO[(4 * g + 3) * 257 + p];
            if (ADDMODE == 2) {
                float4 a4 = *(const float4*)&acell[4 * g];
                v.x += a4.x; v.y += a4.y; v.z += a4.z; v.w += a4.w;
            }
            if (RELU) {
                v.x = fmaxf(v.x, 0.f); v.y = fmaxf(v.y, 0.f);
                v.z = fmaxf(v.z, 0.f); v.w = fmaxf(v.w, 0.f);
            }
            *(float4*)&cellp[4 * g] = v;
        }
    } else {
        const size_t plane = (size_t)H * W;
        float* ob = out + ((size_t)n * COUT + cobase) * plane;
        const float* ab = (ADDMODE == 1) ? addend + ((size_t)n * COUT + cobase) * plane : nullptr;
#pragma unroll
        for (int k = 0; k < 64; ++k) {
            int e = tid + 256 * k;
            int co = e >> 8, p = e & 255;
            int py = p >> 4, px = p & 15;
            size_t g = (size_t)co * plane + (size_t)(y0 + py) * W + x0 + px;
            float v = smO[co * 257 + p];
            if (ADDMODE == 1) v += ab[g];
            if (RELU) v = fmaxf(v, 0.f);
            ob[g] = v;
        }
    }
}

// ============== MFMA 3x3 conv s2 p1 (fp16 hi/lo split) ======================
// Input channels-last; output channels-last. B fragments direct from global.
// FUSED 1x1 stride-2 conv (center tap A-frag) -> out1 (S1), no relu.
template<int CIN, int NG, bool RELU>
__launch_bounds__(256, 3)
__global__ void mconv3s2_k(const float* __restrict__ in,
                           const _Float16* __restrict__ Bh, const _Float16* __restrict__ Bl,
                           const float* __restrict__ bias, float* __restrict__ out,
                           const _Float16* __restrict__ Wh, const _Float16* __restrict__ Wl,
                           const float* __restrict__ bias1, float* __restrict__ out1,
                           int COUT, int Hin, int Win)
{
    constexpr int C32 = CIN / 32;
    constexpr int ASZ = 9 * 2 * 17 * 40;        // 12240 halves per H/L
    __shared__ __align__(16) unsigned char smBuf[2 * ASZ * 2];   // 48960 B
    _Float16* AH = (_Float16*)smBuf;
    _Float16* AL = AH + ASZ;
    float* smO = (float*)smBuf;                 // [NG*16][65] overlay (33280 B)

    const int tid = threadIdx.x;
    const int lane = tid & 63, yb = tid >> 6;
    const int n16 = lane & 15, q = lane >> 4;

    const int Hout = Hin >> 1, Wout = Win >> 1;
    int b = blockIdx.x;
    const int chunks = COUT / (NG * 16);
    const int coch = b % chunks; b /= chunks;
    const int tX = Wout >> 4; const int tx = b % tX; b /= tX;
    const int tY = Hout >> 2; const int ty = b % tY; const int n = b / tY;
    const int x0 = tx * 16, y0 = ty * 4;
    const int gx0 = 2 * x0 - 1, gy0 = 2 * y0 - 1;
    const int NGtot = COUT >> 4;
    const int ngbase = coch * NG, cobase = coch * NG * 16;

    v4f acc[NG];
    v4f accW[NG];
#pragma unroll
    for (int ng = 0; ng < NG; ++ng) {
        float bb = bias[cobase + ng * 16 + n16];
        v4f bv = {bb, bb, bb, bb};
        acc[ng] = bv;
        float bw = bias1[cobase + ng * 16 + n16];
        v4f bwv = {bw, bw, bw, bw};
        accW[ng] = bwv;
    }

    const uint4* bhp = (const uint4*)Bh;
    const uint4* blp = (const uint4*)Bl;
    const uint4* whp = (const uint4*)Wh;
    const uint4* wlp = (const uint4*)Wl;

    for (int c32 = 0; c32 < C32; ++c32) {
        __syncthreads();
        // ---- stage A from CL: 297 cells x 8 float4, parity-split columns ----
        for (int u = tid; u < 2376; u += 256) {
            int cell = u >> 3, f4 = u & 7;
            int yy = cell / 33, xx = cell - yy * 33;
            int gy = gy0 + yy, gx = gx0 + xx;
            float4 v = make_float4(0.f, 0.f, 0.f, 0.f);
            if (gy >= 0 && gy < Hin && gx >= 0 && gx < Win)
                v = *(const float4*)&in[(((size_t)n * Hin + gy) * Win + gx) * CIN + c32 * 32 + f4 * 4];
            f16x4 h4, l4;
            h4[0] = (_Float16)v.x; l4[0] = (_Float16)(v.x - (float)h4[0]);
            h4[1] = (_Float16)v.y; l4[1] = (_Float16)(v.y - (float)h4[1]);
            h4[2] = (_Float16)v.z; l4[2] = (_Float16)(v.z - (float)h4[2]);
            h4[3] = (_Float16)v.w; l4[3] = (_Float16)(v.w - (float)h4[3]);
            int a = ((yy * 2 + (xx & 1)) * 17 + (xx >> 1)) * 40 + f4 * 4;
            *(f16x4*)&AH[a] = h4; *(f16x4*)&AL[a] = l4;
        }
        __syncthreads();
#pragma unroll
        for (int ky = 0; ky < 3; ++ky) {
#pragma unroll
            for (int kx = 0; kx < 3; ++kx) {
                const int par = kx & 1, xs = kx >> 1;
                int aoff = (((2 * yb + ky) * 2 + par) * 17 + n16 + xs) * 40 + q * 8;
                f16x8 aH = *(const f16x8*)&AH[aoff];
                f16x8 aL = *(const f16x8*)&AL[aoff];
                size_t sb0 = (((size_t)(ky * 3 + kx) * C32 + c32) * NGtot + ngbase) * 64 + lane;
                __builtin_amdgcn_s_setprio(1);
#pragma unroll
                for (int ng = 0; ng < NG; ++ng) {
                    uint4 rH = bhp[sb0 + (size_t)ng * 64];
                    uint4 rL = blp[sb0 + (size_t)ng * 64];
                    f16x8 bH = *(const f16x8*)&rH;
                    f16x8 bL = *(const f16x8*)&rL;
                    acc[ng] = __builtin_amdgcn_mfma_f32_16x16x32_f16(aH, bH, acc[ng], 0, 0, 0);
                    acc[ng] = __builtin_amdgcn_mfma_f32_16x16x32_f16(aL, bH, acc[ng], 0, 0, 0);
                    acc[ng] = __builtin_amdgcn_mfma_f32_16x16x32_f16(aH, bL, acc[ng], 0, 0, 0);
                }
                __builtin_amdgcn_s_setprio(0);
                if (ky == 1 && kx == 1) {
                    // fused 1x1: same A-frag (input at (2oy, 2ox))
                    size_t sw0 = ((size_t)c32 * NGtot + ngbase) * 64 + lane;
                    __builtin_amdgcn_s_setprio(1);
#pragma unroll
                    for (int ng = 0; ng < NG; ++ng) {
                        uint4 rH = whp[sw0 + (size_t)ng * 64];
                        uint4 rL = wlp[sw0 + (size_t)ng * 64];
                        f16x8 bH = *(const f16x8*)&rH;
                        f16x8 bL = *(const f16x8*)&rL;
                        accW[ng] = __builtin_amdgcn_mfma_f32_16x16x32_f16(aH, bH, accW[ng], 0, 0, 0);
                        accW[ng] = __builtin_amdgcn_mfma_f32_16x16x32_f16(aL, bH, accW[ng], 0, 0, 0);
                        accW[ng] = __builtin_amdgcn_mfma_f32_16x16x32_f16(aH, bL, accW[ng], 0, 0, 0);
                    }
                    __builtin_amdgcn_s_setprio(0);
                }
            }
        }
    }

    // ---- epilogue pass 1: conv output -> channels-last float4 stores ----
    __syncthreads();
#pragma unroll
    for (int ng = 0; ng < NG; ++ng) {
        int co = ng * 16 + n16;
        int p = yb * 16 + q * 4;
#pragma unroll
        for (int r = 0; r < 4; ++r)
            smO[co * 65 + p + r] = acc[ng][r];
    }
    __syncthreads();
    const int p2 = tid >> 2, s2 = tid & 3;
    const int py = p2 >> 4, px = p2 & 15;
    float* cellp = out + ((((size_t)n * Hout + (y0 + py)) * Wout + (x0 + px)) * COUT + s2 * 32);
#pragma unroll
    for (int k = 0; k < 8; ++k) {
        float4 v;
        v.x = smO[(s2 * 32 + 4 * k + 0) * 65 + p2];
        v.y = smO[(s2 * 32 + 4 * k + 1) * 65 + p2];
        v.z = smO[(s2 * 32 + 4 * k + 2) * 65 + p2];
        v.w = smO[(s2 * 32 + 4 * k + 3) * 65 + p2];
        if (RELU) {
            v.x = fmaxf(v.x, 0.f); v.y = fmaxf(v.y, 0.f);
            v.z = fmaxf(v.z, 0.f); v.w = fmaxf(v.w, 0.f);
        }
        *(float4*)&cellp[4 * k] = v;
    }

    // ---- epilogue pass 2: fused 1x1 output (no relu) ----
    __syncthreads();
#pragma unroll
    for (int ng = 0; ng < NG; ++ng) {
        int co = ng * 16 + n16;
        int p = yb * 16 + q * 4;
#pragma unroll
        for (int r = 0; r < 4; ++r)
            smO[co * 65 + p + r] = accW[ng][r];
    }
    __syncthreads();
    float* cellp1 = out1 + ((((size_t)n * Hout + (y0 + py)) * Wout + (x0 + px)) * COUT + s2 * 32);
#pragma unroll
    for (int k = 0; k < 8; ++k) {
        float4 v;
        v.x = smO[(s2 * 32 + 4 * k + 0) * 65 + p2];
        v.y = smO[(s2 * 32 + 4 * k + 1) * 65 + p2];
        v.z = smO[(s2 * 32 + 4 * k + 2) * 65 + p2];
        v.w = smO[(s2 * 32 + 4 * k + 3) * 65 + p2];
        *(float4*)&cellp1[4 * k] = v;
    }
}

// ======== MFMA ConvT k3 s2 p1 op1 (fp16 hi/lo), 4-phase decomposition =======
// Input D0 channels-last [n][Hin][Win][CIN]; output D1 NCHW.
template<int CIN, bool RELU>
__launch_bounds__(256, 3)
__global__ void mdeconv2_k(const float* __restrict__ in,
                           const _Float16* __restrict__ Bh, const _Float16* __restrict__ Bl,
                           const float* __restrict__ bias, float* __restrict__ out,
                           int COUT, int Hin, int Win)
{
    constexpr int C32 = CIN / 32;
    __shared__ __align__(16) unsigned char smBuf[38976];
    _Float16* AH = (_Float16*)smBuf;        // [5][18][40] = 3600 halves
    _Float16* AL = AH + 3600;               // 3600
    _Float16* BW = AL + 3600;               // [tapL3][ng4][hl2][lane64][8] = 12288
    float* smO = (float*)smBuf;             // [32][257] epilogue overlay = 32896B

    const int tid = threadIdx.x;
    const int lane = tid & 63, yb = tid >> 6;   // wave = one input row
    const int n16 = lane & 15, q = lane >> 4;

    int b = blockIdx.x;
    const int chunks = COUT >> 6;
    const int coch = b % chunks; b /= chunks;
    const int tX = Win >> 4; const int tx = b % tX; b /= tX;
    const int tY = Hin >> 2; const int ty = b % tY; const int n = b / tY;
    const int x0 = tx * 16, y0 = ty * 4;
    const int NGtot = COUT >> 4;
    const int ngbase = coch * 4, cobase = coch * 64;

    v4f acc[4][4];                              // [phase dy*2+dx][ng]
#pragma unroll
    for (int ng = 0; ng < 4; ++ng) {
        float bb = bias[cobase + ng * 16 + n16];
        v4f bv = {bb, bb, bb, bb};
#pragma unroll
        for (int ph = 0; ph < 4; ++ph) acc[ph][ng] = bv;
    }

    for (int c32 = 0; c32 < C32; ++c32) {
        __syncthreads();
        // ---- stage A (channels-last): 5 rows x 17 cols x 32 ci ----
        for (int u = tid; u < 680; u += 256) {
            int cell = u >> 3, f4 = u & 7;
            int yy = cell / 17, xx = cell - yy * 17;
            int gy = y0 + yy, gx = x0 + xx;
            float4 v = make_float4(0.f, 0.f, 0.f, 0.f);
            if (gy < Hin && gx < Win)
                v = *(const float4*)&in[(((size_t)n * Hin + gy) * Win + gx) * CIN + c32 * 32 + f4 * 4];
            f16x4 h4, l4;
            h4[0] = (_Float16)v.x; l4[0] = (_Float16)(v.x - (float)h4[0]);
            h4[1] = (_Float16)v.y; l4[1] = (_Float16)(v.y - (float)h4[1]);
            h4[2] = (_Float16)v.z; l4[2] = (_Float16)(v.z - (float)h4[2]);
            h4[3] = (_Float16)v.w; l4[3] = (_Float16)(v.w - (float)h4[3]);
            int a = (yy * 18 + xx) * 40 + f4 * 4;
            *(f16x4*)&AH[a] = h4; *(f16x4*)&AL[a] = l4;
        }
        for (int ky = 0; ky < 3; ++ky) {
            __syncthreads();
            // ---- stage B row: 3 taps x 4 ng x hi/lo, 1536 x 16B ----
            for (int u = tid; u < 1536; u += 256) {
                int lu = u & 63;
                int rest = u >> 6;
                int hl = rest & 1; rest >>= 1;
                int ng = rest & 3;
                int tapL = rest >> 2;
                const uint4* srcp = (const uint4*)(hl ? Bl : Bh);
                size_t sidx = (((size_t)(ky * 3 + tapL) * C32 + c32) * NGtot + ngbase + ng) * 64 + lu;
                ((uint4*)BW)[u] = srcp[sidx];
            }
            __syncthreads();
            const int iy = (ky == 2) ? 1 : 0;
            const int phy = (ky == 1) ? 0 : 2;
#pragma unroll
            for (int kx = 0; kx < 3; ++kx) {
                const int ix = (kx == 2) ? 1 : 0;
                const int ph = phy + ((kx == 1) ? 0 : 1);
                int aoff = ((yb + iy) * 18 + n16 + ix) * 40 + q * 8;
                f16x8 aH = *(const f16x8*)&AH[aoff];
                f16x8 aL = *(const f16x8*)&AL[aoff];
                __builtin_amdgcn_s_setprio(1);
#pragma unroll
                for (int ng = 0; ng < 4; ++ng) {
                    int boff = ((kx * 4 + ng) * 2) * 512 + lane * 8;
                    f16x8 bH = *(const f16x8*)&BW[boff];
                    f16x8 bL = *(const f16x8*)&BW[boff + 512];
                    acc[ph][ng] = __builtin_amdgcn_mfma_f32_16x16x32_f16(aH, bH, acc[ph][ng], 0, 0, 0);
                    acc[ph][ng] = __builtin_amdgcn_mfma_f32_16x16x32_f16(aL, bH, acc[ph][ng], 0, 0, 0);
                    acc[ph][ng] = __builtin_amdgcn_mfma_f32_16x16x32_f16(aH, bL, acc[ph][ng], 0, 0, 0);
                }
                __builtin_amdgcn_s_setprio(0);
            }
        }
    }

    // ---- epilogue: 2 half-cout passes through [32][257] LDS transpose ----
    const int Wout = Win * 2;
    const size_t plane = (size_t)(Hin * 2) * (size_t)Wout;
    float* ob = out + ((size_t)n * COUT + cobase) * plane;
    const int oy0 = 2 * y0, ox0 = 2 * x0;
#pragma unroll
    for (int half = 0; half < 2; ++half) {
        __syncthreads();
#pragma unroll
        for (int ph = 0; ph < 4; ++ph) {
            const int dy = ph >> 1, dx = ph & 1;
#pragma unroll
            for (int g = 0; g < 2; ++g) {
                int ng = half * 2 + g;
#pragma unroll
                for (int r = 0; r < 4; ++r)
                    smO[(g * 16 + n16) * 257 + (2 * yb + dy) * 32 + 2 * (q * 4 + r) + dx] = acc[ph][ng][r];
            }
        }
        __syncthreads();
#pragma unroll
        for (int k = 0; k < 32; ++k) {
            int pos = tid;
            int oyl = pos >> 5, oxl = pos & 31;
            float v = smO[k * 257 + pos];
            if (RELU) v = fmaxf(v, 0.f);
            ob[(size_t)(half * 32 + k) * plane + (size_t)(oy0 + oyl) * Wout + ox0 + oxl] = v;
        }
    }
}

// ===================== 3x3 conv s2 p1 — fp32, 1x2 out x 32 co ===============
// Output channels-last. FUSE: also compute 1x1 stride-2 (wd, bd) -> out1 from
// the staged smIn center taps (bitwise-identical to the old conv1x1 kernel).
template<int CIN, int CB, bool RELU, bool FUSE>
__launch_bounds__(256, 4)
__global__ void conv3s2_k(const float* __restrict__ in, const float* __restrict__ wp,
                          const float* __restrict__ bias, float* __restrict__ out,
                          const float* __restrict__ wd, const float* __restrict__ bd,
                          float* __restrict__ out1,
                          int COUT, int Hin, int Win)
{
    constexpr int COC = 32;
    __shared__ float smIn[CB * 2178];           // 33 x 66
    __shared__ float smW[CB * 9 * COC];
    __shared__ float smWD[96];
    const int Hout = Hin >> 1, Wout = Win >> 1;
    const int tid = threadIdx.x;
    int b = blockIdx.x;
    const int chunks = COUT / COC;
    const int tX = Wout / 32, tY = Hout / 16;
    const int ch = b % chunks; b /= chunks;
    const int tx = b % tX; b /= tX;
    const int ty = b % tY; const int n = b / tY;
    const int cobase = ch * COC;
    const int r = tid >> 4, c = tid & 15;
    const int gy0 = ty * 32 - 1, gx0 = tx * 64 - 1;

    v4f acc[16];
#pragma unroll
    for (int g = 0; g < 8; ++g) {
        v4f bv = *(const v4f*)&bias[cobase + 4 * g];
        acc[g] = bv; acc[8 + g] = bv;
    }

    const size_t plane = (size_t)Hin * Win;
    const float* ip0 = in + (size_t)n * CIN * plane;
    const float* wp0 = wp + cobase;

    for (int ci0 = 0; ci0 < CIN; ci0 += CB) {
        __syncthreads();
        for (int idx = tid; idx < CB * 2178; idx += 256) {
            int ci = idx / 2178, rem = idx - ci * 2178;
            int rr = rem / 66, cc = rem - rr * 66;
            int gy = gy0 + rr, gx = gx0 + cc;
            float v = 0.f;
            if (gy >= 0 && gy < Hin && gx >= 0 && gx < Win)
                v = ip0[(size_t)(ci0 + ci) * plane + (size_t)gy * Win + gx];
            smIn[idx] = v;
        }
        for (int idx = tid; idx < CB * 9 * COC; idx += 256) {
            int q2 = idx >> 5, co = idx & 31;
            smW[idx] = wp0[((size_t)ci0 * 9 + q2) * COUT + co];
        }
        if (FUSE && tid < 96) {
            int ci = tid >> 5, co = tid & 31;
            smWD[tid] = wd[(size_t)(cobase + co) * 3 + ci];
        }
        __syncthreads();

#pragma unroll 1
        for (int ci = 0; ci < CB; ++ci) {
            float p[15];
            const float* sp = &smIn[ci * 2178 + 2 * r * 66 + 4 * c];
#pragma unroll
            for (int i = 0; i < 3; ++i)
#pragma unroll
                for (int j = 0; j < 5; ++j)
                    p[i * 5 + j] = sp[i * 66 + j];
            const float* wrow = &smW[ci * 288];
#pragma unroll
            for (int k = 0; k < 9; ++k) {
                const int ky = k / 3, kx = k % 3;
#pragma unroll
                for (int g = 0; g < 8; ++g) {
                    v4f wv = *(const v4f*)&wrow[k * 32 + 4 * g];
                    fma4(acc[g],     p[ky * 5 + kx],     wv);
                    fma4(acc[8 + g], p[ky * 5 + kx + 2], wv);
                }
            }
        }
    }

    // channels-last epilogue: two cells (oy,ox), (oy,ox+1), 32 co contiguous
    const int oy = ty * 16 + r, ox = tx * 32 + 2 * c;
    size_t cellBase = (((size_t)n * Hout + oy) * Wout + ox) * COUT + cobase;
#pragma unroll
    for (int g = 0; g < 8; ++g) {
        v4f v0 = acc[g], v1 = acc[8 + g];
        if (RELU) {
#pragma unroll
            for (int e = 0; e < 4; ++e) { v0[e] = fmaxf(v0[e], 0.f); v1[e] = fmaxf(v1[e], 0.f); }
        }
        *(v4f*)&out[cellBase + 4 * g] = v0;
        *(v4f*)&out[cellBase + COUT + 4 * g] = v1;
    }

    if (FUSE) {
        // 1x1 from smIn (valid: CIN==CB, single chunk stays resident)
        v4f a0[8], a1[8];
#pragma unroll
        for (int g = 0; g < 8; ++g) {
            v4f bv = *(const v4f*)&bd[cobase + 4 * g];
            a0[g] = bv; a1[g] = bv;
        }
#pragma unroll
        for (int ci = 0; ci < CB; ++ci) {
            const float* sp = &smIn[ci * 2178 + 2 * r * 66 + 4 * c];
            float v0 = sp[66 + 1], v1 = sp[66 + 3];
#pragma unroll
            for (int g = 0; g < 8; ++g) {
                v4f wv = *(const v4f*)&smWD[ci * 32 + 4 * g];
                fma4(a0[g], v0, wv);
                fma4(a1[g], v1, wv);
            }
        }
        size_t cb1 = (((size_t)n * Hout + oy) * Wout + ox) * COUT + cobase;
#pragma unroll
        for (int g = 0; g < 8; ++g) {
            *(v4f*)&out1[cb1 + 4 * g] = a0[g];
            *(v4f*)&out1[cb1 + COUT + 4 * g] = a1[g];
        }
    }
}

// =========== ConvTranspose k3 s2 p1 op1 — fp32, 2 quads/thread ==============
template<int CIN, int CB, int COC, bool RELU>
__launch_bounds__(256, 3)
__global__ void deconv2_k(const float* __restrict__ in, const float* __restrict__ wp,
                          const float* __restrict__ bias, float* __restrict__ out,
                          int COUTR, int COUTP, int Hin, int Win)
{
    constexpr int RW = 33, RH = 17;
    __shared__ float smIn[CB * RH * RW];
    __shared__ float smW[CB * 9 * COC];
    const int Wout = Win * 2;
    const int tid = threadIdx.x;
    int b = blockIdx.x;
    const int chunks = COUTP / COC;
    const int qTX = Win / 32, qTY = Hin / 16;
    const int ch = b % chunks; b /= chunks;
    const int qtx = b % qTX; b /= qTX;
    const int qty = b % qTY; const int n = b / qTY;
    const int cobase = ch * COC;
    const int tqy = tid >> 4, tqx = tid & 15;
    const int qby = qty * 16, qbx = qtx * 32;

    v4f acc[8 * COC / 4];
#pragma unroll
    for (int g = 0; g < COC / 4; ++g) {
        v4f bv;
#pragma unroll
        for (int e = 0; e < 4; ++e)
            bv[e] = (cobase + 4 * g + e < COUTR) ? bias[cobase + 4 * g + e] : 0.f;
#pragma unroll
        for (int pt = 0; pt < 8; ++pt) acc[pt * (COC / 4) + g] = bv;
    }

    const size_t plane = (size_t)Hin * Win;
    const float* ip0 = in + (size_t)n * CIN * plane;
    const float* wp0 = wp + cobase;

    for (int ci0 = 0; ci0 < CIN; ci0 += CB) {
        __syncthreads();
        for (int idx = tid; idx < CB * RH * RW; idx += 256) {
            int ci = idx / (RH * RW), rem = idx - ci * (RH * RW);
            int rr = rem / RW, cc = rem - rr * RW;
            int gy = qby + rr, gx = qbx + cc;
            float v = 0.f;
            if (gy < Hin && gx < Win)
                v = ip0[(size_t)(ci0 + ci) * plane + (size_t)gy * Win + gx];
            smIn[idx] = v;
        }
        for (int idx = tid; idx < CB * 9 * COC; idx += 256) {
            int q2 = idx / COC, co = idx % COC;
            smW[idx] = wp0[((size_t)ci0 * 9 + q2) * COUTP + co];
        }
        __syncthreads();

#pragma unroll 1
        for (int ci = 0; ci < CB; ++ci) {
            float p[6];
            const float* sp = &smIn[ci * RH * RW + tqy * RW + 2 * tqx];
#pragma unroll
            for (int i = 0; i < 2; ++i)
#pragma unroll
                for (int j = 0; j < 3; ++j)
                    p[i * 3 + j] = sp[i * RW + j];
            const float* wrow = &smW[ci * 9 * COC];
#pragma unroll
            for (int k = 0; k < 9; ++k) {
                const int ky = k / 3, kx = k % 3;
                const int dy = (ky == 1) ? 0 : 1, iy = (ky == 0) ? 1 : 0;
                const int dx = (kx == 1) ? 0 : 1, ix = (kx == 0) ? 1 : 0;
#pragma unroll
                for (int g = 0; g < COC / 4; ++g) {
                    v4f wv = *(const v4f*)&wrow[k * COC + 4 * g];
                    fma4(acc[(0 + dy * 2 + dx) * (COC / 4) + g], p[iy * 3 + ix],     wv);
                    fma4(acc[(4 + dy * 2 + dx) * (COC / 4) + g], p[iy * 3 + ix + 1], wv);
                }
            }
        }
    }

    const size_t oPlane = (size_t)(Hin * 2) * Wout;
    const int oy = 2 * (qby + tqy), ox = 2 * (qbx + 2 * tqx);
#pragma unroll
    for (int g = 0; g < COC / 4; ++g)
#pragma unroll
        for (int e = 0; e < 4; ++e) {
            int cch = cobase + 4 * g + e;
            if (cch >= COUTR) break;
            float* op = out + ((size_t)n * COUTR + cch) * oPlane + (size_t)oy * Wout + ox;
#pragma unroll
            for (int a2 = 0; a2 < 2; ++a2) {
                float u0 = acc[(0 + a2 * 2 + 0) * (COC / 4) + g][e];
                float u1 = acc[(0 + a2 * 2 + 1) * (COC / 4) + g][e];
                float u2 = acc[(4 + a2 * 2 + 0) * (COC / 4) + g][e];
                float u3 = acc[(4 + a2 * 2 + 1) * (COC / 4) + g][e];
                if (RELU) { u0 = fmaxf(u0, 0.f); u1 = fmaxf(u1, 0.f);
                            u2 = fmaxf(u2, 0.f); u3 = fmaxf(u3, 0.f); }
                *(float4*)&op[(size_t)a2 * Wout] = make_float4(u0, u1, u2, u3);
            }
        }
}

// ===================== 1x1 conv stride S — 1 pos/thread, 32 co ==============
template<int CIN, int S, bool RELU, bool CLIN, bool CLOUT>
__launch_bounds__(256, 4)
__global__ void conv1x1_k(const float* __restrict__ in, const float* __restrict__ w,
                          const float* __restrict__ bias, float* __restrict__ out,
                          int COUT, int Hin, int Win, int Hout, int Wout)
{
    constexpr int COC = 32;
    __shared__ float smW[CIN * COC];
    const int tid = threadIdx.x;
    int b = blockIdx.x;
    const int chunks = COUT / COC;
    const int spB = (Hout * Wout) / 256;
    const int ch = b % chunks; b /= chunks;
    const int sb = b % spB; const int n = b / spB;
    const int cobase = ch * COC;

    for (int idx = tid; idx < CIN * COC; idx += 256) {
        int ci = idx / COC, co = idx - ci * COC;
        smW[idx] = w[(size_t)(cobase + co) * CIN + ci];
    }
    __syncthreads();

    const int pos = sb * 256 + tid;
    const int oy = pos / Wout, ox = pos - oy * Wout;

    v4f acc[8];
#pragma unroll
    for (int g = 0; g < 8; ++g) acc[g] = *(const v4f*)&bias[cobase + 4 * g];

    if (CLIN) {
        const float* ip = in + (((size_t)n * Hin + oy * S) * Win + ox * S) * CIN;
#pragma unroll 1
        for (int c4 = 0; c4 < CIN / 4; ++c4) {
            v4f v = *(const v4f*)&ip[c4 * 4];
#pragma unroll
            for (int e = 0; e < 4; ++e)
#pragma unroll
                for (int g = 0; g < 8; ++g)
                    fma4(acc[g], v[e], *(const v4f*)&smW[(c4 * 4 + e) * COC + 4 * g]);
        }
    } else {
        const size_t inPlane = (size_t)Hin * Win;
        const float* ip = in + (size_t)n * CIN * inPlane + (size_t)(oy * S) * Win + (size_t)(ox * S);
#pragma unroll 1
        for (int ci = 0; ci < CIN; ++ci) {
            float v = ip[(size_t)ci * inPlane];
#pragma unroll
            for (int g = 0; g < 8; ++g)
                fma4(acc[g], v, *(const v4f*)&smW[ci * COC + 4 * g]);
        }
    }
    const size_t outPlane = (size_t)Hout * Wout;
    if (CLOUT) {
        size_t cb2 = ((size_t)n * outPlane + pos) * COUT + cobase;
#pragma unroll
        for (int g = 0; g < 8; ++g) {
            v4f v = acc[g];
            if (RELU) {
#pragma unroll
                for (int e = 0; e < 4; ++e) v[e] = fmaxf(v[e], 0.f);
            }
            *(v4f*)&out[cb2 + 4 * g] = v;
        }
    } else {
        float* op = out + ((size_t)n * COUT + cobase) * outPlane + pos;
#pragma unroll
        for (int g = 0; g < 8; ++g)
#pragma unroll
            for (int e = 0; e < 4; ++e) {
                float v = acc[g][e];
                if (RELU) v = fmaxf(v, 0.f);
                op[(size_t)(4 * g + e) * outPlane] = v;
            }
    }
}

// ==================== MFMA quantize (argmin distance GEMM) ==================
// Input S2 channels-last [pos][64]; output Q channels-last [pos][64].
__launch_bounds__(256, 4)
__global__ void mquant_k(const float* __restrict__ h, const _Float16* __restrict__ QB,
                         const float* __restrict__ cn, const float* __restrict__ cb,
                         float* __restrict__ q)
{
    __shared__ __align__(16) _Float16 AF[2][8192];   // [hl][((mt*2+s)*64+lane)*8+j]
    __shared__ float cns[512];
    __shared__ int bidxs[128];

    const int tid = threadIdx.x;
    const int lane = tid & 63;
    const int wv = tid >> 6;
    const int n16 = lane & 15, qq = lane >> 4;

    const int n = blockIdx.x >> 5;
    const int rem0 = (blockIdx.x & 31) << 7;

    for (int u = tid; u < 1024; u += 256) {
        int posL = u >> 3, grp = u & 7;
        const float* gp = h + ((size_t)n * 4096 + rem0 + posL) * 64 + grp * 8;
        float4 v0 = *(const float4*)gp;
        float4 v1 = *(const float4*)(gp + 4);
        f16x8 hh, ll;
        hh[0] = (_Float16)v0.x; ll[0] = (_Float16)(v0.x - (float)hh[0]);
        hh[1] = (_Float16)v0.y; ll[1] = (_Float16)(v0.y - (float)hh[1]);
        hh[2] = (_Float16)v0.z; ll[2] = (_Float16)(v0.z - (float)hh[2]);
        hh[3] = (_Float16)v0.w; ll[3] = (_Float16)(v0.w - (float)hh[3]);
        hh[4] = (_Float16)v1.x; ll[4] = (_Float16)(v1.x - (float)hh[4]);
        hh[5] = (_Float16)v1.y; ll[5] = (_Float16)(v1.y - (float)hh[5]);
        hh[6] = (_Float16)v1.z; ll[6] = (_Float16)(v1.z - (float)hh[6]);
        hh[7] = (_Float16)v1.w; ll[7] = (_Float16)(v1.w - (float)hh[7]);
        int mt = posL >> 4, s = grp >> 2, qv = grp & 3;
        int a = ((mt * 2 + s) * 64 + (posL & 15) + qv * 16) * 8;
        *(f16x8*)&AF[0][a] = hh;
        *(f16x8*)&AF[1][a] = ll;
    }
    for (int u = tid; u < 512; u += 256) cns[u] = cn[u];
    __syncthreads();

    f16x8 aH[2][2], aL[2][2];
#pragma unroll
    for (int m = 0; m < 2; ++m)
#pragma unroll
        for (int s = 0; s < 2; ++s) {
            int a = (((wv * 2 + m) * 2 + s) * 64 + lane) * 8;
            aH[m][s] = *(const f16x8*)&AF[0][a];
            aL[m][s] = *(const f16x8*)&AF[1][a];
        }

    float best[2][4]; int bi[2][4];
#pragma unroll
    for (int m = 0; m < 2; ++m)
#pragma unroll
        for (int r = 0; r < 4; ++r) { best[m][r] = 3.4e38f; bi[m][r] = 0; }

    const uint4* qbp = (const uint4*)QB;
#pragma unroll 1
    for (int nt = 0; nt < 32; ++nt) {
        uint4 rH0 = qbp[((nt * 2 + 0) * 2 + 0) * 64 + lane];
        uint4 rL0 = qbp[((nt * 2 + 0) * 2 + 1) * 64 + lane];
        uint4 rH1 = qbp[((nt * 2 + 1) * 2 + 0) * 64 + lane];
        uint4 rL1 = qbp[((nt * 2 + 1) * 2 + 1) * 64 + lane];
        f16x8 bH0 = *(const f16x8*)&rH0;
        f16x8 bL0 = *(const f16x8*)&rL0;
        f16x8 bH1 = *(const f16x8*)&rH1;
        f16x8 bL1 = *(const f16x8*)&rL1;
        float cnv = cns[nt * 16 + n16];
        const int code = nt * 16 + n16;
        __builtin_amdgcn_s_setprio(1);
#pragma unroll
        for (int m = 0; m < 2; ++m) {
            v4f acc = {0.f, 0.f, 0.f, 0.f};
            acc = __builtin_amdgcn_mfma_f32_16x16x32_f16(aH[m][0], bH0, acc, 0, 0, 0);
            acc = __builtin_amdgcn_mfma_f32_16x16x32_f16(aL[m][0], bH0, acc, 0, 0, 0);
            acc = __builtin_amdgcn_mfma_f32_16x16x32_f16(aH[m][0], bL0, acc, 0, 0, 0);
            acc = __builtin_amdgcn_mfma_f32_16x16x32_f16(aH[m][1], bH1, acc, 0, 0, 0);
            acc = __builtin_amdgcn_mfma_f32_16x16x32_f16(aL[m][1], bH1, acc, 0, 0, 0);
            acc = __builtin_amdgcn_mfma_f32_16x16x32_f16(aH[m][1], bL1, acc, 0, 0, 0);
#pragma unroll
            for (int r = 0; r < 4; ++r) {
                float d = fmaf(-2.f, acc[r], cnv);
                if (d < best[m][r]) { best[m][r] = d; bi[m][r] = code; }
            }
        }
        __builtin_amdgcn_s_setprio(0);
    }

    // reduce across the 16 lane-columns; first-min tie-break (lowest index)
#pragma unroll
    for (int m = 0; m < 2; ++m)
#pragma unroll
        for (int r = 0; r < 4; ++r) {
#pragma unroll
            for (int msk = 1; msk < 16; msk <<= 1) {
                float ob = __shfl_xor(best[m][r], msk);
                int oi = __shfl_xor(bi[m][r], msk);
                if (ob < best[m][r] || (ob == best[m][r] && oi < bi[m][r])) {
                    best[m][r] = ob; bi[m][r] = oi;
                }
            }
            if (n16 == 0) bidxs[wv * 32 + m * 16 + qq * 4 + r] = bi[m][r];
        }
    __syncthreads();

    const int p = tid & 127, jh = tid >> 7;
    const int code = bidxs[p];
    const float4* crow4 = (const float4*)(cb + (size_t)code * 64);
    float4* qp4 = (float4*)(q + ((size_t)n * 4096 + rem0 + p) * 64);
#pragma unroll
    for (int k = 0; k < 8; ++k)
        qp4[jh * 8 + k] = crow4[jh * 8 + k];
}

extern "C" void kernel_launch(void* const* d_in, const int* in_sizes, int n_in,
                              void* d_out, int out_size, void* d_ws, size_t ws_size,
                              hipStream_t stream)
{
    const float* x    = (const float*)d_in[0];
    const float* e0w1 = (const float*)d_in[1];  const float* e0b1 = (const float*)d_in[2];
    const float* e0w2 = (const float*)d_in[3];  const float* e0b2 = (const float*)d_in[4];
    const float* e0wd = (const float*)d_in[5];  const float* e0bd = (const float*)d_in[6];
    const float* e1w1 = (const float*)d_in[7];  const float* e1b1 = (const float*)d_in[8];
    const float* e1w2 = (const float*)d_in[9];  const float* e1b2 = (const float*)d_in[10];
    const float* e1wd = (const float*)d_in[11]; const float* e1bd = (const float*)d_in[12];
    const float* e2w1 = (const float*)d_in[13]; const float* e2b1 = (const float*)d_in[14];
    const float* e2w2 = (const float*)d_in[15]; const float* e2b2 = (const float*)d_in[16];
    const float* e2wd = (const float*)d_in[17]; const float* e2bd = (const float*)d_in[18];
    const float* d0w  = (const float*)d_in[19]; const float* d0b  = (const float*)d_in[20];
    const float* d1w  = (const float*)d_in[21]; const float* d1b  = (const float*)d_in[22];
    const float* d2w  = (const float*)d_in[23]; const float* d2b  = (const float*)d_in[24];
    const float* cb   = (const float*)d_in[25];
    float* out = (float*)d_out;
    float* ws  = (float*)d_ws;

    // ---- packs in d_out slack (d_out only written by the final dec2) ----
    float* P_e0w1 = out + 0;            // fp32 pack, 1728
    _Float16* Bh_d1   = (_Float16*)(out + 1728);     // 73728 halves
    _Float16* Bl_d1   = (_Float16*)(out + 38592);    // 73728 halves
    _Float16* Bh_e0c2 = (_Float16*)(out + 77760);
    _Float16* Bl_e0c2 = (_Float16*)(out + 96192);
    _Float16* Bh_e1c2 = (_Float16*)(out + 114624);
    _Float16* Bl_e1c2 = (_Float16*)(out + 188352);
    _Float16* Bh_e2c1 = (_Float16*)(out + 262080);
    _Float16* Bl_e2c1 = (_Float16*)(out + 298944);
    _Float16* Bh_e2c2 = (_Float16*)(out + 335808);
    _Float16* Bl_e2c2 = (_Float16*)(out + 354240);
    _Float16* Bh_d0   = (_Float16*)(out + 372672);
    _Float16* Bl_d0   = (_Float16*)(out + 409536);
    _Float16* Bh_e1c1 = (_Float16*)(out + 446400);   // 73728 halves
    _Float16* Bl_e1c1 = (_Float16*)(out + 483264);   // 73728 halves
    _Float16* QB = (_Float16*)(out + 520128);
    float* CN = out + 552896;
    // fused-1x1 pack for enc1 downsample (e1wd: 128x64 -> 8192 halves x2)
    _Float16* Wh_e1d = (_Float16*)(out + 553408);
    _Float16* Wl_e1d = (_Float16*)(out + 557504);
    float* P_d2w  = ws + 50405376;      // fp32 pack; written after S1 is dead

    // ---- ws activation layout (floats), liveness-planned ----
    // ALL activations channels-last except x (input) and D1.
    float* S0 = ws;                     // CL [n][128][128][64], enc0 out
    float* T1 = ws + 33554432;          // CL, enc0 conv1 out
    float* T3 = ws + 33554432;          // CL, enc1 conv1 out
    float* S1 = ws + 50331648;          // CL [n][64][64][128], enc1 out
    float* S2 = ws;                     // CL, enc2 out
    float* T5 = ws + 8388608;           // CL
    float* Q  = ws + 16777216;          // CL
    float* D0 = ws + 33554432;          // CL, dec0 out
    float* D1 = ws;                     // NCHW, dec1 out

    dim3 blk(256);
    auto rp = [&](const float* src, float* dst, int cout, int coutR, int cin, int flip, int dec) {
        int tot = cin * 9 * cout;
        repack_k<<<dim3((tot + 255) / 256), blk, 0, stream>>>(src, dst, cout, coutR, cin, flip, dec);
    };
    auto rpB = [&](const float* src, _Float16* bh, _Float16* bl, int cout, int cin, int dec) {
        int tot = 9 * cin * cout;
        repackB16_k<<<dim3((tot + 255) / 256), blk, 0, stream>>>(src, bh, bl, cout, cin, dec);
    };

    rp(e0w1, P_e0w1, 64, 64, 3, 0, 0);
    rpB(e0w2, Bh_e0c2, Bl_e0c2, 64, 64, 0);
    rpB(e1w1, Bh_e1c1, Bl_e1c1, 128, 64, 0);
    rpB(e1w2, Bh_e1c2, Bl_e1c2, 128, 128, 0);
    rpB(e2w1, Bh_e2c1, Bl_e2c1, 64, 128, 0);
    rpB(e2w2, Bh_e2c2, Bl_e2c2, 64, 64, 0);
    rpB(d0w,  Bh_d0,   Bl_d0,   128, 64, 1);   // ConvT s1 == flipped conv
    rpB(d1w,  Bh_d1,   Bl_d1,   64, 128, 1);   // ConvT s2, flipped-tap pack
    repackW16_k<<<dim3(32), blk, 0, stream>>>(e1wd, Wh_e1d, Wl_e1d, 128, 64);
    repackQ_k<<<dim3(256), blk, 0, stream>>>(cb, QB);
    cbnorm_k<<<dim3(2), blk, 0, stream>>>(cb, CN);

    // --- enc0 (3 -> 64, s2): 256 -> 128; conv3s2 also emits S0 = 1x1(x) ---
    conv3s2_k<3, 3, true, true><<<dim3(32 * 8 * 4 * 2), blk, 0, stream>>>(
        x, P_e0w1, e0b1, T1, e0wd, e0bd, S0, 64, 256, 256);
    mconv3s1_k<64, true, 2, true, true><<<dim3(32 * 8 * 8 * 1), blk, 0, stream>>>(
        T1, Bh_e0c2, Bl_e0c2, e0b2, S0, S0, 64, 128, 128);

    // --- enc1 (64 -> 128, s2): 128 -> 64; mconv3s2 also emits S1 = 1x1(S0) ---
    mconv3s2_k<64, 8, true><<<dim3(32 * 16 * 4), blk, 0, stream>>>(
        S0, Bh_e1c1, Bl_e1c1, e1b1, T3, Wh_e1d, Wl_e1d, e1bd, S1, 128, 128, 128);
    mconv3s1_k<128, true, 2, true, true><<<dim3(32 * 4 * 4 * 2), blk, 0, stream>>>(
        T3, Bh_e1c2, Bl_e1c2, e1b2, S1, S1, 128, 64, 64);

    // --- enc2 (128 -> 64, s1) ---
    conv1x1_k<128, 1, false, true, true><<<dim3(32 * 16 * 2), blk, 0, stream>>>(
        S1, e2wd, e2bd, S2, 64, 64, 64, 64, 64);
    mconv3s1_k<128, true, 0, true, true><<<dim3(32 * 4 * 4 * 1), blk, 0, stream>>>(
        S1, Bh_e2c1, Bl_e2c1, e2b1, T5, nullptr, 64, 64, 64);
    rp(d2w, P_d2w, 4, 3, 64, 0, 1);             // S1 dead after the two reads above
    mconv3s1_k<64, true, 2, true, true><<<dim3(32 * 4 * 4 * 1), blk, 0, stream>>>(
        T5, Bh_e2c2, Bl_e2c2, e2b2, S2, S2, 64, 64, 64);

    // --- quantize (MFMA argmin), CL in/out ---
    mquant_k<<<dim3(1024), blk, 0, stream>>>(S2, QB, CN, cb, Q);

    // --- dec0: ConvT s1 (64 -> 128) as flipped conv, ReLU, CL in/out ---
    mconv3s1_k<64, true, 0, true, true><<<dim3(32 * 4 * 4 * 2), blk, 0, stream>>>(
        Q, Bh_d0, Bl_d0, d0b, D0, nullptr, 128, 64, 64);

    // --- dec1: ConvT s2 (128 -> 64), ReLU: 64 -> 128 (MFMA, 4-phase, CL in) ---
    mdeconv2_k<128, true><<<dim3(32 * 16 * 4), blk, 0, stream>>>(
        D0, Bh_d1, Bl_d1, d1b, D1, 64, 64, 64);

    // --- dec2: ConvT s2 (64 -> 3): 128 -> 256 ---
    deconv2_k<64, 8, 4, false><<<dim3(32 * 4 * 8), blk, 0, stream>>>(
        D1, P_d2w, d2b, out, 3, 4, 128, 128);
}